// Round 1
// baseline (401.385 us; speedup 1.0000x reference)
//
#include <hip/hip_runtime.h>

typedef unsigned short u16;
typedef unsigned int   u32;
typedef __attribute__((ext_vector_type(8))) __bf16 bf16x8;
typedef __attribute__((ext_vector_type(8))) short  short8;
typedef __attribute__((ext_vector_type(4))) float  f32x4;
typedef __attribute__((ext_vector_type(4))) u16    u16x4;

#define DEV static __device__ __forceinline__

DEV u16 f2bf(float f){
  u32 u = __builtin_bit_cast(u32, f);
  u += 0x7FFFu + ((u >> 16) & 1u);
  return (u16)(u >> 16);
}
DEV float bf2f(u16 h){
  return __builtin_bit_cast(float, (u32)h << 16);
}
DEV f32x4 mfma16(short8 a, short8 b, f32x4 c){
  return __builtin_amdgcn_mfma_f32_16x16x32_bf16(
      __builtin_bit_cast(bf16x8, a), __builtin_bit_cast(bf16x8, b), c, 0, 0, 0);
}

// ---------------- weight transpose + bf16 cast: W(K,N) f32 -> Wt(N,K) bf16 ----
__global__ __launch_bounds__(256) void k_transpose(const float* __restrict__ W,
                                                   u16* __restrict__ Wt, int K, int N){
  __shared__ float t[32][33];
  const int k0 = blockIdx.x*32, n0 = blockIdx.y*32;
  const int tx = threadIdx.x & 31, ty = threadIdx.x >> 5;
  #pragma unroll
  for (int j=0;j<4;++j) t[ty + j*8][tx] = W[(size_t)(k0+ty+j*8)*N + n0 + tx];
  __syncthreads();
  #pragma unroll
  for (int j=0;j<4;++j) Wt[(size_t)(n0+ty+j*8)*K + k0 + tx] = f2bf(t[tx][ty+j*8]);
}

// ---------------- RMSNorm: x(8192,1024) f32 -> xn bf16 ----------------------
__global__ __launch_bounds__(256) void k_rmsnorm(const float* __restrict__ x,
                                                 const float* __restrict__ w,
                                                 u16* __restrict__ xn){
  const int row = blockIdx.x;
  const int t = threadIdx.x;
  const float4* xr = (const float4*)(x + (size_t)row*1024);
  float4 v = xr[t];
  float ss = v.x*v.x + v.y*v.y + v.z*v.z + v.w*v.w;
  #pragma unroll
  for (int off=32; off; off>>=1) ss += __shfl_xor(ss, off, 64);
  __shared__ float ps[4];
  if ((t & 63) == 0) ps[t>>6] = ss;
  __syncthreads();
  const float tot = ps[0]+ps[1]+ps[2]+ps[3];
  const float rinv = rsqrtf(tot * (1.0f/1024.0f) + 1e-6f);
  const float4* wr = (const float4*)w;
  float4 g = wr[t];
  u16x4 o;
  o.x = f2bf(v.x*rinv*g.x); o.y = f2bf(v.y*rinv*g.y);
  o.z = f2bf(v.z*rinv*g.z); o.w = f2bf(v.w*rinv*g.w);
  *(u16x4*)(xn + (size_t)row*1024 + t*4) = o;
}

// ---------------- RoPE cos/sin table: (2048, 32) float2 ----------------------
__global__ void k_cs(float2* __restrict__ cs){
  const int idx = blockIdx.x*256 + threadIdx.x;
  if (idx >= 2048*32) return;
  const int s = idx >> 5, j = idx & 31;
  // inv_freq = 10000^(-j/32) = exp(-j * ln(10000)/32)
  const float ang = (float)s * expf(-(float)j * (9.210340371976184f/32.0f));
  cs[idx] = make_float2(cosf(ang), sinf(ang));
}

// ---------------- RoPE in-place on bf16 [b][s][h*64+hd] ----------------------
__global__ __launch_bounds__(256) void k_rope(u16* __restrict__ t, const float2* __restrict__ cs){
  const int idx = blockIdx.x*256 + threadIdx.x;     // 8192*16*32 = 4M
  const int j = idx & 31;
  const int h = (idx >> 5) & 15;
  const int row = idx >> 9;                          // b*2048+s
  const int s = row & 2047;
  const float2 c = cs[(s<<5) + j];
  const size_t base = ((size_t)row << 10) + (h<<6) + j;
  const float t1 = bf2f(t[base]), t2 = bf2f(t[base+32]);
  t[base]    = f2bf(t1*c.x - t2*c.y);
  t[base+32] = f2bf(t1*c.y + t2*c.x);
}

// ---------------- GEMM: A(M,K) bf16 rm  x  Bt(N,K) bf16 rm -> C(M,N) ---------
// MODE 0: bf16 store C[m*N+n]
// MODE 1: bf16 transposed store to vT[(b*1024 + n)*2048 + s]   (M=8192,N=1024)
// MODE 2: f32 store with residual add: Cf = acc + resid
template<int MODE>
__global__ __launch_bounds__(256) void k_gemm(const u16* __restrict__ A,
                                              const u16* __restrict__ Bt,
                                              u16* __restrict__ Cb,
                                              float* __restrict__ Cf,
                                              const float* __restrict__ resid,
                                              int N, int K){
  __shared__ u16 Al[128*72];
  __shared__ u16 Bl[128*72];
  const int tid = threadIdx.x;
  const int lane = tid & 63;
  const int wv_ = tid >> 6;
  const int wm = (wv_ >> 1) * 64, wn = (wv_ & 1) * 64;
  const int m0 = blockIdx.y * 128, n0 = blockIdx.x * 128;
  const int lr = lane & 15, lg = lane >> 4;

  f32x4 acc[4][4] = {};

  const int srow = tid >> 1;          // 0..127
  const int scol = (tid & 1) * 32;    // 0 / 32

  for (int k0 = 0; k0 < K; k0 += 64) {
    __syncthreads();
    const u16* Ag = A  + (size_t)(m0 + srow)*K + k0 + scol;
    const u16* Bg = Bt + (size_t)(n0 + srow)*K + k0 + scol;
    u16* Aw = Al + srow*72 + scol;
    u16* Bw = Bl + srow*72 + scol;
    #pragma unroll
    for (int j=0;j<4;++j){
      *(short8*)(Aw + j*8) = *(const short8*)(Ag + j*8);
      *(short8*)(Bw + j*8) = *(const short8*)(Bg + j*8);
    }
    __syncthreads();
    #pragma unroll
    for (int kk=0; kk<2; ++kk){
      const int ko = kk*32 + lg*8;
      short8 af[4], bfr[4];
      #pragma unroll
      for (int m=0;m<4;++m) af[m]  = *(const short8*)(Al + (wm + m*16 + lr)*72 + ko);
      #pragma unroll
      for (int n=0;n<4;++n) bfr[n] = *(const short8*)(Bl + (wn + n*16 + lr)*72 + ko);
      #pragma unroll
      for (int m=0;m<4;++m)
        #pragma unroll
        for (int n=0;n<4;++n)
          acc[m][n] = mfma16(af[m], bfr[n], acc[m][n]);
    }
  }

  #pragma unroll
  for (int m=0;m<4;++m){
    const int rb = m0 + wm + m*16 + lg*4;        // first of 4 consecutive rows
    #pragma unroll
    for (int n=0;n<4;++n){
      const int c = n0 + wn + n*16 + lr;
      if (MODE == 0){
        #pragma unroll
        for (int i=0;i<4;++i) Cb[(size_t)(rb+i)*N + c] = f2bf(acc[m][n][i]);
      } else if (MODE == 1){
        const int b = rb >> 11, s = rb & 2047;
        u16x4 pk;
        pk.x = f2bf(acc[m][n][0]); pk.y = f2bf(acc[m][n][1]);
        pk.z = f2bf(acc[m][n][2]); pk.w = f2bf(acc[m][n][3]);
        *(u16x4*)(Cb + (((size_t)(b*1024 + c)) << 11) + s) = pk;
      } else {
        #pragma unroll
        for (int i=0;i<4;++i){
          const size_t off = (size_t)(rb+i)*N + c;
          Cf[off] = acc[m][n][i] + resid[off];
        }
      }
    }
  }
}

// ---------------- flash attention ------------------------------------------
// q,k: [b][s][h*64+hd] bf16 (RoPE'd); vT: [(b*1024 + h*64+hd)][s] bf16
// out: [b][s][h*64+hd] bf16.  grid (S/64, B*H), 256 thr = 4 waves x 16 q-rows
__global__ __launch_bounds__(256) void k_attn(const u16* __restrict__ q,
                                              const u16* __restrict__ kmat,
                                              const u16* __restrict__ vT,
                                              u16* __restrict__ o){
  __shared__ u16 Kl[64*72];
  __shared__ u16 Vl[64*72];
  __shared__ u16 Pl[4][16*72];
  const int tid = threadIdx.x, lane = tid & 63, w = tid >> 6;
  const int lr = lane & 15, lg = lane >> 4;
  const int bh = blockIdx.y, b = bh >> 4, h = bh & 15;
  const int q0 = blockIdx.x * 64;

  short8 qf[2];
  {
    const size_t base = ((size_t)(b*2048 + q0 + w*16 + lr) << 10) + (h<<6) + lg*8;
    qf[0] = *(const short8*)(q + base);
    qf[1] = *(const short8*)(q + base + 32);
  }
  f32x4 oacc[4] = {};
  float mrow[4] = {-1e30f,-1e30f,-1e30f,-1e30f};
  float lrow[4] = {0.f,0.f,0.f,0.f};

  const size_t kbase = ((size_t)(b*2048) << 10) + (h << 6);
  const size_t vbase = ((size_t)(b*1024 + h*64)) << 11;

  const int sr = tid >> 2;        // 0..63
  const int sc = (tid & 3) * 8;   // 0,8,16,24

  for (int kv0 = 0; kv0 < 2048; kv0 += 64){
    __syncthreads();
    {
      const u16* kg = kmat + kbase + ((size_t)(kv0 + sr) << 10) + sc;
      *(short8*)(Kl + sr*72 + sc)      = *(const short8*)(kg);
      *(short8*)(Kl + sr*72 + sc + 32) = *(const short8*)(kg + 32);
      const u16* vg = vT + vbase + ((size_t)sr << 11) + kv0 + sc;
      *(short8*)(Vl + sr*72 + sc)      = *(const short8*)(vg);
      *(short8*)(Vl + sr*72 + sc + 32) = *(const short8*)(vg + 32);
    }
    __syncthreads();

    f32x4 sacc[4] = {};
    #pragma unroll
    for (int kt=0; kt<2; ++kt){
      const int ko = kt*32 + lg*8;
      #pragma unroll
      for (int n=0;n<4;++n){
        short8 kf = *(const short8*)(Kl + (n*16 + lr)*72 + ko);
        sacc[n] = mfma16(qf[kt], kf, sacc[n]);
      }
    }
    // online softmax over this 64-key tile (rows live in (lg, reg i))
    #pragma unroll
    for (int i=0;i<4;++i){
      float s0 = sacc[0][i]*0.125f, s1 = sacc[1][i]*0.125f;
      float s2 = sacc[2][i]*0.125f, s3 = sacc[3][i]*0.125f;
      float mx = fmaxf(fmaxf(s0,s1), fmaxf(s2,s3));
      #pragma unroll
      for (int off=1; off<16; off<<=1) mx = fmaxf(mx, __shfl_xor(mx, off, 64));
      const float mnew = fmaxf(mrow[i], mx);
      const float corr = __expf(mrow[i] - mnew);
      mrow[i] = mnew;
      const float p0 = __expf(s0-mnew), p1 = __expf(s1-mnew);
      const float p2 = __expf(s2-mnew), p3 = __expf(s3-mnew);
      float rs = p0+p1+p2+p3;
      #pragma unroll
      for (int off=1; off<16; off<<=1) rs += __shfl_xor(rs, off, 64);
      lrow[i] = lrow[i]*corr + rs;
      #pragma unroll
      for (int n=0;n<4;++n) oacc[n][i] *= corr;
      u16* pr = &Pl[w][(lg*4 + i)*72 + lr];
      pr[0]  = f2bf(p0); pr[16] = f2bf(p1);
      pr[32] = f2bf(p2); pr[48] = f2bf(p3);
    }
    __syncthreads();
    // PV
    #pragma unroll
    for (int kt=0;kt<2;++kt){
      const int ko = kt*32 + lg*8;
      short8 pf = *(const short8*)(&Pl[w][lr*72 + ko]);
      #pragma unroll
      for (int n=0;n<4;++n){
        short8 vf = *(const short8*)(Vl + (n*16 + lr)*72 + ko);
        oacc[n] = mfma16(pf, vf, oacc[n]);
      }
    }
  }
  float inv[4];
  #pragma unroll
  for (int i=0;i<4;++i) inv[i] = 1.0f / lrow[i];
  const size_t obase = ((size_t)(b*2048 + q0 + w*16 + lg*4) << 10) + (h<<6);
  #pragma unroll
  for (int n=0;n<4;++n)
    #pragma unroll
    for (int i=0;i<4;++i)
      o[obase + ((size_t)i << 10) + n*16 + lr] = f2bf(oacc[n][i] * inv[i]);
}

// ---------------------------------------------------------------------------
extern "C" void kernel_launch(void* const* d_in, const int* in_sizes, int n_in,
                              void* d_out, int out_size, void* d_ws, size_t ws_size,
                              hipStream_t stream){
  const float* x      = (const float*)d_in[0];
  const float* norm_w = (const float*)d_in[1];
  const float* wq     = (const float*)d_in[2];
  const float* kvd    = (const float*)d_in[3];
  const float* wk     = (const float*)d_in[4];
  const float* wv     = (const float*)d_in[5];
  const float* wo     = (const float*)d_in[6];
  float* out = (float*)d_out;

  char* ws = (char*)d_ws;
  const size_t SZ = (size_t)8192*1024*2;       // 16 MB bf16 tensor
  u16* xn   = (u16*)(ws);
  u16* q    = (u16*)(ws + SZ);
  u16* kmat = (u16*)(ws + 2*SZ);
  u16* vT   = (u16*)(ws + 3*SZ);
  u16* attn = (u16*)(ws + 4*SZ);
  u16* kv   = (u16*)(ws + 5*SZ);               // 8 MB
  u16* wqT  = (u16*)(ws + 5*SZ + (size_t)8192*512*2);
  u16* kvdT = wqT  + 1024*1024;
  u16* wkT  = kvdT + 512*1024;
  u16* wvT  = wkT  + 1024*512;
  u16* woT  = wvT  + 1024*512;
  float2* cs = (float2*)(woT + 1024*1024);

  // weights -> bf16 transposed
  k_transpose<<<dim3(32,32), 256, 0, stream>>>(wq,  wqT,  1024, 1024);
  k_transpose<<<dim3(32,16), 256, 0, stream>>>(kvd, kvdT, 1024, 512);
  k_transpose<<<dim3(16,32), 256, 0, stream>>>(wk,  wkT,  512, 1024);
  k_transpose<<<dim3(16,32), 256, 0, stream>>>(wv,  wvT,  512, 1024);
  k_transpose<<<dim3(32,32), 256, 0, stream>>>(wo,  woT,  1024, 1024);

  k_rmsnorm<<<8192, 256, 0, stream>>>(x, norm_w, xn);
  k_cs<<<256, 256, 0, stream>>>(cs);

  // q = xn @ wq ; kv = xn @ kv_down ; k = kv @ wk ; vT = (kv @ wv)^T
  k_gemm<0><<<dim3(8,64), 256, 0, stream>>>(xn, wqT,  q,    nullptr, nullptr, 1024, 1024);
  k_gemm<0><<<dim3(4,64), 256, 0, stream>>>(xn, kvdT, kv,   nullptr, nullptr, 512,  1024);
  k_gemm<0><<<dim3(8,64), 256, 0, stream>>>(kv, wkT,  kmat, nullptr, nullptr, 1024, 512);
  k_gemm<1><<<dim3(8,64), 256, 0, stream>>>(kv, wvT,  vT,   nullptr, nullptr, 1024, 512);

  k_rope<<<16384, 256, 0, stream>>>(q,    cs);
  k_rope<<<16384, 256, 0, stream>>>(kmat, cs);

  k_attn<<<dim3(32,64), 256, 0, stream>>>(q, kmat, vT, attn);

  // out = attn @ wo + x
  k_gemm<2><<<dim3(8,64), 256, 0, stream>>>(attn, woT, nullptr, out, x, 1024, 1024);
}

// Round 2
// 285.198 us; speedup vs baseline: 1.4074x; 1.4074x over previous
//
#include <hip/hip_runtime.h>

typedef unsigned short u16;
typedef unsigned int   u32;
typedef __attribute__((ext_vector_type(8))) __bf16 bf16x8;
typedef __attribute__((ext_vector_type(8))) short  short8;
typedef __attribute__((ext_vector_type(4))) float  f32x4;
typedef __attribute__((ext_vector_type(4))) u16    u16x4;

#define DEV static __device__ __forceinline__

DEV u16 f2bf(float f){
  u32 u = __builtin_bit_cast(u32, f);
  u += 0x7FFFu + ((u >> 16) & 1u);
  return (u16)(u >> 16);
}
DEV float bf2f(u16 h){
  return __builtin_bit_cast(float, (u32)h << 16);
}
DEV f32x4 mfma16(short8 a, short8 b, f32x4 c){
  return __builtin_amdgcn_mfma_f32_16x16x32_bf16(
      __builtin_bit_cast(bf16x8, a), __builtin_bit_cast(bf16x8, b), c, 0, 0, 0);
}
// XOR swizzle for 128-byte-row LDS tiles: spread rows across bank quads.
DEV int swz(int byteoff, int row){ return byteoff ^ ((row & 7) << 4); }

// ---------------- weight transpose + bf16 cast: W(K,N) f32 -> Wt(N,K) bf16 ----
__global__ __launch_bounds__(256) void k_transpose(const float* __restrict__ W,
                                                   u16* __restrict__ Wt, int K, int N){
  __shared__ float t[32][33];
  const int k0 = blockIdx.x*32, n0 = blockIdx.y*32;
  const int tx = threadIdx.x & 31, ty = threadIdx.x >> 5;
  #pragma unroll
  for (int j=0;j<4;++j) t[ty + j*8][tx] = W[(size_t)(k0+ty+j*8)*N + n0 + tx];
  __syncthreads();
  #pragma unroll
  for (int j=0;j<4;++j) Wt[(size_t)(n0+ty+j*8)*K + k0 + tx] = f2bf(t[tx][ty+j*8]);
}

// ---------------- RMSNorm: x(8192,1024) f32 -> xn bf16 ----------------------
__global__ __launch_bounds__(256) void k_rmsnorm(const float* __restrict__ x,
                                                 const float* __restrict__ w,
                                                 u16* __restrict__ xn){
  const int row = blockIdx.x;
  const int t = threadIdx.x;
  const float4* xr = (const float4*)(x + (size_t)row*1024);
  float4 v = xr[t];
  float ss = v.x*v.x + v.y*v.y + v.z*v.z + v.w*v.w;
  #pragma unroll
  for (int off=32; off; off>>=1) ss += __shfl_xor(ss, off, 64);
  __shared__ float ps[4];
  if ((t & 63) == 0) ps[t>>6] = ss;
  __syncthreads();
  const float tot = ps[0]+ps[1]+ps[2]+ps[3];
  const float rinv = rsqrtf(tot * (1.0f/1024.0f) + 1e-6f);
  const float4* wr = (const float4*)w;
  float4 g = wr[t];
  u16x4 o;
  o.x = f2bf(v.x*rinv*g.x); o.y = f2bf(v.y*rinv*g.y);
  o.z = f2bf(v.z*rinv*g.z); o.w = f2bf(v.w*rinv*g.w);
  *(u16x4*)(xn + (size_t)row*1024 + t*4) = o;
}

// ---------------- RoPE cos/sin table: (2048, 32) float2 ----------------------
__global__ void k_cs(float2* __restrict__ cs){
  const int idx = blockIdx.x*256 + threadIdx.x;
  if (idx >= 2048*32) return;
  const int s = idx >> 5, j = idx & 31;
  const float ang = (float)s * expf(-(float)j * (9.210340371976184f/32.0f));
  cs[idx] = make_float2(cosf(ang), sinf(ang));
}

// ---------------- RoPE in-place on bf16 [b][s][h*64+hd], optional scale ------
__global__ __launch_bounds__(256) void k_rope(u16* __restrict__ t, const float2* __restrict__ cs,
                                              float scale){
  const int idx = blockIdx.x*256 + threadIdx.x;     // 8192*16*32 = 4M
  const int j = idx & 31;
  const int h = (idx >> 5) & 15;
  const int row = idx >> 9;                          // b*2048+s
  const int s = row & 2047;
  const float2 c = cs[(s<<5) + j];
  const size_t base = ((size_t)row << 10) + (h<<6) + j;
  const float t1 = bf2f(t[base]), t2 = bf2f(t[base+32]);
  t[base]    = f2bf((t1*c.x - t2*c.y)*scale);
  t[base+32] = f2bf((t1*c.y + t2*c.x)*scale);
}

// ---------------- GEMM: A(M,K) bf16 rm  x  Bt(N,K) bf16 rm -> C(M,N) ---------
template<int MODE>
__global__ __launch_bounds__(256) void k_gemm(const u16* __restrict__ A,
                                              const u16* __restrict__ Bt,
                                              u16* __restrict__ Cb,
                                              float* __restrict__ Cf,
                                              const float* __restrict__ resid,
                                              int N, int K){
  __shared__ u16 Al[128*72];
  __shared__ u16 Bl[128*72];
  const int tid = threadIdx.x;
  const int lane = tid & 63;
  const int wv_ = tid >> 6;
  const int wm = (wv_ >> 1) * 64, wn = (wv_ & 1) * 64;
  const int m0 = blockIdx.y * 128, n0 = blockIdx.x * 128;
  const int lr = lane & 15, lg = lane >> 4;

  f32x4 acc[4][4] = {};

  const int srow = tid >> 1;          // 0..127
  const int scol = (tid & 1) * 32;    // 0 / 32

  for (int k0 = 0; k0 < K; k0 += 64) {
    __syncthreads();
    const u16* Ag = A  + (size_t)(m0 + srow)*K + k0 + scol;
    const u16* Bg = Bt + (size_t)(n0 + srow)*K + k0 + scol;
    u16* Aw = Al + srow*72 + scol;
    u16* Bw = Bl + srow*72 + scol;
    #pragma unroll
    for (int j=0;j<4;++j){
      *(short8*)(Aw + j*8) = *(const short8*)(Ag + j*8);
      *(short8*)(Bw + j*8) = *(const short8*)(Bg + j*8);
    }
    __syncthreads();
    #pragma unroll
    for (int kk=0; kk<2; ++kk){
      const int ko = kk*32 + lg*8;
      short8 af[4], bfr[4];
      #pragma unroll
      for (int m=0;m<4;++m) af[m]  = *(const short8*)(Al + (wm + m*16 + lr)*72 + ko);
      #pragma unroll
      for (int n=0;n<4;++n) bfr[n] = *(const short8*)(Bl + (wn + n*16 + lr)*72 + ko);
      #pragma unroll
      for (int m=0;m<4;++m)
        #pragma unroll
        for (int n=0;n<4;++n)
          acc[m][n] = mfma16(af[m], bfr[n], acc[m][n]);
    }
  }

  #pragma unroll
  for (int m=0;m<4;++m){
    const int rb = m0 + wm + m*16 + lg*4;
    #pragma unroll
    for (int n=0;n<4;++n){
      const int c = n0 + wn + n*16 + lr;
      if (MODE == 0){
        #pragma unroll
        for (int i=0;i<4;++i) Cb[(size_t)(rb+i)*N + c] = f2bf(acc[m][n][i]);
      } else if (MODE == 1){
        const int b = rb >> 11, s = rb & 2047;
        u16x4 pk;
        pk.x = f2bf(acc[m][n][0]); pk.y = f2bf(acc[m][n][1]);
        pk.z = f2bf(acc[m][n][2]); pk.w = f2bf(acc[m][n][3]);
        *(u16x4*)(Cb + (((size_t)(b*1024 + c)) << 11) + s) = pk;
      } else {
        #pragma unroll
        for (int i=0;i<4;++i){
          const size_t off = (size_t)(rb+i)*N + c;
          Cf[off] = acc[m][n][i] + resid[off];
        }
      }
    }
  }
}

// ---------------- flash attention (swapped-QK, swizzled LDS, async stage) ----
// q: pre-scaled by 1/8.  q,k: [b][s][h*64+hd] bf16; vT: [(b*1024+h*64+hd)][s]
// grid (S/64, B*H), 256 thr = 4 waves x 16 q-rows each, KVBLK=64.
__global__ __launch_bounds__(256) void k_attn(const u16* __restrict__ q,
                                              const u16* __restrict__ kmat,
                                              const u16* __restrict__ vT,
                                              u16* __restrict__ o){
  __shared__ __align__(16) u16 Kl[64*64];
  __shared__ __align__(16) u16 Vl[64*64];
  __shared__ __align__(16) u16 Pl[4][16*64];
  const int tid = threadIdx.x, lane = tid & 63, w = tid >> 6;
  const int lr = lane & 15, lg = lane >> 4;
  const int bh = blockIdx.y, b = bh >> 4, h = bh & 15;
  const int q0 = blockIdx.x * 64;

  // Q fragment (B-operand): lane holds q-col = lr, k(hd) = kt*32 + lg*8 + i
  short8 qf[2];
  {
    const size_t base = ((size_t)(b*2048 + q0 + w*16 + lr) << 10) + (h<<6) + lg*8;
    qf[0] = *(const short8*)(q + base);
    qf[1] = *(const short8*)(q + base + 32);
  }
  f32x4 oacc[4] = {};
  float mrow = -1e30f, lrow = 0.f;     // per-lane: q = lr (4 dup copies across lg)

  const size_t kbase = ((size_t)(b*2048) << 10) + (h << 6);
  const size_t vbase = ((size_t)(b*1024 + h*64)) << 11;

  const int sr = tid >> 2;            // staging row 0..63
  const int sc = (tid & 3) * 16;      // staging col (u16): 0,16,32,48
  const int wb0 = swz(sr*128 + (tid & 3)*32,      sr);
  const int wb1 = swz(sr*128 + (tid & 3)*32 + 16, sr);

  short8 kr0, kr1, vr0, vr1;
  auto issue = [&](int kv0){
    const u16* kg = kmat + kbase + ((size_t)(kv0 + sr) << 10) + sc;
    kr0 = *(const short8*)(kg);
    kr1 = *(const short8*)(kg + 8);
    const u16* vg = vT + vbase + ((size_t)sr << 11) + kv0 + sc;
    vr0 = *(const short8*)(vg);
    vr1 = *(const short8*)(vg + 8);
  };

  issue(0);
  for (int t = 0; t < 32; ++t){
    __syncthreads();                          // prev tile's compute done, LDS free
    *(short8*)((char*)Kl + wb0) = kr0;
    *(short8*)((char*)Kl + wb1) = kr1;
    *(short8*)((char*)Vl + wb0) = vr0;
    *(short8*)((char*)Vl + wb1) = vr1;
    __syncthreads();                          // K/V tile ready
    if (t < 31) issue((t+1)*64);              // in-flight across compute (T14)

    // QK^T swapped: sacc[n] = S^T[kv = n*16 + lg*4 + i][q = lr]
    f32x4 sacc[4] = {};
    __builtin_amdgcn_s_setprio(1);
    #pragma unroll
    for (int kt=0; kt<2; ++kt){
      const int cb = kt*64 + lg*16;           // byte col within row
      #pragma unroll
      for (int n=0;n<4;++n){
        const int row = n*16 + lr;
        short8 kf = *(const short8*)((char*)Kl + swz(row*128 + cb, row));
        sacc[n] = mfma16(kf, qf[kt], sacc[n]);
      }
    }
    __builtin_amdgcn_s_setprio(0);

    // online softmax, fully per-lane for q = lr (+2 shuffles across lg copies)
    float tmax = sacc[0][0];
    #pragma unroll
    for (int n=0;n<4;++n)
      #pragma unroll
      for (int i=0;i<4;++i) tmax = fmaxf(tmax, sacc[n][i]);
    tmax = fmaxf(tmax, __shfl_xor(tmax, 16, 64));
    tmax = fmaxf(tmax, __shfl_xor(tmax, 32, 64));

    if (__any(tmax > mrow + 8.0f)){           // T13 defer-max, THR=8
      const float mnew = fmaxf(mrow, tmax);
      const float corr = __expf(mrow - mnew);
      mrow = mnew;
      lrow *= corr;
      #pragma unroll
      for (int i=0;i<4;++i){
        const float cb_ = __shfl(corr, (lg<<2)|i, 64);   // corr for q=lg*4+i
        #pragma unroll
        for (int n=0;n<4;++n) oacc[n][i] *= cb_;
      }
    }

    float rs = 0.f;
    u16x4 pk[4];
    #pragma unroll
    for (int n=0;n<4;++n){
      #pragma unroll
      for (int i=0;i<4;++i){
        const float p = __expf(sacc[n][i] - mrow);
        rs += p;
        pk[n][i] = f2bf(p);
      }
    }
    rs += __shfl_xor(rs, 16, 64);
    rs += __shfl_xor(rs, 32, 64);
    lrow += rs;
    #pragma unroll
    for (int n=0;n<4;++n)
      *(u16x4*)((char*)&Pl[w][0] + swz(lr*128 + n*32 + lg*8, lr)) = pk[n];
    // Pl is wave-private: compiler-inserted lgkmcnt ordering suffices, no barrier.

    // PV: A = P row lr, B = V^T row n*16+lr(d), k = kv
    __builtin_amdgcn_s_setprio(1);
    #pragma unroll
    for (int kt=0;kt<2;++kt){
      const int cb = kt*64 + lg*16;
      short8 pf = *(const short8*)((char*)&Pl[w][0] + swz(lr*128 + cb, lr));
      #pragma unroll
      for (int n=0;n<4;++n){
        const int row = n*16 + lr;
        short8 vf = *(const short8*)((char*)Vl + swz(row*128 + cb, row));
        oacc[n] = mfma16(pf, vf, oacc[n]);
      }
    }
    __builtin_amdgcn_s_setprio(0);
  }

  const float linv = 1.0f / lrow;
  const size_t obase = ((size_t)(b*2048 + q0 + w*16 + lg*4) << 10) + (h<<6);
  #pragma unroll
  for (int i=0;i<4;++i){
    const float iv = __shfl(linv, (lg<<2)|i, 64);        // 1/l for q=lg*4+i
    #pragma unroll
    for (int n=0;n<4;++n)
      o[obase + ((size_t)i << 10) + n*16 + lr] = f2bf(oacc[n][i] * iv);
  }
}

// ---------------------------------------------------------------------------
extern "C" void kernel_launch(void* const* d_in, const int* in_sizes, int n_in,
                              void* d_out, int out_size, void* d_ws, size_t ws_size,
                              hipStream_t stream){
  const float* x      = (const float*)d_in[0];
  const float* norm_w = (const float*)d_in[1];
  const float* wq     = (const float*)d_in[2];
  const float* kvd    = (const float*)d_in[3];
  const float* wk     = (const float*)d_in[4];
  const float* wv     = (const float*)d_in[5];
  const float* wo     = (const float*)d_in[6];
  float* out = (float*)d_out;

  char* ws = (char*)d_ws;
  const size_t SZ = (size_t)8192*1024*2;       // 16 MB bf16 tensor
  u16* xn   = (u16*)(ws);
  u16* q    = (u16*)(ws + SZ);
  u16* kmat = (u16*)(ws + 2*SZ);
  u16* vT   = (u16*)(ws + 3*SZ);
  u16* attn = (u16*)(ws + 4*SZ);
  u16* kv   = (u16*)(ws + 5*SZ);               // 8 MB
  u16* wqT  = (u16*)(ws + 5*SZ + (size_t)8192*512*2);
  u16* kvdT = wqT  + 1024*1024;
  u16* wkT  = kvdT + 512*1024;
  u16* wvT  = wkT  + 1024*512;
  u16* woT  = wvT  + 1024*512;
  float2* cs = (float2*)(woT + 1024*1024);

  k_transpose<<<dim3(32,32), 256, 0, stream>>>(wq,  wqT,  1024, 1024);
  k_transpose<<<dim3(32,16), 256, 0, stream>>>(kvd, kvdT, 1024, 512);
  k_transpose<<<dim3(16,32), 256, 0, stream>>>(wk,  wkT,  512, 1024);
  k_transpose<<<dim3(16,32), 256, 0, stream>>>(wv,  wvT,  512, 1024);
  k_transpose<<<dim3(32,32), 256, 0, stream>>>(wo,  woT,  1024, 1024);

  k_rmsnorm<<<8192, 256, 0, stream>>>(x, norm_w, xn);
  k_cs<<<256, 256, 0, stream>>>(cs);

  k_gemm<0><<<dim3(8,64), 256, 0, stream>>>(xn, wqT,  q,    nullptr, nullptr, 1024, 1024);
  k_gemm<0><<<dim3(4,64), 256, 0, stream>>>(xn, kvdT, kv,   nullptr, nullptr, 512,  1024);
  k_gemm<0><<<dim3(8,64), 256, 0, stream>>>(kv, wkT,  kmat, nullptr, nullptr, 1024, 512);
  k_gemm<1><<<dim3(8,64), 256, 0, stream>>>(kv, wvT,  vT,   nullptr, nullptr, 1024, 512);

  // q additionally pre-scaled by softmax 1/sqrt(64) = 0.125 (exact in bf16)
  k_rope<<<16384, 256, 0, stream>>>(q,    cs, 0.125f);
  k_rope<<<16384, 256, 0, stream>>>(kmat, cs, 1.0f);

  k_attn<<<dim3(32,64), 256, 0, stream>>>(q, kmat, vT, attn);

  k_gemm<2><<<dim3(8,64), 256, 0, stream>>>(attn, woT, nullptr, out, x, 1024, 1024);
}

// Round 3
// 265.415 us; speedup vs baseline: 1.5123x; 1.0745x over previous
//
#include <hip/hip_runtime.h>

typedef unsigned short u16;
typedef unsigned int   u32;
typedef __attribute__((ext_vector_type(8))) __bf16 bf16x8;
typedef __attribute__((ext_vector_type(8))) short  short8;
typedef __attribute__((ext_vector_type(4))) float  f32x4;
typedef __attribute__((ext_vector_type(4))) u16    u16x4;

#define DEV static __device__ __forceinline__

// native bf16 convert (RTNE) -> compiler packs pairs into v_cvt_pk_bf16_f32
DEV u16 f2bf(float f){ return __builtin_bit_cast(u16, (__bf16)f); }

#if __has_builtin(__builtin_amdgcn_exp2f)
DEV float fexp2(float x){ return __builtin_amdgcn_exp2f(x); }
#else
DEV float fexp2(float x){ return exp2f(x); }
#endif

DEV f32x4 mfma16(short8 a, short8 b, f32x4 c){
  return __builtin_amdgcn_mfma_f32_16x16x32_bf16(
      __builtin_bit_cast(bf16x8, a), __builtin_bit_cast(bf16x8, b), c, 0, 0, 0);
}
// XOR swizzle for 128-byte-row LDS tiles (attn)
DEV int swz(int byteoff, int row){ return byteoff ^ ((row & 7) << 4); }

// async global->LDS, 16B per lane, LDS dest = wave-uniform base + lane*16
#if __has_builtin(__builtin_amdgcn_global_load_lds)
#define USE_GLL 1
typedef __attribute__((address_space(1))) const u32 gas_u32;
typedef __attribute__((address_space(3)))       u32 las_u32;
#define GL2L(g, l) __builtin_amdgcn_global_load_lds((gas_u32*)(g), (las_u32*)(l), 16, 0, 0)
#endif

// ---------------- weight transpose + bf16 cast + scale: W(K,N)f32 -> Wt(N,K)bf16
__global__ __launch_bounds__(256) void k_transpose(const float* __restrict__ W,
                                                   u16* __restrict__ Wt, int K, int N,
                                                   float scale){
  __shared__ float t[32][33];
  const int k0 = blockIdx.x*32, n0 = blockIdx.y*32;
  const int tx = threadIdx.x & 31, ty = threadIdx.x >> 5;
  #pragma unroll
  for (int j=0;j<4;++j) t[ty + j*8][tx] = W[(size_t)(k0+ty+j*8)*N + n0 + tx];
  __syncthreads();
  #pragma unroll
  for (int j=0;j<4;++j) Wt[(size_t)(n0+ty+j*8)*K + k0 + tx] = f2bf(t[tx][ty+j*8]*scale);
}

// ---------------- RMSNorm: x(8192,1024) f32 -> xn bf16 ----------------------
__global__ __launch_bounds__(256) void k_rmsnorm(const float* __restrict__ x,
                                                 const float* __restrict__ w,
                                                 u16* __restrict__ xn){
  const int row = blockIdx.x;
  const int t = threadIdx.x;
  const float4* xr = (const float4*)(x + (size_t)row*1024);
  float4 v = xr[t];
  float ss = v.x*v.x + v.y*v.y + v.z*v.z + v.w*v.w;
  #pragma unroll
  for (int off=32; off; off>>=1) ss += __shfl_xor(ss, off, 64);
  __shared__ float ps[4];
  if ((t & 63) == 0) ps[t>>6] = ss;
  __syncthreads();
  const float tot = ps[0]+ps[1]+ps[2]+ps[3];
  const float rinv = rsqrtf(tot * (1.0f/1024.0f) + 1e-6f);
  const float4* wr = (const float4*)w;
  float4 g = wr[t];
  u16x4 o;
  o.x = f2bf(v.x*rinv*g.x); o.y = f2bf(v.y*rinv*g.y);
  o.z = f2bf(v.z*rinv*g.z); o.w = f2bf(v.w*rinv*g.w);
  *(u16x4*)(xn + (size_t)row*1024 + t*4) = o;
}

// ---------------- RoPE cos/sin table: (2048, 32) float2 ----------------------
__global__ void k_cs(float2* __restrict__ cs){
  const int idx = blockIdx.x*256 + threadIdx.x;
  if (idx >= 2048*32) return;
  const int s = idx >> 5, j = idx & 31;
  const float ang = (float)s * expf(-(float)j * (9.210340371976184f/32.0f));
  cs[idx] = make_float2(cosf(ang), sinf(ang));
}

// ---------------- GEMM: A(M,K) bf16 rm x Bt(N,K) bf16 rm -> C(M,N) -----------
// MODE 0: bf16 store
// MODE 1: bf16 transposed store to vT[(b*1024 + n)*2048 + s]
// MODE 2: f32 store with residual add
// MODE 3: RoPE epilogue + bf16 store (wave's 64-col span == one head)
template<int MODE>
__global__ __launch_bounds__(256) void k_gemm(const u16* __restrict__ A,
                                              const u16* __restrict__ Bt,
                                              u16* __restrict__ Cb,
                                              float* __restrict__ Cf,
                                              const float* __restrict__ resid,
                                              const float2* __restrict__ cs,
                                              int N, int K){
  __shared__ __align__(16) u16 Al[128*64];
  __shared__ __align__(16) u16 Bl[128*64];
  const int tid = threadIdx.x, lane = tid & 63, w = tid >> 6;
  const int wm = (w >> 1) * 64, wn = (w & 1) * 64;
  const int m0 = blockIdx.y * 128, n0 = blockIdx.x * 128;
  const int lr = lane & 15, lg = lane >> 4;

  f32x4 acc[4][4] = {};

  const int lrow = lane >> 3;          // 0..7 (row within 8-row chunk)
  const int lcol = (lane & 7) * 8;     // u16 col 0..56

  for (int k0 = 0; k0 < K; k0 += 64) {
    __syncthreads();
#ifdef USE_GLL
    #pragma unroll
    for (int j=0;j<4;++j){
      const int c = w*4 + j;           // chunk 0..15 (8 rows x 64 u16 = 1KB)
      GL2L(A  + (size_t)(m0 + c*8 + lrow)*K + k0 + lcol, Al + c*512);
      GL2L(Bt + (size_t)(n0 + c*8 + lrow)*K + k0 + lcol, Bl + c*512);
    }
#else
    {
      const int srow = tid >> 1, scol = (tid & 1) * 32;
      const u16* Ag = A  + (size_t)(m0 + srow)*K + k0 + scol;
      const u16* Bg = Bt + (size_t)(n0 + srow)*K + k0 + scol;
      #pragma unroll
      for (int j=0;j<4;++j){
        *(short8*)(Al + srow*64 + scol + j*8) = *(const short8*)(Ag + j*8);
        *(short8*)(Bl + srow*64 + scol + j*8) = *(const short8*)(Bg + j*8);
      }
    }
#endif
    __syncthreads();
    #pragma unroll
    for (int kk=0; kk<2; ++kk){
      const int ko = kk*32 + lg*8;
      short8 af[4], bfr[4];
      #pragma unroll
      for (int m=0;m<4;++m) af[m]  = *(const short8*)(Al + (wm + m*16 + lr)*64 + ko);
      #pragma unroll
      for (int n=0;n<4;++n) bfr[n] = *(const short8*)(Bl + (wn + n*16 + lr)*64 + ko);
      #pragma unroll
      for (int m=0;m<4;++m)
        #pragma unroll
        for (int n=0;n<4;++n)
          acc[m][n] = mfma16(af[m], bfr[n], acc[m][n]);
    }
  }

  #pragma unroll
  for (int m=0;m<4;++m){
    const int rb = m0 + wm + m*16 + lg*4;
    if (MODE == 3){
      #pragma unroll
      for (int n=0;n<2;++n){
        const int c = n0 + wn + n*16 + lr;     // head dim j = n*16+lr in [0,32)
        const int j = n*16 + lr;
        #pragma unroll
        for (int i=0;i<4;++i){
          const float2 t = cs[(size_t)((rb+i) & 2047)*32 + j];
          const float t1 = acc[m][n][i], t2 = acc[m][n+2][i];
          Cb[(size_t)(rb+i)*N + c]      = f2bf(t1*t.x - t2*t.y);
          Cb[(size_t)(rb+i)*N + c + 32] = f2bf(t1*t.y + t2*t.x);
        }
      }
    } else {
      #pragma unroll
      for (int n=0;n<4;++n){
        const int c = n0 + wn + n*16 + lr;
        if (MODE == 0){
          #pragma unroll
          for (int i=0;i<4;++i) Cb[(size_t)(rb+i)*N + c] = f2bf(acc[m][n][i]);
        } else if (MODE == 1){
          const int b = rb >> 11, s = rb & 2047;
          u16x4 pk;
          pk.x = f2bf(acc[m][n][0]); pk.y = f2bf(acc[m][n][1]);
          pk.z = f2bf(acc[m][n][2]); pk.w = f2bf(acc[m][n][3]);
          *(u16x4*)(Cb + (((size_t)(b*1024 + c)) << 11) + s) = pk;
        } else if (MODE == 2){
          #pragma unroll
          for (int i=0;i<4;++i){
            const size_t off = (size_t)(rb+i)*N + c;
            Cf[off] = acc[m][n][i] + resid[off];
          }
        }
      }
    }
  }
}

// ---------------- flash attention (exp2-domain, dbuf LDS, 1 barrier/tile) ----
// q pre-scaled by 0.125*log2(e) via wqT. q,k: [b][s][h*64+hd]; vT: [(b*1024+d)][s]
// grid (S/64, B*H), 256 thr = 4 waves x 16 q-rows, KVBLK=64.
__global__ __launch_bounds__(256) void k_attn(const u16* __restrict__ q,
                                              const u16* __restrict__ kmat,
                                              const u16* __restrict__ vT,
                                              u16* __restrict__ o){
  __shared__ __align__(16) u16 Kl[2][64*64];
  __shared__ __align__(16) u16 Vl[2][64*64];
  __shared__ __align__(16) u16 Pl[4][16*64];
  const int tid = threadIdx.x, lane = tid & 63, w = tid >> 6;
  const int lr = lane & 15, lg = lane >> 4;
  const int bh = blockIdx.y, b = bh >> 4, h = bh & 15;
  const int q0 = blockIdx.x * 64;

  short8 qf[2];
  {
    const size_t base = ((size_t)(b*2048 + q0 + w*16 + lr) << 10) + (h<<6) + lg*8;
    qf[0] = *(const short8*)(q + base);
    qf[1] = *(const short8*)(q + base + 32);
  }
  f32x4 oacc[4] = {};
  float mrow = -1e30f, lrow = 0.f;     // per-lane: q = lr (dup across lg)

  const size_t kbase = ((size_t)(b*2048) << 10) + (h << 6);
  const size_t vbase = ((size_t)(b*1024 + h*64)) << 11;

  const int sr = tid >> 2;            // staging row 0..63
  const int sc = (tid & 3) * 16;      // staging col (u16)
  const int wb0 = swz(sr*128 + (tid & 3)*32,      sr);
  const int wb1 = swz(sr*128 + (tid & 3)*32 + 16, sr);

  short8 kr0, kr1, vr0, vr1;
  auto issue = [&](int kv0){
    const u16* kg = kmat + kbase + ((size_t)(kv0 + sr) << 10) + sc;
    kr0 = *(const short8*)(kg);
    kr1 = *(const short8*)(kg + 8);
    const u16* vg = vT + vbase + ((size_t)sr << 11) + kv0 + sc;
    vr0 = *(const short8*)(vg);
    vr1 = *(const short8*)(vg + 8);
  };

  issue(0);
  for (int t = 0; t < 32; ++t){
    u16* Kb = Kl[t & 1];
    u16* Vb = Vl[t & 1];
    // WAR-safe: barrier(t-1) guaranteed all waves finished compute(t-2) on this buf
    *(short8*)((char*)Kb + wb0) = kr0;
    *(short8*)((char*)Kb + wb1) = kr1;
    *(short8*)((char*)Vb + wb0) = vr0;
    *(short8*)((char*)Vb + wb1) = vr1;
    __syncthreads();
    if (t < 31) issue((t+1)*64);              // in-flight across compute (T14)

    // QK^T swapped: sacc[n] = S^T[kv = n*16 + lg*4 + i][q = lr]
    f32x4 sacc[4] = {};
    __builtin_amdgcn_s_setprio(1);
    #pragma unroll
    for (int kt=0; kt<2; ++kt){
      const int cb = kt*64 + lg*16;
      #pragma unroll
      for (int n=0;n<4;++n){
        const int row = n*16 + lr;
        short8 kf = *(const short8*)((char*)Kb + swz(row*128 + cb, row));
        sacc[n] = mfma16(kf, qf[kt], sacc[n]);
      }
    }
    __builtin_amdgcn_s_setprio(0);

    float tmax = sacc[0][0];
    #pragma unroll
    for (int n=0;n<4;++n)
      #pragma unroll
      for (int i=0;i<4;++i) tmax = fmaxf(tmax, sacc[n][i]);
    tmax = fmaxf(tmax, __shfl_xor(tmax, 16, 64));
    tmax = fmaxf(tmax, __shfl_xor(tmax, 32, 64));

    if (__any(tmax > mrow + 8.0f)){           // T13 defer-max (log2 domain)
      const float mnew = fmaxf(mrow, tmax);
      const float corr = fexp2(mrow - mnew);
      mrow = mnew;
      lrow *= corr;
      #pragma unroll
      for (int i=0;i<4;++i){
        const float cb_ = __shfl(corr, (lg<<2)|i, 64);
        #pragma unroll
        for (int n=0;n<4;++n) oacc[n][i] *= cb_;
      }
    }

    float rs = 0.f;
    u16x4 pk[4];
    #pragma unroll
    for (int n=0;n<4;++n){
      #pragma unroll
      for (int i=0;i<4;++i){
        const float p = fexp2(sacc[n][i] - mrow);
        rs += p;
        pk[n][i] = f2bf(p);
      }
    }
    rs += __shfl_xor(rs, 16, 64);
    rs += __shfl_xor(rs, 32, 64);
    lrow += rs;
    #pragma unroll
    for (int n=0;n<4;++n)
      *(u16x4*)((char*)&Pl[w][0] + swz(lr*128 + n*32 + lg*8, lr)) = pk[n];
    // Pl wave-private: lgkmcnt ordering suffices, no barrier

    __builtin_amdgcn_s_setprio(1);
    #pragma unroll
    for (int kt=0;kt<2;++kt){
      const int cb = kt*64 + lg*16;
      short8 pf = *(const short8*)((char*)&Pl[w][0] + swz(lr*128 + cb, lr));
      #pragma unroll
      for (int n=0;n<4;++n){
        const int row = n*16 + lr;
        short8 vf = *(const short8*)((char*)Vb + swz(row*128 + cb, row));
        oacc[n] = mfma16(pf, vf, oacc[n]);
      }
    }
    __builtin_amdgcn_s_setprio(0);
  }

  const float linv = 1.0f / lrow;
  const size_t obase = ((size_t)(b*2048 + q0 + w*16 + lg*4) << 10) + (h<<6);
  #pragma unroll
  for (int i=0;i<4;++i){
    const float iv = __shfl(linv, (lg<<2)|i, 64);
    #pragma unroll
    for (int n=0;n<4;++n)
      o[obase + ((size_t)i << 10) + n*16 + lr] = f2bf(oacc[n][i] * iv);
  }
}

// ---------------------------------------------------------------------------
extern "C" void kernel_launch(void* const* d_in, const int* in_sizes, int n_in,
                              void* d_out, int out_size, void* d_ws, size_t ws_size,
                              hipStream_t stream){
  const float* x      = (const float*)d_in[0];
  const float* norm_w = (const float*)d_in[1];
  const float* wq     = (const float*)d_in[2];
  const float* kvd    = (const float*)d_in[3];
  const float* wk     = (const float*)d_in[4];
  const float* wv     = (const float*)d_in[5];
  const float* wo     = (const float*)d_in[6];
  float* out = (float*)d_out;

  char* ws = (char*)d_ws;
  const size_t SZ = (size_t)8192*1024*2;       // 16 MB bf16 tensor
  u16* xn   = (u16*)(ws);
  u16* q    = (u16*)(ws + SZ);
  u16* kmat = (u16*)(ws + 2*SZ);
  u16* vT   = (u16*)(ws + 3*SZ);
  u16* attn = (u16*)(ws + 4*SZ);
  u16* kv   = (u16*)(ws + 5*SZ);               // 8 MB
  u16* wqT  = (u16*)(ws + 5*SZ + (size_t)8192*512*2);
  u16* kvdT = wqT  + 1024*1024;
  u16* wkT  = kvdT + 512*1024;
  u16* wvT  = wkT  + 1024*512;
  u16* woT  = wvT  + 1024*512;
  float2* cs = (float2*)(woT + 1024*1024);

  // q-weight carries softmax scale and log2(e) for exp2-domain softmax
  const float QSCALE = 0.125f * 1.4426950408889634f;
  k_transpose<<<dim3(32,32), 256, 0, stream>>>(wq,  wqT,  1024, 1024, QSCALE);
  k_transpose<<<dim3(32,16), 256, 0, stream>>>(kvd, kvdT, 1024, 512,  1.0f);
  k_transpose<<<dim3(16,32), 256, 0, stream>>>(wk,  wkT,  512, 1024,  1.0f);
  k_transpose<<<dim3(16,32), 256, 0, stream>>>(wv,  wvT,  512, 1024,  1.0f);
  k_transpose<<<dim3(32,32), 256, 0, stream>>>(wo,  woT,  1024, 1024, 1.0f);

  k_rmsnorm<<<8192, 256, 0, stream>>>(x, norm_w, xn);
  k_cs<<<256, 256, 0, stream>>>(cs);

  // q = rope(xn@wq*QSCALE); kv = xn@kvd; k = rope(kv@wk); vT = (kv@wv)^T
  k_gemm<3><<<dim3(8,64), 256, 0, stream>>>(xn, wqT,  q,    nullptr, nullptr, cs, 1024, 1024);
  k_gemm<0><<<dim3(4,64), 256, 0, stream>>>(xn, kvdT, kv,   nullptr, nullptr, nullptr, 512,  1024);
  k_gemm<3><<<dim3(8,64), 256, 0, stream>>>(kv, wkT,  kmat, nullptr, nullptr, cs, 1024, 512);
  k_gemm<1><<<dim3(8,64), 256, 0, stream>>>(kv, wvT,  vT,   nullptr, nullptr, nullptr, 1024, 512);

  k_attn<<<dim3(32,64), 256, 0, stream>>>(q, kmat, vT, attn);

  k_gemm<2><<<dim3(8,64), 256, 0, stream>>>(attn, woT, nullptr, out, x, nullptr, 1024, 1024);
}

// Round 4
// 245.119 us; speedup vs baseline: 1.6375x; 1.0828x over previous
//
#include <hip/hip_runtime.h>

typedef unsigned short u16;
typedef unsigned int   u32;
typedef __attribute__((ext_vector_type(8))) __bf16 bf16x8;
typedef __attribute__((ext_vector_type(8))) short  short8;
typedef __attribute__((ext_vector_type(4))) float  f32x4;
typedef __attribute__((ext_vector_type(4))) u16    u16x4;

#define DEV static __device__ __forceinline__

DEV u16 f2bf(float f){ return __builtin_bit_cast(u16, (__bf16)f); }

#if __has_builtin(__builtin_amdgcn_exp2f)
DEV float fexp2(float x){ return __builtin_amdgcn_exp2f(x); }
#else
DEV float fexp2(float x){ return exp2f(x); }
#endif

DEV f32x4 mfma16(short8 a, short8 b, f32x4 c){
  return __builtin_amdgcn_mfma_f32_16x16x32_bf16(
      __builtin_bit_cast(bf16x8, a), __builtin_bit_cast(bf16x8, b), c, 0, 0, 0);
}
// XOR swizzle for 128-byte-row LDS tiles
DEV int swz(int byteoff, int row){ return byteoff ^ ((row & 7) << 4); }

#if __has_builtin(__builtin_amdgcn_global_load_lds)
#define USE_GLL 1
typedef __attribute__((address_space(1))) const u32 gas_u32;
typedef __attribute__((address_space(3)))       u32 las_u32;
#define GL2L(g, l) __builtin_amdgcn_global_load_lds((gas_u32*)(g), (las_u32*)(l), 16, 0, 0)
#endif

// ---------------- prep: 5 weight transposes (+cast/scale) + RoPE cs table ----
// z=0..4: W(K,N) f32 -> Wt(N,K) bf16; z=5: cs table
__global__ __launch_bounds__(256) void k_prep(const float* __restrict__ wq,
                                              const float* __restrict__ kvd,
                                              const float* __restrict__ wk,
                                              const float* __restrict__ wv,
                                              const float* __restrict__ wo,
                                              u16* __restrict__ wqT, u16* __restrict__ kvdT,
                                              u16* __restrict__ wkT, u16* __restrict__ wvT,
                                              u16* __restrict__ woT, float2* __restrict__ cs,
                                              float qscale){
  const int z = blockIdx.z;
  if (z == 5){
    if (blockIdx.y >= 8) return;
    const int idx = (blockIdx.y*32 + blockIdx.x)*256 + threadIdx.x;   // 65536 total
    const int s = idx >> 5, j = idx & 31;
    const float ang = (float)s * expf(-(float)j * (9.210340371976184f/32.0f));
    cs[idx] = make_float2(cosf(ang), sinf(ang));
    return;
  }
  const float* W; u16* Wt; int K, N; float sc = 1.0f;
  switch (z){
    case 0: W = wq;  Wt = wqT;  K = 1024; N = 1024; sc = qscale; break;
    case 1: W = kvd; Wt = kvdT; K = 1024; N = 512;  break;
    case 2: W = wk;  Wt = wkT;  K = 512;  N = 1024; break;
    case 3: W = wv;  Wt = wvT;  K = 512;  N = 1024; break;
    default: W = wo; Wt = woT;  K = 1024; N = 1024; break;
  }
  const int k0 = blockIdx.x*32, n0 = blockIdx.y*32;
  if (k0 >= K || n0 >= N) return;
  __shared__ float t[32][33];
  const int tx = threadIdx.x & 31, ty = threadIdx.x >> 5;
  #pragma unroll
  for (int j=0;j<4;++j) t[ty + j*8][tx] = W[(size_t)(k0+ty+j*8)*N + n0 + tx];
  __syncthreads();
  #pragma unroll
  for (int j=0;j<4;++j) Wt[(size_t)(n0+ty+j*8)*K + k0 + tx] = f2bf(t[tx][ty+j*8]*sc);
}

// ---------------- RMSNorm: x(8192,1024) f32 -> xn bf16 ----------------------
__global__ __launch_bounds__(256) void k_rmsnorm(const float* __restrict__ x,
                                                 const float* __restrict__ w,
                                                 u16* __restrict__ xn){
  const int row = blockIdx.x;
  const int t = threadIdx.x;
  const float4* xr = (const float4*)(x + (size_t)row*1024);
  float4 v = xr[t];
  float ss = v.x*v.x + v.y*v.y + v.z*v.z + v.w*v.w;
  #pragma unroll
  for (int off=32; off; off>>=1) ss += __shfl_xor(ss, off, 64);
  __shared__ float ps[4];
  if ((t & 63) == 0) ps[t>>6] = ss;
  __syncthreads();
  const float tot = ps[0]+ps[1]+ps[2]+ps[3];
  const float rinv = rsqrtf(tot * (1.0f/1024.0f) + 1e-6f);
  const float4* wr = (const float4*)w;
  float4 g = wr[t];
  u16x4 o;
  o.x = f2bf(v.x*rinv*g.x); o.y = f2bf(v.y*rinv*g.y);
  o.z = f2bf(v.z*rinv*g.z); o.w = f2bf(v.w*rinv*g.w);
  *(u16x4*)(xn + (size_t)row*1024 + t*4) = o;
}

// ---------------- GEMM: A(M,K) bf16 rm x Bt(N,K) bf16 rm --------------------
// MODE 2: f32 out + residual (N=1024), Bt only.
// MODE 4: x<8: RoPE->Cb (N=1024); x>=8: plain bf16 -> Cb2 (N=512, B=Bt2)
// MODE 5: x<8: RoPE->Cb (N=1024); x>=8: vT store  -> Cb2 (B=Bt2)
template<int MODE>
__global__ __launch_bounds__(256) void k_gemm(const u16* __restrict__ A,
                                              const u16* __restrict__ Bt,
                                              const u16* __restrict__ Bt2,
                                              u16* __restrict__ Cb,
                                              u16* __restrict__ Cb2,
                                              float* __restrict__ Cf,
                                              const float* __restrict__ resid,
                                              const float2* __restrict__ cs,
                                              int K){
  __shared__ __align__(16) u16 Al[128*64];
  __shared__ __align__(16) u16 Bl[128*64];
  const int tid = threadIdx.x, lane = tid & 63, w = tid >> 6;
  const int wm = (w >> 1) * 64, wn = (w & 1) * 64;
  const bool second = (MODE != 2) && (blockIdx.x >= 8);
  const u16* B = second ? Bt2 : Bt;
  const int n0 = (second ? blockIdx.x - 8 : blockIdx.x) * 128;
  const int m0 = blockIdx.y * 128;
  const int lr = lane & 15, lg = lane >> 4;

  f32x4 acc[4][4] = {};

  const int lrow = lane >> 3;
  const int lcol = (lane & 7) * 8;

  for (int k0 = 0; k0 < K; k0 += 64) {
    __syncthreads();
#ifdef USE_GLL
    #pragma unroll
    for (int j=0;j<4;++j){
      const int c = w*4 + j;
      GL2L(A + (size_t)(m0 + c*8 + lrow)*K + k0 + lcol, Al + c*512);
      GL2L(B + (size_t)(n0 + c*8 + lrow)*K + k0 + lcol, Bl + c*512);
    }
#else
    {
      const int srow = tid >> 1, scol = (tid & 1) * 32;
      #pragma unroll
      for (int j=0;j<4;++j){
        *(short8*)(Al + srow*64 + scol + j*8) = *(const short8*)(A + (size_t)(m0+srow)*K + k0 + scol + j*8);
        *(short8*)(Bl + srow*64 + scol + j*8) = *(const short8*)(B + (size_t)(n0+srow)*K + k0 + scol + j*8);
      }
    }
#endif
    __syncthreads();
    #pragma unroll
    for (int kk=0; kk<2; ++kk){
      const int ko = kk*32 + lg*8;
      short8 af[4], bfr[4];
      #pragma unroll
      for (int m=0;m<4;++m) af[m]  = *(const short8*)(Al + (wm + m*16 + lr)*64 + ko);
      #pragma unroll
      for (int n=0;n<4;++n) bfr[n] = *(const short8*)(Bl + (wn + n*16 + lr)*64 + ko);
      #pragma unroll
      for (int m=0;m<4;++m)
        #pragma unroll
        for (int n=0;n<4;++n)
          acc[m][n] = mfma16(af[m], bfr[n], acc[m][n]);
    }
  }

  #pragma unroll
  for (int m=0;m<4;++m){
    const int rb = m0 + wm + m*16 + lg*4;
    if (MODE == 2){
      #pragma unroll
      for (int n=0;n<4;++n){
        const int c = n0 + wn + n*16 + lr;
        #pragma unroll
        for (int i=0;i<4;++i){
          const size_t off = (size_t)(rb+i)*1024 + c;
          Cf[off] = acc[m][n][i] + resid[off];
        }
      }
    } else if (!second){
      // RoPE epilogue: wave's 64-col span is one head; pair (n, n+2) = (j, j+32)
      #pragma unroll
      for (int n=0;n<2;++n){
        const int c = n0 + wn + n*16 + lr;
        const int j = n*16 + lr;
        #pragma unroll
        for (int i=0;i<4;++i){
          const float2 t = cs[(size_t)((rb+i) & 2047)*32 + j];
          const float t1 = acc[m][n][i], t2 = acc[m][n+2][i];
          Cb[(size_t)(rb+i)*1024 + c]      = f2bf(t1*t.x - t2*t.y);
          Cb[(size_t)(rb+i)*1024 + c + 32] = f2bf(t1*t.y + t2*t.x);
        }
      }
    } else if (MODE == 4){
      #pragma unroll
      for (int n=0;n<4;++n){
        const int c = n0 + wn + n*16 + lr;
        #pragma unroll
        for (int i=0;i<4;++i) Cb2[(size_t)(rb+i)*512 + c] = f2bf(acc[m][n][i]);
      }
    } else {
      #pragma unroll
      for (int n=0;n<4;++n){
        const int c = n0 + wn + n*16 + lr;
        const int b = rb >> 11, s = rb & 2047;
        u16x4 pk;
        pk.x = f2bf(acc[m][n][0]); pk.y = f2bf(acc[m][n][1]);
        pk.z = f2bf(acc[m][n][2]); pk.w = f2bf(acc[m][n][3]);
        *(u16x4*)(Cb2 + (((size_t)(b*1024 + c)) << 11) + s) = pk;
      }
    }
  }
}

// ---------------- flash attention: 8 waves x 32 q-rows, KVBLK=64 ------------
// q pre-scaled by 0.125*log2(e). q,k: [b][s][h*64+hd]; vT: [(b*1024+d)][s]
// GLL-staged K/V dbuf with pre-swizzled global source; P via LDS per wave.
__global__ __launch_bounds__(512, 2) void k_attn(const u16* __restrict__ q,
                                                 const u16* __restrict__ kmat,
                                                 const u16* __restrict__ vT,
                                                 u16* __restrict__ o){
  __shared__ __align__(16) u16 Kl[2][64*64];
  __shared__ __align__(16) u16 Vl[2][64*64];
  __shared__ __align__(16) u16 Pl[8][32*64];
  const int tid = threadIdx.x, lane = tid & 63, w = tid >> 6;   // w 0..7
  const int lr = lane & 15, lg = lane >> 4;
  const int bh = blockIdx.y, b = bh >> 4, h = bh & 15;
  const int q0 = blockIdx.x * 256;

  // Q fragments: group g covers q-rows q0 + w*32 + g*16 + lr
  short8 qf[2][2];
  #pragma unroll
  for (int g=0; g<2; ++g){
    const size_t base = ((size_t)(b*2048 + q0 + w*32 + g*16 + lr) << 10) + (h<<6) + lg*8;
    qf[g][0] = *(const short8*)(q + base);
    qf[g][1] = *(const short8*)(q + base + 32);
  }
  f32x4 oacc[2][4] = {};
  float mrow[2] = {-1e30f, -1e30f}, lrow[2] = {0.f, 0.f};

  // GLL staging: wave w owns K-chunk w and V-chunk w (8 rows x 128B = 1KB).
  // Pre-swizzled global col so linear LDS content == swizzled layout (m173).
  const int sr8  = lane >> 3;                 // row within chunk (== row&7)
  const int colq = (lane & 7) ^ sr8;          // 16B col, pre-swizzled
  const u16* kg0 = kmat + ((size_t)(b*2048 + w*8 + sr8) << 10) + (h<<6) + colq*8;
  const u16* vg0 = vT + (((size_t)(b*1024 + h*64 + w*8 + sr8)) << 11) + colq*8;
  u16* const Kdst[2] = { Kl[0] + w*512, Kl[1] + w*512 };
  u16* const Vdst[2] = { Vl[0] + w*512, Vl[1] + w*512 };

#ifdef USE_GLL
  #define STAGE(t_) { const int buf_=(t_)&1; const int kv0_=(t_)*64; \
      GL2L(kg0 + ((size_t)kv0_ << 10), Kdst[buf_]); \
      GL2L(vg0 + kv0_,                 Vdst[buf_]); }
#else
  #define STAGE(t_) { const int buf_=(t_)&1; const int kv0_=(t_)*64; \
      *(short8*)(Kdst[buf_] + lane*8) = *(const short8*)(kg0 + ((size_t)kv0_ << 10)); \
      *(short8*)(Vdst[buf_] + lane*8) = *(const short8*)(vg0 + kv0_); }
#endif

  STAGE(0);
  for (int t = 0; t < 32; ++t){
    const u16* Kb = Kl[t & 1];
    const u16* Vb = Vl[t & 1];
    __syncthreads();                   // drains GLL(t); protects buf^1 reuse
    if (t < 31) STAGE(t+1);            // in flight under compute(t)

    f32x4 sacc[2][4] = {};
    __builtin_amdgcn_s_setprio(1);
    #pragma unroll
    for (int kt=0; kt<2; ++kt){
      const int cb = kt*64 + lg*16;
      #pragma unroll
      for (int n=0;n<4;++n){
        const int row = n*16 + lr;
        short8 kf = *(const short8*)((const char*)Kb + swz(row*128 + cb, row));
        sacc[0][n] = mfma16(kf, qf[0][kt], sacc[0][n]);
        sacc[1][n] = mfma16(kf, qf[1][kt], sacc[1][n]);
      }
    }
    __builtin_amdgcn_s_setprio(0);

    float tmax[2];
    #pragma unroll
    for (int g=0; g<2; ++g){
      float tm = sacc[g][0][0];
      #pragma unroll
      for (int n=0;n<4;++n)
        #pragma unroll
        for (int i=0;i<4;++i) tm = fmaxf(tm, sacc[g][n][i]);
      tm = fmaxf(tm, __shfl_xor(tm, 16, 64));
      tm = fmaxf(tm, __shfl_xor(tm, 32, 64));
      tmax[g] = tm;
    }
    if (__any(fmaxf(tmax[0]-mrow[0], tmax[1]-mrow[1]) > 8.0f)){   // T13 defer
      #pragma unroll
      for (int g=0; g<2; ++g){
        const float mnew = fmaxf(mrow[g], tmax[g]);
        const float corr = fexp2(mrow[g] - mnew);
        mrow[g] = mnew;
        lrow[g] *= corr;
        #pragma unroll
        for (int i=0;i<4;++i){
          const float cb_ = __shfl(corr, (lg<<2)|i, 64);
          #pragma unroll
          for (int n=0;n<4;++n) oacc[g][n][i] *= cb_;
        }
      }
    }
    #pragma unroll
    for (int g=0; g<2; ++g){
      float rs = 0.f;
      u16x4 pk[4];
      #pragma unroll
      for (int n=0;n<4;++n){
        #pragma unroll
        for (int i=0;i<4;++i){
          const float p = fexp2(sacc[g][n][i] - mrow[g]);
          rs += p;
          pk[n][i] = f2bf(p);
        }
      }
      rs += __shfl_xor(rs, 16, 64);
      rs += __shfl_xor(rs, 32, 64);
      lrow[g] += rs;
      const int prow = g*16 + lr;
      #pragma unroll
      for (int n=0;n<4;++n)
        *(u16x4*)((char*)Pl[w] + swz(prow*128 + n*32 + lg*8, prow)) = pk[n];
    }
    // Pl wave-private: lgkmcnt ordering suffices, no barrier

    __builtin_amdgcn_s_setprio(1);
    #pragma unroll
    for (int kt=0; kt<2; ++kt){
      const int cb = kt*64 + lg*16;
      short8 pf0 = *(const short8*)((char*)Pl[w] + swz(lr*128 + cb, lr));
      short8 pf1 = *(const short8*)((char*)Pl[w] + swz((16+lr)*128 + cb, 16+lr));
      #pragma unroll
      for (int n=0;n<4;++n){
        const int row = n*16 + lr;
        short8 vf = *(const short8*)((const char*)Vb + swz(row*128 + cb, row));
        oacc[0][n] = mfma16(pf0, vf, oacc[0][n]);
        oacc[1][n] = mfma16(pf1, vf, oacc[1][n]);
      }
    }
    __builtin_amdgcn_s_setprio(0);
  }

  #pragma unroll
  for (int g=0; g<2; ++g){
    const float linv = 1.0f / lrow[g];
    const size_t obase = ((size_t)(b*2048 + q0 + w*32 + g*16 + lg*4) << 10) + (h<<6);
    #pragma unroll
    for (int i=0;i<4;++i){
      const float iv = __shfl(linv, (lg<<2)|i, 64);
      #pragma unroll
      for (int n=0;n<4;++n)
        o[obase + ((size_t)i << 10) + n*16 + lr] = f2bf(oacc[g][n][i] * iv);
    }
  }
  #undef STAGE
}

// ---------------------------------------------------------------------------
extern "C" void kernel_launch(void* const* d_in, const int* in_sizes, int n_in,
                              void* d_out, int out_size, void* d_ws, size_t ws_size,
                              hipStream_t stream){
  const float* x      = (const float*)d_in[0];
  const float* norm_w = (const float*)d_in[1];
  const float* wq     = (const float*)d_in[2];
  const float* kvd    = (const float*)d_in[3];
  const float* wk     = (const float*)d_in[4];
  const float* wv     = (const float*)d_in[5];
  const float* wo     = (const float*)d_in[6];
  float* out = (float*)d_out;

  char* ws = (char*)d_ws;
  const size_t SZ = (size_t)8192*1024*2;       // 16 MB bf16 tensor
  u16* xn   = (u16*)(ws);
  u16* q    = (u16*)(ws + SZ);
  u16* kmat = (u16*)(ws + 2*SZ);
  u16* vT   = (u16*)(ws + 3*SZ);
  u16* attn = (u16*)(ws + 4*SZ);
  u16* kv   = (u16*)(ws + 5*SZ);               // 8 MB
  u16* wqT  = (u16*)(ws + 5*SZ + (size_t)8192*512*2);
  u16* kvdT = wqT  + 1024*1024;
  u16* wkT  = kvdT + 512*1024;
  u16* wvT  = wkT  + 1024*512;
  u16* woT  = wvT  + 1024*512;
  float2* cs = (float2*)(woT + 1024*1024);

  const float QSCALE = 0.125f * 1.4426950408889634f;   // softmax scale * log2(e)

  k_prep<<<dim3(32,32,6), 256, 0, stream>>>(wq, kvd, wk, wv, wo,
                                            wqT, kvdT, wkT, wvT, woT, cs, QSCALE);
  k_rmsnorm<<<8192, 256, 0, stream>>>(x, norm_w, xn);

  // q = rope(xn@wq*QSCALE) | kv = xn@kvd        (fused, shared A)
  k_gemm<4><<<dim3(12,64), 256, 0, stream>>>(xn, wqT, kvdT, q, kv, nullptr, nullptr, cs, 1024);
  // kmat = rope(kv@wk) | vT = (kv@wv)^T         (fused, shared A)
  k_gemm<5><<<dim3(16,64), 256, 0, stream>>>(kv, wkT, wvT, kmat, vT, nullptr, nullptr, cs, 512);

  k_attn<<<dim3(8,64), 512, 0, stream>>>(q, kmat, vT, attn);

  // out = attn @ wo + x
  k_gemm<2><<<dim3(8,64), 256, 0, stream>>>(attn, woT, nullptr, nullptr, nullptr, out, x, nullptr, 1024);
}

// Round 5
// 219.396 us; speedup vs baseline: 1.8295x; 1.1172x over previous
//
#include <hip/hip_runtime.h>

typedef unsigned short u16;
typedef unsigned int   u32;
typedef __attribute__((ext_vector_type(8))) __bf16 bf16x8;
typedef __attribute__((ext_vector_type(8))) short  short8;
typedef __attribute__((ext_vector_type(4))) float  f32x4;
typedef __attribute__((ext_vector_type(4))) u16    u16x4;

#define DEV static __device__ __forceinline__

DEV u16 f2bf(float f){ return __builtin_bit_cast(u16, (__bf16)f); }

#if __has_builtin(__builtin_amdgcn_exp2f)
DEV float fexp2(float x){ return __builtin_amdgcn_exp2f(x); }
#else
DEV float fexp2(float x){ return exp2f(x); }
#endif

DEV f32x4 mfma16(short8 a, short8 b, f32x4 c){
  return __builtin_amdgcn_mfma_f32_16x16x32_bf16(
      __builtin_bit_cast(bf16x8, a), __builtin_bit_cast(bf16x8, b), c, 0, 0, 0);
}
// XOR swizzle for 128-byte-row LDS tiles
DEV int swz(int byteoff, int row){ return byteoff ^ ((row & 7) << 4); }

#if __has_builtin(__builtin_amdgcn_global_load_lds)
#define USE_GLL 1
typedef __attribute__((address_space(1))) const u32 gas_u32;
typedef __attribute__((address_space(3)))       u32 las_u32;
#define GL2L(g, l) __builtin_amdgcn_global_load_lds((gas_u32*)(g), (las_u32*)(l), 16, 0, 0)
#define LSWZ(boff, r) swz(boff, r)
#else
#define LSWZ(boff, r) (boff)
#endif

// ---------------- prep: 5 weight transposes + cs table + RMSNorm -------------
// z=0..4: W(K,N) f32 -> Wt(N,K) bf16; z=5: cs table; z=6: RMSNorm (8 rows/blk)
__global__ __launch_bounds__(256) void k_prep(const float* __restrict__ wq,
                                              const float* __restrict__ kvd,
                                              const float* __restrict__ wk,
                                              const float* __restrict__ wv,
                                              const float* __restrict__ wo,
                                              const float* __restrict__ x,
                                              const float* __restrict__ norm_w,
                                              u16* __restrict__ wqT, u16* __restrict__ kvdT,
                                              u16* __restrict__ wkT, u16* __restrict__ wvT,
                                              u16* __restrict__ woT, u16* __restrict__ xn,
                                              float2* __restrict__ cs, float qscale){
  const int z = blockIdx.z;
  if (z == 6){
    // RMSNorm: 1024 blocks x 8 rows
    const int bid = blockIdx.y*32 + blockIdx.x;
    const int t = threadIdx.x;
    __shared__ float ps[4];
    const float4 g = ((const float4*)norm_w)[t];
    #pragma unroll 1
    for (int it = 0; it < 8; ++it){
      const int row = bid*8 + it;
      const float4 v = ((const float4*)(x + (size_t)row*1024))[t];
      float ss = v.x*v.x + v.y*v.y + v.z*v.z + v.w*v.w;
      #pragma unroll
      for (int off=32; off; off>>=1) ss += __shfl_xor(ss, off, 64);
      if ((t & 63) == 0) ps[t>>6] = ss;
      __syncthreads();
      const float tot = ps[0]+ps[1]+ps[2]+ps[3];
      const float rinv = rsqrtf(tot * (1.0f/1024.0f) + 1e-6f);
      u16x4 o;
      o.x = f2bf(v.x*rinv*g.x); o.y = f2bf(v.y*rinv*g.y);
      o.z = f2bf(v.z*rinv*g.z); o.w = f2bf(v.w*rinv*g.w);
      *(u16x4*)(xn + (size_t)row*1024 + t*4) = o;
      __syncthreads();
    }
    return;
  }
  if (z == 5){
    if (blockIdx.y >= 8) return;
    const int idx = (blockIdx.y*32 + blockIdx.x)*256 + threadIdx.x;   // 65536 total
    const int s = idx >> 5, j = idx & 31;
    const float ang = (float)s * expf(-(float)j * (9.210340371976184f/32.0f));
    cs[idx] = make_float2(cosf(ang), sinf(ang));
    return;
  }
  const float* W; u16* Wt; int K, N; float sc = 1.0f;
  switch (z){
    case 0: W = wq;  Wt = wqT;  K = 1024; N = 1024; sc = qscale; break;
    case 1: W = kvd; Wt = kvdT; K = 1024; N = 512;  break;
    case 2: W = wk;  Wt = wkT;  K = 512;  N = 1024; break;
    case 3: W = wv;  Wt = wvT;  K = 512;  N = 1024; break;
    default: W = wo; Wt = woT;  K = 1024; N = 1024; break;
  }
  const int k0 = blockIdx.x*32, n0 = blockIdx.y*32;
  if (k0 >= K || n0 >= N) return;
  __shared__ float t[32][33];
  const int tx = threadIdx.x & 31, ty = threadIdx.x >> 5;
  #pragma unroll
  for (int j=0;j<4;++j) t[ty + j*8][tx] = W[(size_t)(k0+ty+j*8)*N + n0 + tx];
  __syncthreads();
  #pragma unroll
  for (int j=0;j<4;++j) Wt[(size_t)(n0+ty+j*8)*K + k0 + tx] = f2bf(t[tx][ty+j*8]*sc);
}

// ---------------- GEMM: A(M,K) bf16 rm x Bt(N,K) bf16 rm --------------------
// 2-phase pipeline: dbuf LDS, STAGE(t+1) issued after barrier, swizzled layout.
// MODE 2: f32 out + residual (N=1024), Bt only.
// MODE 4: x<8: RoPE->Cb (N=1024); x>=8: plain bf16 -> Cb2 (N=512, B=Bt2)
// MODE 5: x<8: RoPE->Cb (N=1024); x>=8: vT store  -> Cb2 (B=Bt2)
template<int MODE>
__global__ __launch_bounds__(256) void k_gemm(const u16* __restrict__ A,
                                              const u16* __restrict__ Bt,
                                              const u16* __restrict__ Bt2,
                                              u16* __restrict__ Cb,
                                              u16* __restrict__ Cb2,
                                              float* __restrict__ Cf,
                                              const float* __restrict__ resid,
                                              const float2* __restrict__ cs,
                                              int K){
  __shared__ __align__(16) u16 Al[2][128*64];
  __shared__ __align__(16) u16 Bl[2][128*64];
  const int tid = threadIdx.x, lane = tid & 63, w = tid >> 6;
  const int wm = (w >> 1) * 64, wn = (w & 1) * 64;
  const bool second = (MODE != 2) && (blockIdx.x >= 8);
  const u16* B = second ? Bt2 : Bt;
  const int n0 = (second ? blockIdx.x - 8 : blockIdx.x) * 128;
  const int m0 = blockIdx.y * 128;
  const int lr = lane & 15, lg = lane >> 4;
  const int nt = K >> 6;

  f32x4 acc[4][4] = {};

#ifdef USE_GLL
  // staging: wave w owns chunks w*4+j (8 rows x 128B each); lane: row lane>>3,
  // 16B slot lane&7, global col pre-swizzled so linear GLL dest == swizzled LDS
  const int rin  = lane >> 3;
  const int colq = (lane & 7) ^ rin;
  auto stage = [&](int t_){
    u16* Ad = &Al[t_ & 1][0];
    u16* Bd = &Bl[t_ & 1][0];
    const int kb = t_ << 6;
    #pragma unroll
    for (int j=0;j<4;++j){
      const int c = w*4 + j;
      GL2L(A + (size_t)(m0 + c*8 + rin)*K + kb + colq*8, Ad + c*512);
      GL2L(B + (size_t)(n0 + c*8 + rin)*K + kb + colq*8, Bd + c*512);
    }
  };
#else
  auto stage = [&](int t_){
    u16* Ad = &Al[t_ & 1][0];
    u16* Bd = &Bl[t_ & 1][0];
    const int kb = t_ << 6;
    const int srow = tid >> 1, scol = (tid & 1) * 32;
    #pragma unroll
    for (int j=0;j<4;++j){
      *(short8*)(Ad + srow*64 + scol + j*8) = *(const short8*)(A + (size_t)(m0+srow)*K + kb + scol + j*8);
      *(short8*)(Bd + srow*64 + scol + j*8) = *(const short8*)(B + (size_t)(n0+srow)*K + kb + scol + j*8);
    }
  };
#endif

  stage(0);
  for (int t = 0; t < nt; ++t){
    __syncthreads();                 // drains own GLL(t) (vmcnt 0) + rendezvous
    if (t + 1 < nt) stage(t + 1);    // in flight under compute(t)
    const u16* Ab = &Al[t & 1][0];
    const u16* Bb = &Bl[t & 1][0];
    #pragma unroll
    for (int kk=0; kk<2; ++kk){
      const int cb = kk*64 + lg*16;  // byte col
      short8 af[4], bfr[4];
      #pragma unroll
      for (int m=0;m<4;++m){
        const int r = wm + m*16 + lr;
        af[m] = *(const short8*)((const char*)Ab + LSWZ(r*128 + cb, r));
      }
      #pragma unroll
      for (int n=0;n<4;++n){
        const int r = wn + n*16 + lr;
        bfr[n] = *(const short8*)((const char*)Bb + LSWZ(r*128 + cb, r));
      }
      #pragma unroll
      for (int m=0;m<4;++m)
        #pragma unroll
        for (int n=0;n<4;++n)
          acc[m][n] = mfma16(af[m], bfr[n], acc[m][n]);
    }
  }

  #pragma unroll
  for (int m=0;m<4;++m){
    const int rb = m0 + wm + m*16 + lg*4;
    if (MODE == 2){
      #pragma unroll
      for (int n=0;n<4;++n){
        const int c = n0 + wn + n*16 + lr;
        #pragma unroll
        for (int i=0;i<4;++i){
          const size_t off = (size_t)(rb+i)*1024 + c;
          Cf[off] = acc[m][n][i] + resid[off];
        }
      }
    } else if (!second){
      // RoPE epilogue: wave's 64-col span is one head; pair (n, n+2) = (j, j+32)
      #pragma unroll
      for (int n=0;n<2;++n){
        const int c = n0 + wn + n*16 + lr;
        const int j = n*16 + lr;
        #pragma unroll
        for (int i=0;i<4;++i){
          const float2 t = cs[(size_t)((rb+i) & 2047)*32 + j];
          const float t1 = acc[m][n][i], t2 = acc[m][n+2][i];
          Cb[(size_t)(rb+i)*1024 + c]      = f2bf(t1*t.x - t2*t.y);
          Cb[(size_t)(rb+i)*1024 + c + 32] = f2bf(t1*t.y + t2*t.x);
        }
      }
    } else if (MODE == 4){
      #pragma unroll
      for (int n=0;n<4;++n){
        const int c = n0 + wn + n*16 + lr;
        #pragma unroll
        for (int i=0;i<4;++i) Cb2[(size_t)(rb+i)*512 + c] = f2bf(acc[m][n][i]);
      }
    } else {
      #pragma unroll
      for (int n=0;n<4;++n){
        const int c = n0 + wn + n*16 + lr;
        const int b = rb >> 11, s = rb & 2047;
        u16x4 pk;
        pk.x = f2bf(acc[m][n][0]); pk.y = f2bf(acc[m][n][1]);
        pk.z = f2bf(acc[m][n][2]); pk.w = f2bf(acc[m][n][3]);
        *(u16x4*)(Cb2 + (((size_t)(b*1024 + c)) << 11) + s) = pk;
      }
    }
  }
}

// ---------------- flash attention: 8 waves x 32 q-rows, KVBLK=64 ------------
// q pre-scaled by 0.125*log2(e). q,k: [b][s][h*64+hd]; vT: [(b*1024+d)][s]
// GLL-staged K/V dbuf with pre-swizzled global source; P via LDS per wave.
__global__ __launch_bounds__(512, 2) void k_attn(const u16* __restrict__ q,
                                                 const u16* __restrict__ kmat,
                                                 const u16* __restrict__ vT,
                                                 u16* __restrict__ o){
  __shared__ __align__(16) u16 Kl[2][64*64];
  __shared__ __align__(16) u16 Vl[2][64*64];
  __shared__ __align__(16) u16 Pl[8][32*64];
  const int tid = threadIdx.x, lane = tid & 63, w = tid >> 6;   // w 0..7
  const int lr = lane & 15, lg = lane >> 4;
  const int bh = blockIdx.y, b = bh >> 4, h = bh & 15;
  const int q0 = blockIdx.x * 256;

  // Q fragments: group g covers q-rows q0 + w*32 + g*16 + lr
  short8 qf[2][2];
  #pragma unroll
  for (int g=0; g<2; ++g){
    const size_t base = ((size_t)(b*2048 + q0 + w*32 + g*16 + lr) << 10) + (h<<6) + lg*8;
    qf[g][0] = *(const short8*)(q + base);
    qf[g][1] = *(const short8*)(q + base + 32);
  }
  f32x4 oacc[2][4] = {};
  float mrow[2] = {-1e30f, -1e30f}, lrow[2] = {0.f, 0.f};

  // GLL staging: wave w owns K-chunk w and V-chunk w (8 rows x 128B = 1KB).
  const int sr8  = lane >> 3;
  const int colq = (lane & 7) ^ sr8;          // pre-swizzled 16B col
  const u16* kg0 = kmat + ((size_t)(b*2048 + w*8 + sr8) << 10) + (h<<6) + colq*8;
  const u16* vg0 = vT + (((size_t)(b*1024 + h*64 + w*8 + sr8)) << 11) + colq*8;
  u16* const Kdst[2] = { Kl[0] + w*512, Kl[1] + w*512 };
  u16* const Vdst[2] = { Vl[0] + w*512, Vl[1] + w*512 };

#ifdef USE_GLL
  #define STAGE(t_) { const int buf_=(t_)&1; const int kv0_=(t_)*64; \
      GL2L(kg0 + ((size_t)kv0_ << 10), Kdst[buf_]); \
      GL2L(vg0 + kv0_,                 Vdst[buf_]); }
#else
  #define STAGE(t_) { const int buf_=(t_)&1; const int kv0_=(t_)*64; \
      *(short8*)(Kdst[buf_] + lane*8) = *(const short8*)(kg0 + ((size_t)kv0_ << 10)); \
      *(short8*)(Vdst[buf_] + lane*8) = *(const short8*)(vg0 + kv0_); }
#endif

  STAGE(0);
  for (int t = 0; t < 32; ++t){
    const u16* Kb = Kl[t & 1];
    const u16* Vb = Vl[t & 1];
    __syncthreads();                   // drains GLL(t); protects buf^1 reuse
    if (t < 31) STAGE(t+1);            // in flight under compute(t)

    f32x4 sacc[2][4] = {};
    __builtin_amdgcn_s_setprio(1);
    #pragma unroll
    for (int kt=0; kt<2; ++kt){
      const int cb = kt*64 + lg*16;
      #pragma unroll
      for (int n=0;n<4;++n){
        const int row = n*16 + lr;
        short8 kf = *(const short8*)((const char*)Kb + swz(row*128 + cb, row));
        sacc[0][n] = mfma16(kf, qf[0][kt], sacc[0][n]);
        sacc[1][n] = mfma16(kf, qf[1][kt], sacc[1][n]);
      }
    }
    __builtin_amdgcn_s_setprio(0);

    float tmax[2];
    #pragma unroll
    for (int g=0; g<2; ++g){
      float tm = sacc[g][0][0];
      #pragma unroll
      for (int n=0;n<4;++n)
        #pragma unroll
        for (int i=0;i<4;++i) tm = fmaxf(tm, sacc[g][n][i]);
      tm = fmaxf(tm, __shfl_xor(tm, 16, 64));
      tm = fmaxf(tm, __shfl_xor(tm, 32, 64));
      tmax[g] = tm;
    }
    if (__any(fmaxf(tmax[0]-mrow[0], tmax[1]-mrow[1]) > 8.0f)){   // T13 defer
      #pragma unroll
      for (int g=0; g<2; ++g){
        const float mnew = fmaxf(mrow[g], tmax[g]);
        const float corr = fexp2(mrow[g] - mnew);
        mrow[g] = mnew;
        lrow[g] *= corr;
        #pragma unroll
        for (int i=0;i<4;++i){
          const float cb_ = __shfl(corr, (lg<<2)|i, 64);
          #pragma unroll
          for (int n=0;n<4;++n) oacc[g][n][i] *= cb_;
        }
      }
    }
    #pragma unroll
    for (int g=0; g<2; ++g){
      float rs = 0.f;
      u16x4 pk[4];
      #pragma unroll
      for (int n=0;n<4;++n){
        #pragma unroll
        for (int i=0;i<4;++i){
          const float p = fexp2(sacc[g][n][i] - mrow[g]);
          rs += p;
          pk[n][i] = f2bf(p);
        }
      }
      rs += __shfl_xor(rs, 16, 64);
      rs += __shfl_xor(rs, 32, 64);
      lrow[g] += rs;
      const int prow = g*16 + lr;
      #pragma unroll
      for (int n=0;n<4;++n)
        *(u16x4*)((char*)Pl[w] + swz(prow*128 + n*32 + lg*8, prow)) = pk[n];
    }
    // Pl wave-private: lgkmcnt ordering suffices, no barrier

    __builtin_amdgcn_s_setprio(1);
    #pragma unroll
    for (int kt=0; kt<2; ++kt){
      const int cb = kt*64 + lg*16;
      short8 pf0 = *(const short8*)((char*)Pl[w] + swz(lr*128 + cb, lr));
      short8 pf1 = *(const short8*)((char*)Pl[w] + swz((16+lr)*128 + cb, 16+lr));
      #pragma unroll
      for (int n=0;n<4;++n){
        const int row = n*16 + lr;
        short8 vf = *(const short8*)((const char*)Vb + swz(row*128 + cb, row));
        oacc[0][n] = mfma16(pf0, vf, oacc[0][n]);
        oacc[1][n] = mfma16(pf1, vf, oacc[1][n]);
      }
    }
    __builtin_amdgcn_s_setprio(0);
  }

  #pragma unroll
  for (int g=0; g<2; ++g){
    const float linv = 1.0f / lrow[g];
    const size_t obase = ((size_t)(b*2048 + q0 + w*32 + g*16 + lg*4) << 10) + (h<<6);
    #pragma unroll
    for (int i=0;i<4;++i){
      const float iv = __shfl(linv, (lg<<2)|i, 64);
      #pragma unroll
      for (int n=0;n<4;++n)
        o[obase + ((size_t)i << 10) + n*16 + lr] = f2bf(oacc[g][n][i] * iv);
    }
  }
  #undef STAGE
}

// ---------------------------------------------------------------------------
extern "C" void kernel_launch(void* const* d_in, const int* in_sizes, int n_in,
                              void* d_out, int out_size, void* d_ws, size_t ws_size,
                              hipStream_t stream){
  const float* x      = (const float*)d_in[0];
  const float* norm_w = (const float*)d_in[1];
  const float* wq     = (const float*)d_in[2];
  const float* kvd    = (const float*)d_in[3];
  const float* wk     = (const float*)d_in[4];
  const float* wv     = (const float*)d_in[5];
  const float* wo     = (const float*)d_in[6];
  float* out = (float*)d_out;

  char* ws = (char*)d_ws;
  const size_t SZ = (size_t)8192*1024*2;       // 16 MB bf16 tensor
  u16* xn   = (u16*)(ws);
  u16* q    = (u16*)(ws + SZ);
  u16* kmat = (u16*)(ws + 2*SZ);
  u16* vT   = (u16*)(ws + 3*SZ);
  u16* attn = (u16*)(ws + 4*SZ);
  u16* kv   = (u16*)(ws + 5*SZ);               // 8 MB
  u16* wqT  = (u16*)(ws + 5*SZ + (size_t)8192*512*2);
  u16* kvdT = wqT  + 1024*1024;
  u16* wkT  = kvdT + 512*1024;
  u16* wvT  = wkT  + 1024*512;
  u16* woT  = wvT  + 1024*512;
  float2* cs = (float2*)(woT + 1024*1024);

  const float QSCALE = 0.125f * 1.4426950408889634f;   // softmax scale * log2(e)

  // prep: weights (z=0..4) + cs (z=5) + rmsnorm (z=6)
  k_prep<<<dim3(32,32,7), 256, 0, stream>>>(wq, kvd, wk, wv, wo, x, norm_w,
                                            wqT, kvdT, wkT, wvT, woT, xn, cs, QSCALE);

  // q = rope(xn@wq*QSCALE) | kv = xn@kvd        (fused, shared A)
  k_gemm<4><<<dim3(12,64), 256, 0, stream>>>(xn, wqT, kvdT, q, kv, nullptr, nullptr, cs, 1024);
  // kmat = rope(kv@wk) | vT = (kv@wv)^T         (fused, shared A)
  k_gemm<5><<<dim3(16,64), 256, 0, stream>>>(kv, wkT, wvT, kmat, vT, nullptr, nullptr, cs, 512);

  k_attn<<<dim3(8,64), 512, 0, stream>>>(q, kmat, vT, attn);

  // out = attn @ wo + x
  k_gemm<2><<<dim3(8,64), 256, 0, stream>>>(attn, woT, nullptr, nullptr, nullptr, out, x, nullptr, 1024);
}

// Round 7
// 208.016 us; speedup vs baseline: 1.9296x; 1.0547x over previous
//
#include <hip/hip_runtime.h>

typedef unsigned short u16;
typedef unsigned int   u32;
typedef __attribute__((ext_vector_type(8)))  __bf16 bf16x8;
typedef __attribute__((ext_vector_type(8)))  short  short8;
typedef __attribute__((ext_vector_type(4)))  float  f32x4;
typedef __attribute__((ext_vector_type(16))) float  f32x16;
typedef __attribute__((ext_vector_type(4)))  u16    u16x4;
typedef __attribute__((ext_vector_type(4)))  u32    u32x4;

#define DEV static __device__ __forceinline__

DEV u16 f2bf(float f){ return __builtin_bit_cast(u16, (__bf16)f); }

#if __has_builtin(__builtin_amdgcn_exp2f)
DEV float fexp2(float x){ return __builtin_amdgcn_exp2f(x); }
#else
DEV float fexp2(float x){ return exp2f(x); }
#endif

DEV f32x4 mfma16(short8 a, short8 b, f32x4 c){
  return __builtin_amdgcn_mfma_f32_16x16x32_bf16(
      __builtin_bit_cast(bf16x8, a), __builtin_bit_cast(bf16x8, b), c, 0, 0, 0);
}
DEV f32x16 mfma32(short8 a, short8 b, f32x16 c){
  return __builtin_amdgcn_mfma_f32_32x32x16_bf16(
      __builtin_bit_cast(bf16x8, a), __builtin_bit_cast(bf16x8, b), c, 0, 0, 0);
}
// XOR swizzle for 128-byte-row LDS tiles
DEV int swz(int byteoff, int row){ return byteoff ^ ((row & 7) << 4); }

#if __has_builtin(__builtin_amdgcn_global_load_lds)
#define USE_GLL 1
typedef __attribute__((address_space(1))) const u32 gas_u32;
typedef __attribute__((address_space(3)))       u32 las_u32;
#define GL2L(g, l) __builtin_amdgcn_global_load_lds((gas_u32*)(g), (las_u32*)(l), 16, 0, 0)
#define LSWZ(boff, r) swz(boff, r)
#else
#define LSWZ(boff, r) (boff)
#endif

// ---------------- prep: 5 weight transposes + cs table + RMSNorm -------------
// z=0..4: W(K,N) f32 -> Wt(N,K) bf16; z=5: cs table; z=6: RMSNorm (8 rows/blk)
__global__ __launch_bounds__(256) void k_prep(const float* __restrict__ wq,
                                              const float* __restrict__ kvd,
                                              const float* __restrict__ wk,
                                              const float* __restrict__ wv,
                                              const float* __restrict__ wo,
                                              const float* __restrict__ x,
                                              const float* __restrict__ norm_w,
                                              u16* __restrict__ wqT, u16* __restrict__ kvdT,
                                              u16* __restrict__ wkT, u16* __restrict__ wvT,
                                              u16* __restrict__ woT, u16* __restrict__ xn,
                                              float2* __restrict__ cs, float qscale){
  const int z = blockIdx.z;
  if (z == 6){
    const int bid = blockIdx.y*32 + blockIdx.x;
    const int t = threadIdx.x;
    __shared__ float ps[4];
    const float4 g = ((const float4*)norm_w)[t];
    #pragma unroll 1
    for (int it = 0; it < 8; ++it){
      const int row = bid*8 + it;
      const float4 v = ((const float4*)(x + (size_t)row*1024))[t];
      float ss = v.x*v.x + v.y*v.y + v.z*v.z + v.w*v.w;
      #pragma unroll
      for (int off=32; off; off>>=1) ss += __shfl_xor(ss, off, 64);
      if ((t & 63) == 0) ps[t>>6] = ss;
      __syncthreads();
      const float tot = ps[0]+ps[1]+ps[2]+ps[3];
      const float rinv = rsqrtf(tot * (1.0f/1024.0f) + 1e-6f);
      u16x4 o;
      o.x = f2bf(v.x*rinv*g.x); o.y = f2bf(v.y*rinv*g.y);
      o.z = f2bf(v.z*rinv*g.z); o.w = f2bf(v.w*rinv*g.w);
      *(u16x4*)(xn + (size_t)row*1024 + t*4) = o;
      __syncthreads();
    }
    return;
  }
  if (z == 5){
    if (blockIdx.y >= 8) return;
    const int idx = (blockIdx.y*32 + blockIdx.x)*256 + threadIdx.x;   // 65536 total
    const int s = idx >> 5, j = idx & 31;
    const float ang = (float)s * expf(-(float)j * (9.210340371976184f/32.0f));
    cs[idx] = make_float2(cosf(ang), sinf(ang));
    return;
  }
  const float* W; u16* Wt; int K, N; float sc = 1.0f;
  switch (z){
    case 0: W = wq;  Wt = wqT;  K = 1024; N = 1024; sc = qscale; break;
    case 1: W = kvd; Wt = kvdT; K = 1024; N = 512;  break;
    case 2: W = wk;  Wt = wkT;  K = 512;  N = 1024; break;
    case 3: W = wv;  Wt = wvT;  K = 512;  N = 1024; break;
    default: W = wo; Wt = woT;  K = 1024; N = 1024; break;
  }
  const int k0 = blockIdx.x*32, n0 = blockIdx.y*32;
  if (k0 >= K || n0 >= N) return;
  __shared__ float t[32][33];
  const int tx = threadIdx.x & 31, ty = threadIdx.x >> 5;
  #pragma unroll
  for (int j=0;j<4;++j) t[ty + j*8][tx] = W[(size_t)(k0+ty+j*8)*N + n0 + tx];
  __syncthreads();
  #pragma unroll
  for (int j=0;j<4;++j) Wt[(size_t)(n0+ty+j*8)*K + k0 + tx] = f2bf(t[tx][ty+j*8]*sc);
}

// ---------------- GEMM: A(M,K) bf16 rm x Bt(N,K) bf16 rm --------------------
// 2-phase pipeline: dbuf LDS, STAGE(t+1) issued after barrier, swizzled layout.
// MODE 2: f32 out + residual (N=1024), Bt only.
// MODE 4: x<8: RoPE->Cb (N=1024); x>=8: plain bf16 -> Cb2 (N=512, B=Bt2)
// MODE 5: x<8: RoPE->Cb (N=1024); x>=8: vT store  -> Cb2 (B=Bt2)
template<int MODE>
__global__ __launch_bounds__(256) void k_gemm(const u16* __restrict__ A,
                                              const u16* __restrict__ Bt,
                                              const u16* __restrict__ Bt2,
                                              u16* __restrict__ Cb,
                                              u16* __restrict__ Cb2,
                                              float* __restrict__ Cf,
                                              const float* __restrict__ resid,
                                              const float2* __restrict__ cs,
                                              int K){
  __shared__ __align__(16) u16 Al[2][128*64];
  __shared__ __align__(16) u16 Bl[2][128*64];
  const int tid = threadIdx.x, lane = tid & 63, w = tid >> 6;
  const int wm = (w >> 1) * 64, wn = (w & 1) * 64;
  const bool second = (MODE != 2) && (blockIdx.x >= 8);
  const u16* B = second ? Bt2 : Bt;
  const int n0 = (second ? blockIdx.x - 8 : blockIdx.x) * 128;
  const int m0 = blockIdx.y * 128;
  const int lr = lane & 15, lg = lane >> 4;
  const int nt = K >> 6;

  f32x4 acc[4][4] = {};

#ifdef USE_GLL
  const int rin  = lane >> 3;
  const int colq = (lane & 7) ^ rin;
  auto stage = [&](int t_){
    u16* Ad = &Al[t_ & 1][0];
    u16* Bd = &Bl[t_ & 1][0];
    const int kb = t_ << 6;
    #pragma unroll
    for (int j=0;j<4;++j){
      const int c = w*4 + j;
      GL2L(A + (size_t)(m0 + c*8 + rin)*K + kb + colq*8, Ad + c*512);
      GL2L(B + (size_t)(n0 + c*8 + rin)*K + kb + colq*8, Bd + c*512);
    }
  };
#else
  auto stage = [&](int t_){
    u16* Ad = &Al[t_ & 1][0];
    u16* Bd = &Bl[t_ & 1][0];
    const int kb = t_ << 6;
    const int srow = tid >> 1, scol = (tid & 1) * 32;
    #pragma unroll
    for (int j=0;j<4;++j){
      *(short8*)(Ad + srow*64 + scol + j*8) = *(const short8*)(A + (size_t)(m0+srow)*K + kb + scol + j*8);
      *(short8*)(Bd + srow*64 + scol + j*8) = *(const short8*)(B + (size_t)(n0+srow)*K + kb + scol + j*8);
    }
  };
#endif

  stage(0);
  for (int t = 0; t < nt; ++t){
    __syncthreads();
    if (t + 1 < nt) stage(t + 1);
    const u16* Ab = &Al[t & 1][0];
    const u16* Bb = &Bl[t & 1][0];
    #pragma unroll
    for (int kk=0; kk<2; ++kk){
      const int cb = kk*64 + lg*16;
      short8 af[4], bfr[4];
      #pragma unroll
      for (int m=0;m<4;++m){
        const int r = wm + m*16 + lr;
        af[m] = *(const short8*)((const char*)Ab + LSWZ(r*128 + cb, r));
      }
      #pragma unroll
      for (int n=0;n<4;++n){
        const int r = wn + n*16 + lr;
        bfr[n] = *(const short8*)((const char*)Bb + LSWZ(r*128 + cb, r));
      }
      #pragma unroll
      for (int m=0;m<4;++m)
        #pragma unroll
        for (int n=0;n<4;++n)
          acc[m][n] = mfma16(af[m], bfr[n], acc[m][n]);
    }
  }

  #pragma unroll
  for (int m=0;m<4;++m){
    const int rb = m0 + wm + m*16 + lg*4;
    if (MODE == 2){
      #pragma unroll
      for (int n=0;n<4;++n){
        const int c = n0 + wn + n*16 + lr;
        #pragma unroll
        for (int i=0;i<4;++i){
          const size_t off = (size_t)(rb+i)*1024 + c;
          Cf[off] = acc[m][n][i] + resid[off];
        }
      }
    } else if (!second){
      #pragma unroll
      for (int n=0;n<2;++n){
        const int c = n0 + wn + n*16 + lr;
        const int j = n*16 + lr;
        #pragma unroll
        for (int i=0;i<4;++i){
          const float2 t = cs[(size_t)((rb+i) & 2047)*32 + j];
          const float t1 = acc[m][n][i], t2 = acc[m][n+2][i];
          Cb[(size_t)(rb+i)*1024 + c]      = f2bf(t1*t.x - t2*t.y);
          Cb[(size_t)(rb+i)*1024 + c + 32] = f2bf(t1*t.y + t2*t.x);
        }
      }
    } else if (MODE == 4){
      #pragma unroll
      for (int n=0;n<4;++n){
        const int c = n0 + wn + n*16 + lr;
        #pragma unroll
        for (int i=0;i<4;++i) Cb2[(size_t)(rb+i)*512 + c] = f2bf(acc[m][n][i]);
      }
    } else {
      #pragma unroll
      for (int n=0;n<4;++n){
        const int c = n0 + wn + n*16 + lr;
        const int b = rb >> 11, s = rb & 2047;
        u16x4 pk;
        pk.x = f2bf(acc[m][n][0]); pk.y = f2bf(acc[m][n][1]);
        pk.z = f2bf(acc[m][n][2]); pk.w = f2bf(acc[m][n][3]);
        *(u16x4*)(Cb2 + (((size_t)(b*1024 + c)) << 11) + s) = pk;
      }
    }
  }
}

// ---------------- flash attention: 32x32 MFMA, in-register softmax/P ---------
// q pre-scaled by 0.125*log2(e). q,k: [b][s][h*64+hd]; vT: [(b*1024+d)][s]
// 4 waves x 32 q-rows (QBLK=128), KVBLK=64, K/V dbuf in LDS (32KB), no P LDS.
// Lane (l31,hi) holds the INTERLEAVED HALF of S[q=l31][kv] (kv = rowmap+4*hi);
// partner lane l31^32 holds the other half -> m/l need one shfl_xor(32) fold.
__global__ __launch_bounds__(256, 4) void k_attn(const u16* __restrict__ q,
                                                 const u16* __restrict__ kmat,
                                                 const u16* __restrict__ vT,
                                                 u16* __restrict__ o){
  __shared__ __align__(16) u16 Kl[2][64*64];
  __shared__ __align__(16) u16 Vl[2][64*64];
  const int tid = threadIdx.x, lane = tid & 63, w = tid >> 6;   // 4 waves
  const int l31 = lane & 31, hi = lane >> 5;

  // XCD-aware bijective swizzle: 1024 blocks, each head's 16 blocks on 1 XCD
  const int fid = blockIdx.y * 16 + blockIdx.x;
  const int sid = (fid & 7) * 128 + (fid >> 3);
  const int qx = sid & 15, bh = sid >> 4;
  const int b = bh >> 4, h = bh & 15;
  const int q0 = qx * 128;

  // Q fragments (B-operand): lane = q-col q0+w*32+l31; chain c: hd = c*16+hi*8+j
  short8 qf[4];
  {
    const size_t base = ((size_t)(b*2048 + q0 + w*32 + l31) << 10) + (h<<6) + hi*8;
    qf[0] = *(const short8*)(q + base);
    qf[1] = *(const short8*)(q + base + 16);
    qf[2] = *(const short8*)(q + base + 32);
    qf[3] = *(const short8*)(q + base + 48);
  }
  f32x16 oacc0 = {}, oacc1 = {};        // O[q(reg,hi)][d = {0,1}*32 + l31]
  float m = -1e30f, l = 0.f;            // per-lane state for q = l31 (synced w/ partner)

  // staging: wave w owns chunks 2w, 2w+1 of K and V (8 rows x 128B each)
  const int rin  = lane >> 3;
  const int colq = (lane & 7) ^ rin;    // pre-swizzled 16B slot
  const u16* kg0 = kmat + ((size_t)(b*2048 + w*16 + rin) << 10) + (h<<6) + colq*8;
  const u16* vg0 = vT + (((size_t)(b*1024 + h*64 + w*16 + rin)) << 11) + colq*8;
  u16* const Kd[2] = { Kl[0] + w*1024, Kl[1] + w*1024 };
  u16* const Vd[2] = { Vl[0] + w*1024, Vl[1] + w*1024 };

#ifdef USE_GLL
  #define STAGE(t_) { const int buf_=(t_)&1; const int kv0_=(t_)*64;            \
      GL2L(kg0 + ((size_t)kv0_ << 10),              Kd[buf_]);                  \
      GL2L(kg0 + ((size_t)(kv0_ + 8) << 10),        Kd[buf_] + 512);            \
      GL2L(vg0 + kv0_,                              Vd[buf_]);                  \
      GL2L(vg0 + ((size_t)8 << 11) + kv0_,          Vd[buf_] + 512); }
#else
  #define STAGE(t_) { const int buf_=(t_)&1; const int kv0_=(t_)*64;            \
      *(short8*)(Kd[buf_] + lane*8)       = *(const short8*)(kg0 + ((size_t)kv0_ << 10));       \
      *(short8*)(Kd[buf_] + 512 + lane*8) = *(const short8*)(kg0 + ((size_t)(kv0_+8) << 10));   \
      *(short8*)(Vd[buf_] + lane*8)       = *(const short8*)(vg0 + kv0_);                       \
      *(short8*)(Vd[buf_] + 512 + lane*8) = *(const short8*)(vg0 + ((size_t)8 << 11) + kv0_); }
#endif

  STAGE(0);
  for (int t = 0; t < 32; ++t){
    const u16* Kb = Kl[t & 1];
    const u16* Vb = Vl[t & 1];
    __syncthreads();                   // drains GLL(t); protects buf^1 reuse
    if (t < 31) STAGE(t+1);            // in flight under compute(t)

    // QK^T: s0 = S^T tile kv 0..31, s1 = kv 32..63; col = q = l31
    f32x16 s0 = {}, s1 = {};
    __builtin_amdgcn_s_setprio(1);
    #pragma unroll
    for (int c=0;c<4;++c){
      const int r0 = l31, r1 = 32 + l31;
      short8 kf0 = *(const short8*)((const char*)Kb + swz(r0*128 + c*32 + hi*16, r0));
      short8 kf1 = *(const short8*)((const char*)Kb + swz(r1*128 + c*32 + hi*16, r1));
      s0 = mfma32(kf0, qf[c], s0);
      s1 = mfma32(kf1, qf[c], s1);
    }
    __builtin_amdgcn_s_setprio(0);

    // softmax for q = l31: in-lane over own half + one partner fold (hi^1)
    float tmax = s0[0];
    #pragma unroll
    for (int r=1;r<16;++r) tmax = fmaxf(tmax, s0[r]);
    #pragma unroll
    for (int r=0;r<16;++r) tmax = fmaxf(tmax, s1[r]);
    tmax = fmaxf(tmax, __shfl_xor(tmax, 32, 64));   // fold partner's half

    if (__any(tmax > m + 8.0f)){       // T13 defer-max (log2 domain)
      const float mn = fmaxf(m, tmax);
      const float corr = fexp2(m - mn);
      m = mn; l *= corr;
      #pragma unroll
      for (int reg=0; reg<16; ++reg){  // corr for O-row q = rowmap(reg,hi)
        const int cq = (reg&3) + 8*(reg>>2) + 4*hi;
        const float cr = __shfl(corr, cq, 64);
        oacc0[reg] *= cr; oacc1[reg] *= cr;
      }
    }

    // P = exp2(S - m), packed bf16 pairs: pk[s][a*2+e] = (kv 8a+4hi+2e, +1)
    float rs = 0.f;
    u32 pk0[8], pk1[8];
    #pragma unroll
    for (int a=0;a<4;++a){
      #pragma unroll
      for (int e=0;e<2;++e){
        float pa = fexp2(s0[a*4+e*2]   - m);
        float pb = fexp2(s0[a*4+e*2+1] - m);
        rs += pa + pb;
        pk0[a*2+e] = (u32)f2bf(pa) | ((u32)f2bf(pb) << 16);
        pa = fexp2(s1[a*4+e*2]   - m);
        pb = fexp2(s1[a*4+e*2+1] - m);
        rs += pa + pb;
        pk1[a*2+e] = (u32)f2bf(pa) | ((u32)f2bf(pb) << 16);
      }
    }
    rs += __shfl_xor(rs, 32, 64);      // fold partner's half-sum
    l += rs;

    // PV: pf for chain c via permlane32_swap (T12); B = V^T rows d
    __builtin_amdgcn_s_setprio(1);
    #pragma unroll
    for (int c=0;c<4;++c){
      u32* pks = (c < 2) ? pk0 : pk1;
      const int cc = c & 1;
      u32 a0 = pks[(2*cc)*2+0], b0 = pks[(2*cc+1)*2+0];
      u32 a1 = pks[(2*cc)*2+1], b1 = pks[(2*cc+1)*2+1];
      asm volatile("v_permlane32_swap_b32 %0, %1" : "+v"(a0), "+v"(b0));
      asm volatile("v_permlane32_swap_b32 %0, %1" : "+v"(a1), "+v"(b1));
      u32x4 pfv; pfv.x = a0; pfv.y = a1; pfv.z = b0; pfv.w = b1;
      const short8 pf = __builtin_bit_cast(short8, pfv);
      const int r0 = l31, r1 = 32 + l31;
      short8 vf0 = *(const short8*)((const char*)Vb + swz(r0*128 + c*32 + hi*16, r0));
      short8 vf1 = *(const short8*)((const char*)Vb + swz(r1*128 + c*32 + hi*16, r1));
      oacc0 = mfma32(pf, vf0, oacc0);
      oacc1 = mfma32(pf, vf1, oacc1);
    }
    __builtin_amdgcn_s_setprio(0);
  }

  // epilogue: divide by l (per O-row), store O[q][d]
  const float linv = 1.0f / l;
  #pragma unroll
  for (int reg=0; reg<16; ++reg){
    const int cq = (reg&3) + 8*(reg>>2) + 4*hi;
    const float lv = __shfl(linv, cq, 64);
    const size_t rowbase = ((size_t)(b*2048 + q0 + w*32 + cq) << 10) + (h<<6);
    o[rowbase + l31]      = f2bf(oacc0[reg] * lv);
    o[rowbase + 32 + l31] = f2bf(oacc1[reg] * lv);
  }
  #undef STAGE
}

// ---------------------------------------------------------------------------
extern "C" void kernel_launch(void* const* d_in, const int* in_sizes, int n_in,
                              void* d_out, int out_size, void* d_ws, size_t ws_size,
                              hipStream_t stream){
  const float* x      = (const float*)d_in[0];
  const float* norm_w = (const float*)d_in[1];
  const float* wq     = (const float*)d_in[2];
  const float* kvd    = (const float*)d_in[3];
  const float* wk     = (const float*)d_in[4];
  const float* wv     = (const float*)d_in[5];
  const float* wo     = (const float*)d_in[6];
  float* out = (float*)d_out;

  char* ws = (char*)d_ws;
  const size_t SZ = (size_t)8192*1024*2;       // 16 MB bf16 tensor
  u16* xn   = (u16*)(ws);
  u16* q    = (u16*)(ws + SZ);
  u16* kmat = (u16*)(ws + 2*SZ);
  u16* vT   = (u16*)(ws + 3*SZ);
  u16* attn = (u16*)(ws + 4*SZ);
  u16* kv   = (u16*)(ws + 5*SZ);               // 8 MB
  u16* wqT  = (u16*)(ws + 5*SZ + (size_t)8192*512*2);
  u16* kvdT = wqT  + 1024*1024;
  u16* wkT  = kvdT + 512*1024;
  u16* wvT  = wkT  + 1024*512;
  u16* woT  = wvT  + 1024*512;
  float2* cs = (float2*)(woT + 1024*1024);

  const float QSCALE = 0.125f * 1.4426950408889634f;   // softmax scale * log2(e)

  // prep: weights (z=0..4) + cs (z=5) + rmsnorm (z=6)
  k_prep<<<dim3(32,32,7), 256, 0, stream>>>(wq, kvd, wk, wv, wo, x, norm_w,
                                            wqT, kvdT, wkT, wvT, woT, xn, cs, QSCALE);

  // q = rope(xn@wq*QSCALE) | kv = xn@kvd        (fused, shared A)
  k_gemm<4><<<dim3(12,64), 256, 0, stream>>>(xn, wqT, kvdT, q, kv, nullptr, nullptr, cs, 1024);
  // kmat = rope(kv@wk) | vT = (kv@wv)^T         (fused, shared A)
  k_gemm<5><<<dim3(16,64), 256, 0, stream>>>(kv, wkT, wvT, kmat, vT, nullptr, nullptr, cs, 512);

  k_attn<<<dim3(16,64), 256, 0, stream>>>(q, kmat, vT, attn);

  // out = attn @ wo + x
  k_gemm<2><<<dim3(8,64), 256, 0, stream>>>(attn, woT, nullptr, nullptr, nullptr, out, x, nullptr, 1024);
}

// Round 8
// 202.826 us; speedup vs baseline: 1.9790x; 1.0256x over previous
//
#include <hip/hip_runtime.h>

typedef unsigned short u16;
typedef unsigned int   u32;
typedef __attribute__((ext_vector_type(8)))  __bf16 bf16x8;
typedef __attribute__((ext_vector_type(8)))  short  short8;
typedef __attribute__((ext_vector_type(4)))  float  f32x4;
typedef __attribute__((ext_vector_type(16))) float  f32x16;
typedef __attribute__((ext_vector_type(4)))  u16    u16x4;
typedef __attribute__((ext_vector_type(4)))  u32    u32x4;

#define DEV static __device__ __forceinline__

DEV u16 f2bf(float f){ return __builtin_bit_cast(u16, (__bf16)f); }

#if __has_builtin(__builtin_amdgcn_exp2f)
DEV float fexp2(float x){ return __builtin_amdgcn_exp2f(x); }
#else
DEV float fexp2(float x){ return exp2f(x); }
#endif

DEV f32x4 mfma16(short8 a, short8 b, f32x4 c){
  return __builtin_amdgcn_mfma_f32_16x16x32_bf16(
      __builtin_bit_cast(bf16x8, a), __builtin_bit_cast(bf16x8, b), c, 0, 0, 0);
}
DEV f32x16 mfma32(short8 a, short8 b, f32x16 c){
  return __builtin_amdgcn_mfma_f32_32x32x16_bf16(
      __builtin_bit_cast(bf16x8, a), __builtin_bit_cast(bf16x8, b), c, 0, 0, 0);
}
// XOR swizzle for 128-byte-row LDS tiles
DEV int swz(int byteoff, int row){ return byteoff ^ ((row & 7) << 4); }

#if __has_builtin(__builtin_amdgcn_global_load_lds)
#define USE_GLL 1
typedef __attribute__((address_space(1))) const u32 gas_u32;
typedef __attribute__((address_space(3)))       u32 las_u32;
#define GL2L(g, l) __builtin_amdgcn_global_load_lds((gas_u32*)(g), (las_u32*)(l), 16, 0, 0)
#define LSWZ(boff, r) swz(boff, r)
#else
#define LSWZ(boff, r) (boff)
#endif

// ---------------- prep: 5 weight transposes + cs table + RMSNorm -------------
// z=0..4: W(K,N) f32 -> Wt(N,K) bf16; z=5: cs table; z=6: RMSNorm (8 rows/blk)
__global__ __launch_bounds__(256) void k_prep(const float* __restrict__ wq,
                                              const float* __restrict__ kvd,
                                              const float* __restrict__ wk,
                                              const float* __restrict__ wv,
                                              const float* __restrict__ wo,
                                              const float* __restrict__ x,
                                              const float* __restrict__ norm_w,
                                              u16* __restrict__ wqT, u16* __restrict__ kvdT,
                                              u16* __restrict__ wkT, u16* __restrict__ wvT,
                                              u16* __restrict__ woT, u16* __restrict__ xn,
                                              float2* __restrict__ cs, float qscale){
  const int z = blockIdx.z;
  if (z == 6){
    const int bid = blockIdx.y*32 + blockIdx.x;
    const int t = threadIdx.x;
    __shared__ float ps[4];
    const float4 g = ((const float4*)norm_w)[t];
    #pragma unroll 1
    for (int it = 0; it < 8; ++it){
      const int row = bid*8 + it;
      const float4 v = ((const float4*)(x + (size_t)row*1024))[t];
      float ss = v.x*v.x + v.y*v.y + v.z*v.z + v.w*v.w;
      #pragma unroll
      for (int off=32; off; off>>=1) ss += __shfl_xor(ss, off, 64);
      if ((t & 63) == 0) ps[t>>6] = ss;
      __syncthreads();
      const float tot = ps[0]+ps[1]+ps[2]+ps[3];
      const float rinv = rsqrtf(tot * (1.0f/1024.0f) + 1e-6f);
      u16x4 o;
      o.x = f2bf(v.x*rinv*g.x); o.y = f2bf(v.y*rinv*g.y);
      o.z = f2bf(v.z*rinv*g.z); o.w = f2bf(v.w*rinv*g.w);
      *(u16x4*)(xn + (size_t)row*1024 + t*4) = o;
      __syncthreads();
    }
    return;
  }
  if (z == 5){
    if (blockIdx.y >= 8) return;
    const int idx = (blockIdx.y*32 + blockIdx.x)*256 + threadIdx.x;   // 65536 total
    const int s = idx >> 5, j = idx & 31;
    const float ang = (float)s * expf(-(float)j * (9.210340371976184f/32.0f));
    cs[idx] = make_float2(cosf(ang), sinf(ang));
    return;
  }
  const float* W; u16* Wt; int K, N; float sc = 1.0f;
  switch (z){
    case 0: W = wq;  Wt = wqT;  K = 1024; N = 1024; sc = qscale; break;
    case 1: W = kvd; Wt = kvdT; K = 1024; N = 512;  break;
    case 2: W = wk;  Wt = wkT;  K = 512;  N = 1024; break;
    case 3: W = wv;  Wt = wvT;  K = 512;  N = 1024; break;
    default: W = wo; Wt = woT;  K = 1024; N = 1024; break;
  }
  const int k0 = blockIdx.x*32, n0 = blockIdx.y*32;
  if (k0 >= K || n0 >= N) return;
  __shared__ float t[32][33];
  const int tx = threadIdx.x & 31, ty = threadIdx.x >> 5;
  #pragma unroll
  for (int j=0;j<4;++j) t[ty + j*8][tx] = W[(size_t)(k0+ty+j*8)*N + n0 + tx];
  __syncthreads();
  #pragma unroll
  for (int j=0;j<4;++j) Wt[(size_t)(n0+ty+j*8)*K + k0 + tx] = f2bf(t[tx][ty+j*8]*sc);
}

// ---------------- GEMM: A(M,K) bf16 rm x Bt(N,K) bf16 rm --------------------
// 2-phase pipeline: dbuf LDS, STAGE(t+1) issued after barrier, swizzled layout.
// T1 XCD-chunked block swizzle (grid count % 8 == 0).
// MODE 2: f32 out + residual (N=1024), Bt only.
// MODE 4: x<8: RoPE->Cb (N=1024); x>=8: plain bf16 -> Cb2 (N=512, B=Bt2)
// MODE 5: x<8: RoPE->Cb (N=1024); x>=8: vT store  -> Cb2 (B=Bt2)
template<int MODE>
__global__ __launch_bounds__(256) void k_gemm(const u16* __restrict__ A,
                                              const u16* __restrict__ Bt,
                                              const u16* __restrict__ Bt2,
                                              u16* __restrict__ Cb,
                                              u16* __restrict__ Cb2,
                                              float* __restrict__ Cf,
                                              const float* __restrict__ resid,
                                              const float2* __restrict__ cs,
                                              int K){
  __shared__ __align__(16) u16 Al[2][128*64];
  __shared__ __align__(16) u16 Bl[2][128*64];
  const int tid = threadIdx.x, lane = tid & 63, w = tid >> 6;
  const int wm = (w >> 1) * 64, wn = (w & 1) * 64;

  // T1: XCD-chunked swizzle — same-row (by) blocks co-locate on one XCD
  const int gx = gridDim.x;
  const int nwg = gx * gridDim.y;
  int fid = blockIdx.y * gx + blockIdx.x;
  fid = (fid & 7) * (nwg >> 3) + (fid >> 3);
  const int bx = fid % gx, by = fid / gx;

  const bool second = (MODE != 2) && (bx >= 8);
  const u16* B = second ? Bt2 : Bt;
  const int n0 = (second ? bx - 8 : bx) * 128;
  const int m0 = by * 128;
  const int lr = lane & 15, lg = lane >> 4;
  const int nt = K >> 6;

  f32x4 acc[4][4] = {};

#ifdef USE_GLL
  const int rin  = lane >> 3;
  const int colq = (lane & 7) ^ rin;
  auto stage = [&](int t_){
    u16* Ad = &Al[t_ & 1][0];
    u16* Bd = &Bl[t_ & 1][0];
    const int kb = t_ << 6;
    #pragma unroll
    for (int j=0;j<4;++j){
      const int c = w*4 + j;
      GL2L(A + (size_t)(m0 + c*8 + rin)*K + kb + colq*8, Ad + c*512);
      GL2L(B + (size_t)(n0 + c*8 + rin)*K + kb + colq*8, Bd + c*512);
    }
  };
#else
  auto stage = [&](int t_){
    u16* Ad = &Al[t_ & 1][0];
    u16* Bd = &Bl[t_ & 1][0];
    const int kb = t_ << 6;
    const int srow = tid >> 1, scol = (tid & 1) * 32;
    #pragma unroll
    for (int j=0;j<4;++j){
      *(short8*)(Ad + srow*64 + scol + j*8) = *(const short8*)(A + (size_t)(m0+srow)*K + kb + scol + j*8);
      *(short8*)(Bd + srow*64 + scol + j*8) = *(const short8*)(B + (size_t)(n0+srow)*K + kb + scol + j*8);
    }
  };
#endif

  stage(0);
  for (int t = 0; t < nt; ++t){
    __syncthreads();
    if (t + 1 < nt) stage(t + 1);
    const u16* Ab = &Al[t & 1][0];
    const u16* Bb = &Bl[t & 1][0];
    #pragma unroll
    for (int kk=0; kk<2; ++kk){
      const int cb = kk*64 + lg*16;
      short8 af[4], bfr[4];
      #pragma unroll
      for (int m=0;m<4;++m){
        const int r = wm + m*16 + lr;
        af[m] = *(const short8*)((const char*)Ab + LSWZ(r*128 + cb, r));
      }
      #pragma unroll
      for (int n=0;n<4;++n){
        const int r = wn + n*16 + lr;
        bfr[n] = *(const short8*)((const char*)Bb + LSWZ(r*128 + cb, r));
      }
      #pragma unroll
      for (int m=0;m<4;++m)
        #pragma unroll
        for (int n=0;n<4;++n)
          acc[m][n] = mfma16(af[m], bfr[n], acc[m][n]);
    }
  }

  #pragma unroll
  for (int m=0;m<4;++m){
    const int rb = m0 + wm + m*16 + lg*4;
    if (MODE == 2){
      #pragma unroll
      for (int n=0;n<4;++n){
        const int c = n0 + wn + n*16 + lr;
        #pragma unroll
        for (int i=0;i<4;++i){
          const size_t off = (size_t)(rb+i)*1024 + c;
          Cf[off] = acc[m][n][i] + resid[off];
        }
      }
    } else if (!second){
      #pragma unroll
      for (int n=0;n<2;++n){
        const int c = n0 + wn + n*16 + lr;
        const int j = n*16 + lr;
        #pragma unroll
        for (int i=0;i<4;++i){
          const float2 t = cs[(size_t)((rb+i) & 2047)*32 + j];
          const float t1 = acc[m][n][i], t2 = acc[m][n+2][i];
          Cb[(size_t)(rb+i)*1024 + c]      = f2bf(t1*t.x - t2*t.y);
          Cb[(size_t)(rb+i)*1024 + c + 32] = f2bf(t1*t.y + t2*t.x);
        }
      }
    } else if (MODE == 4){
      #pragma unroll
      for (int n=0;n<4;++n){
        const int c = n0 + wn + n*16 + lr;
        #pragma unroll
        for (int i=0;i<4;++i) Cb2[(size_t)(rb+i)*512 + c] = f2bf(acc[m][n][i]);
      }
    } else {
      #pragma unroll
      for (int n=0;n<4;++n){
        const int c = n0 + wn + n*16 + lr;
        const int b = rb >> 11, s = rb & 2047;
        u16x4 pk;
        pk.x = f2bf(acc[m][n][0]); pk.y = f2bf(acc[m][n][1]);
        pk.z = f2bf(acc[m][n][2]); pk.w = f2bf(acc[m][n][3]);
        *(u16x4*)(Cb2 + (((size_t)(b*1024 + c)) << 11) + s) = pk;
      }
    }
  }
}

// ---------------- flash attention: 32x32 MFMA, in-register softmax/P ---------
// q pre-scaled by 0.125*log2(e). q,k: [b][s][h*64+hd]; vT: [(b*1024+d)][s]
// 4 waves x 32 q-rows (QBLK=128), KVBLK=64, K/V dbuf in LDS (32KB), no P LDS.
// Lane (l31,hi) holds the INTERLEAVED HALF of S[q=l31][kv] (kv = rowmap+4*hi);
// partner lane l31^32 holds the other half -> m/l need one shfl_xor(32) fold.
// s0/s1 pinned to arch VGPRs (empty-asm) to avoid accvgpr read/write churn.
__global__ __launch_bounds__(256, 3) void k_attn(const u16* __restrict__ q,
                                                 const u16* __restrict__ kmat,
                                                 const u16* __restrict__ vT,
                                                 u16* __restrict__ o){
  __shared__ __align__(16) u16 Kl[2][64*64];
  __shared__ __align__(16) u16 Vl[2][64*64];
  const int tid = threadIdx.x, lane = tid & 63, w = tid >> 6;   // 4 waves
  const int l31 = lane & 31, hi = lane >> 5;

  // XCD-aware bijective swizzle: 1024 blocks, each head's 16 blocks on 1 XCD
  const int fid = blockIdx.y * 16 + blockIdx.x;
  const int sid = (fid & 7) * 128 + (fid >> 3);
  const int qx = sid & 15, bh = sid >> 4;
  const int b = bh >> 4, h = bh & 15;
  const int q0 = qx * 128;

  // Q fragments (B-operand): lane = q-col q0+w*32+l31; chain c: hd = c*16+hi*8+j
  short8 qf[4];
  {
    const size_t base = ((size_t)(b*2048 + q0 + w*32 + l31) << 10) + (h<<6) + hi*8;
    qf[0] = *(const short8*)(q + base);
    qf[1] = *(const short8*)(q + base + 16);
    qf[2] = *(const short8*)(q + base + 32);
    qf[3] = *(const short8*)(q + base + 48);
  }
  f32x16 oacc0 = {}, oacc1 = {};        // O[q(reg,hi)][d = {0,1}*32 + l31]
  float m = -1e30f, l = 0.f;            // per-lane state for q = l31 (synced w/ partner)

  // staging: wave w owns chunks 2w, 2w+1 of K and V (8 rows x 128B each)
  const int rin  = lane >> 3;
  const int colq = (lane & 7) ^ rin;    // pre-swizzled 16B slot
  const u16* kg0 = kmat + ((size_t)(b*2048 + w*16 + rin) << 10) + (h<<6) + colq*8;
  const u16* vg0 = vT + (((size_t)(b*1024 + h*64 + w*16 + rin)) << 11) + colq*8;
  u16* const Kd[2] = { Kl[0] + w*1024, Kl[1] + w*1024 };
  u16* const Vd[2] = { Vl[0] + w*1024, Vl[1] + w*1024 };

#ifdef USE_GLL
  #define STAGE(t_) { const int buf_=(t_)&1; const int kv0_=(t_)*64;            \
      GL2L(kg0 + ((size_t)kv0_ << 10),              Kd[buf_]);                  \
      GL2L(kg0 + ((size_t)(kv0_ + 8) << 10),        Kd[buf_] + 512);            \
      GL2L(vg0 + kv0_,                              Vd[buf_]);                  \
      GL2L(vg0 + ((size_t)8 << 11) + kv0_,          Vd[buf_] + 512); }
#else
  #define STAGE(t_) { const int buf_=(t_)&1; const int kv0_=(t_)*64;            \
      *(short8*)(Kd[buf_] + lane*8)       = *(const short8*)(kg0 + ((size_t)kv0_ << 10));       \
      *(short8*)(Kd[buf_] + 512 + lane*8) = *(const short8*)(kg0 + ((size_t)(kv0_+8) << 10));   \
      *(short8*)(Vd[buf_] + lane*8)       = *(const short8*)(vg0 + kv0_);                       \
      *(short8*)(Vd[buf_] + 512 + lane*8) = *(const short8*)(vg0 + ((size_t)8 << 11) + kv0_); }
#endif

  STAGE(0);
  for (int t = 0; t < 32; ++t){
    const u16* Kb = Kl[t & 1];
    const u16* Vb = Vl[t & 1];
    __syncthreads();                   // drains GLL(t); protects buf^1 reuse
    if (t < 31) STAGE(t+1);            // in flight under compute(t)

    // QK^T: s0 = S^T tile kv 0..31, s1 = kv 32..63; col = q = l31
    f32x16 s0 = {}, s1 = {};
    __builtin_amdgcn_s_setprio(1);
    #pragma unroll
    for (int c=0;c<4;++c){
      const int r0 = l31, r1 = 32 + l31;
      short8 kf0 = *(const short8*)((const char*)Kb + swz(r0*128 + c*32 + hi*16, r0));
      short8 kf1 = *(const short8*)((const char*)Kb + swz(r1*128 + c*32 + hi*16, r1));
      s0 = mfma32(kf0, qf[c], s0);
      s1 = mfma32(kf1, qf[c], s1);
    }
    __builtin_amdgcn_s_setprio(0);
    asm volatile("" : "+v"(s0), "+v"(s1));   // pin S to arch VGPRs (no accvgpr churn)

    // softmax for q = l31: in-lane over own half + one partner fold (hi^1)
    float tmax = s0[0];
    #pragma unroll
    for (int r=1;r<16;++r) tmax = fmaxf(tmax, s0[r]);
    #pragma unroll
    for (int r=0;r<16;++r) tmax = fmaxf(tmax, s1[r]);
    tmax = fmaxf(tmax, __shfl_xor(tmax, 32, 64));   // fold partner's half

    if (__any(tmax > m + 8.0f)){       // T13 defer-max (log2 domain)
      const float mn = fmaxf(m, tmax);
      const float corr = fexp2(m - mn);
      m = mn; l *= corr;
      #pragma unroll
      for (int reg=0; reg<16; ++reg){  // corr for O-row q = rowmap(reg,hi)
        const int cq = (reg&3) + 8*(reg>>2) + 4*hi;
        const float cr = __shfl(corr, cq, 64);
        oacc0[reg] *= cr; oacc1[reg] *= cr;
      }
    }

    // P = exp2(S - m), packed bf16 pairs: pk[s][a*2+e] = (kv 8a+4hi+2e, +1)
    float rs = 0.f;
    u32 pk0[8], pk1[8];
    #pragma unroll
    for (int a=0;a<4;++a){
      #pragma unroll
      for (int e=0;e<2;++e){
        float pa = fexp2(s0[a*4+e*2]   - m);
        float pb = fexp2(s0[a*4+e*2+1] - m);
        rs += pa + pb;
        pk0[a*2+e] = (u32)f2bf(pa) | ((u32)f2bf(pb) << 16);
        pa = fexp2(s1[a*4+e*2]   - m);
        pb = fexp2(s1[a*4+e*2+1] - m);
        rs += pa + pb;
        pk1[a*2+e] = (u32)f2bf(pa) | ((u32)f2bf(pb) << 16);
      }
    }
    rs += __shfl_xor(rs, 32, 64);      // fold partner's half-sum
    l += rs;

    // PV: pf for chain c via permlane32_swap (T12); B = V^T rows d
    __builtin_amdgcn_s_setprio(1);
    #pragma unroll
    for (int c=0;c<4;++c){
      u32* pks = (c < 2) ? pk0 : pk1;
      const int cc = c & 1;
      u32 a0 = pks[(2*cc)*2+0], b0 = pks[(2*cc+1)*2+0];
      u32 a1 = pks[(2*cc)*2+1], b1 = pks[(2*cc+1)*2+1];
      asm volatile("v_permlane32_swap_b32 %0, %1" : "+v"(a0), "+v"(b0));
      asm volatile("v_permlane32_swap_b32 %0, %1" : "+v"(a1), "+v"(b1));
      u32x4 pfv; pfv.x = a0; pfv.y = a1; pfv.z = b0; pfv.w = b1;
      const short8 pf = __builtin_bit_cast(short8, pfv);
      const int r0 = l31, r1 = 32 + l31;
      short8 vf0 = *(const short8*)((const char*)Vb + swz(r0*128 + c*32 + hi*16, r0));
      short8 vf1 = *(const short8*)((const char*)Vb + swz(r1*128 + c*32 + hi*16, r1));
      oacc0 = mfma32(pf, vf0, oacc0);
      oacc1 = mfma32(pf, vf1, oacc1);
    }
    __builtin_amdgcn_s_setprio(0);
  }

  // epilogue: divide by l (per O-row), store O[q][d]
  const float linv = 1.0f / l;
  #pragma unroll
  for (int reg=0; reg<16; ++reg){
    const int cq = (reg&3) + 8*(reg>>2) + 4*hi;
    const float lv = __shfl(linv, cq, 64);
    const size_t rowbase = ((size_t)(b*2048 + q0 + w*32 + cq) << 10) + (h<<6);
    o[rowbase + l31]      = f2bf(oacc0[reg] * lv);
    o[rowbase + 32 + l31] = f2bf(oacc1[reg] * lv);
  }
  #undef STAGE
}

// ---------------------------------------------------------------------------
extern "C" void kernel_launch(void* const* d_in, const int* in_sizes, int n_in,
                              void* d_out, int out_size, void* d_ws, size_t ws_size,
                              hipStream_t stream){
  const float* x      = (const float*)d_in[0];
  const float* norm_w = (const float*)d_in[1];
  const float* wq     = (const float*)d_in[2];
  const float* kvd    = (const float*)d_in[3];
  const float* wk     = (const float*)d_in[4];
  const float* wv     = (const float*)d_in[5];
  const float* wo     = (const float*)d_in[6];
  float* out = (float*)d_out;

  char* ws = (char*)d_ws;
  const size_t SZ = (size_t)8192*1024*2;       // 16 MB bf16 tensor
  u16* xn   = (u16*)(ws);
  u16* q    = (u16*)(ws + SZ);
  u16* kmat = (u16*)(ws + 2*SZ);
  u16* vT   = (u16*)(ws + 3*SZ);
  u16* attn = (u16*)(ws + 4*SZ);
  u16* kv   = (u16*)(ws + 5*SZ);               // 8 MB
  u16* wqT  = (u16*)(ws + 5*SZ + (size_t)8192*512*2);
  u16* kvdT = wqT  + 1024*1024;
  u16* wkT  = kvdT + 512*1024;
  u16* wvT  = wkT  + 1024*512;
  u16* woT  = wvT  + 1024*512;
  float2* cs = (float2*)(woT + 1024*1024);

  const float QSCALE = 0.125f * 1.4426950408889634f;   // softmax scale * log2(e)

  // prep: weights (z=0..4) + cs (z=5) + rmsnorm (z=6)
  k_prep<<<dim3(32,32,7), 256, 0, stream>>>(wq, kvd, wk, wv, wo, x, norm_w,
                                            wqT, kvdT, wkT, wvT, woT, xn, cs, QSCALE);

  // q = rope(xn@wq*QSCALE) | kv = xn@kvd        (fused, shared A)
  k_gemm<4><<<dim3(12,64), 256, 0, stream>>>(xn, wqT, kvdT, q, kv, nullptr, nullptr, cs, 1024);
  // kmat = rope(kv@wk) | vT = (kv@wv)^T         (fused, shared A)
  k_gemm<5><<<dim3(16,64), 256, 0, stream>>>(kv, wkT, wvT, kmat, vT, nullptr, nullptr, cs, 512);

  k_attn<<<dim3(16,64), 256, 0, stream>>>(q, kmat, vT, attn);

  // out = attn @ wo + x
  k_gemm<2><<<dim3(8,64), 256, 0, stream>>>(attn, woT, nullptr, nullptr, nullptr, out, x, nullptr, 1024);
}

// Round 9
// 201.033 us; speedup vs baseline: 1.9966x; 1.0089x over previous
//
#include <hip/hip_runtime.h>

typedef unsigned short u16;
typedef unsigned int   u32;
typedef __attribute__((ext_vector_type(8)))  __bf16 bf16x8;
typedef __attribute__((ext_vector_type(2)))  __bf16 bf16x2;
typedef __attribute__((ext_vector_type(8)))  short  short8;
typedef __attribute__((ext_vector_type(4)))  float  f32x4;
typedef __attribute__((ext_vector_type(16))) float  f32x16;
typedef __attribute__((ext_vector_type(4)))  u16    u16x4;
typedef __attribute__((ext_vector_type(4)))  u32    u32x4;

#define DEV static __device__ __forceinline__

DEV u16 f2bf(float f){ return __builtin_bit_cast(u16, (__bf16)f); }
DEV u32 pkbf(float a, float b){ bf16x2 t; t[0] = (__bf16)a; t[1] = (__bf16)b;
                                return __builtin_bit_cast(u32, t); }

#if __has_builtin(__builtin_amdgcn_exp2f)
DEV float fexp2(float x){ return __builtin_amdgcn_exp2f(x); }
#else
DEV float fexp2(float x){ return exp2f(x); }
#endif

DEV f32x4 mfma16(short8 a, short8 b, f32x4 c){
  return __builtin_amdgcn_mfma_f32_16x16x32_bf16(
      __builtin_bit_cast(bf16x8, a), __builtin_bit_cast(bf16x8, b), c, 0, 0, 0);
}
DEV f32x16 mfma32(short8 a, short8 b, f32x16 c){
  return __builtin_amdgcn_mfma_f32_32x32x16_bf16(
      __builtin_bit_cast(bf16x8, a), __builtin_bit_cast(bf16x8, b), c, 0, 0, 0);
}
// XOR swizzle for 128-byte-row LDS tiles
DEV int swz(int byteoff, int row){ return byteoff ^ ((row & 7) << 4); }

#if __has_builtin(__builtin_amdgcn_global_load_lds)
#define USE_GLL 1
typedef __attribute__((address_space(1))) const u32 gas_u32;
typedef __attribute__((address_space(3)))       u32 las_u32;
#define GL2L(g, l) __builtin_amdgcn_global_load_lds((gas_u32*)(g), (las_u32*)(l), 16, 0, 0)
#define LSWZ(boff, r) swz(boff, r)
#else
#define LSWZ(boff, r) (boff)
#endif

// ---------------- prep: 5 weight transposes + cs table + RMSNorm -------------
// z=0..4: W(K,N) f32 -> Wt(N,K) bf16; z=5: cs table; z=6: RMSNorm (8 rows/blk)
__global__ __launch_bounds__(256) void k_prep(const float* __restrict__ wq,
                                              const float* __restrict__ kvd,
                                              const float* __restrict__ wk,
                                              const float* __restrict__ wv,
                                              const float* __restrict__ wo,
                                              const float* __restrict__ x,
                                              const float* __restrict__ norm_w,
                                              u16* __restrict__ wqT, u16* __restrict__ kvdT,
                                              u16* __restrict__ wkT, u16* __restrict__ wvT,
                                              u16* __restrict__ woT, u16* __restrict__ xn,
                                              float2* __restrict__ cs, float qscale){
  const int z = blockIdx.z;
  if (z == 6){
    const int bid = blockIdx.y*32 + blockIdx.x;
    const int t = threadIdx.x;
    __shared__ float ps[4];
    const float4 g = ((const float4*)norm_w)[t];
    #pragma unroll 1
    for (int it = 0; it < 8; ++it){
      const int row = bid*8 + it;
      const float4 v = ((const float4*)(x + (size_t)row*1024))[t];
      float ss = v.x*v.x + v.y*v.y + v.z*v.z + v.w*v.w;
      #pragma unroll
      for (int off=32; off; off>>=1) ss += __shfl_xor(ss, off, 64);
      if ((t & 63) == 0) ps[t>>6] = ss;
      __syncthreads();
      const float tot = ps[0]+ps[1]+ps[2]+ps[3];
      const float rinv = rsqrtf(tot * (1.0f/1024.0f) + 1e-6f);
      u16x4 o;
      o.x = f2bf(v.x*rinv*g.x); o.y = f2bf(v.y*rinv*g.y);
      o.z = f2bf(v.z*rinv*g.z); o.w = f2bf(v.w*rinv*g.w);
      *(u16x4*)(xn + (size_t)row*1024 + t*4) = o;
      __syncthreads();
    }
    return;
  }
  if (z == 5){
    if (blockIdx.y >= 8) return;
    const int idx = (blockIdx.y*32 + blockIdx.x)*256 + threadIdx.x;   // 65536 total
    const int s = idx >> 5, j = idx & 31;
    const float ang = (float)s * expf(-(float)j * (9.210340371976184f/32.0f));
    cs[idx] = make_float2(cosf(ang), sinf(ang));
    return;
  }
  const float* W; u16* Wt; int K, N; float sc = 1.0f;
  switch (z){
    case 0: W = wq;  Wt = wqT;  K = 1024; N = 1024; sc = qscale; break;
    case 1: W = kvd; Wt = kvdT; K = 1024; N = 512;  break;
    case 2: W = wk;  Wt = wkT;  K = 512;  N = 1024; break;
    case 3: W = wv;  Wt = wvT;  K = 512;  N = 1024; break;
    default: W = wo; Wt = woT;  K = 1024; N = 1024; break;
  }
  const int k0 = blockIdx.x*32, n0 = blockIdx.y*32;
  if (k0 >= K || n0 >= N) return;
  __shared__ float t[32][33];
  const int tx = threadIdx.x & 31, ty = threadIdx.x >> 5;
  #pragma unroll
  for (int j=0;j<4;++j) t[ty + j*8][tx] = W[(size_t)(k0+ty+j*8)*N + n0 + tx];
  __syncthreads();
  #pragma unroll
  for (int j=0;j<4;++j) Wt[(size_t)(n0+ty+j*8)*K + k0 + tx] = f2bf(t[tx][ty+j*8]*sc);
}

// ---------------- GEMM: A(M,K) bf16 rm x Bt(N,K) bf16 rm --------------------
// 2-phase pipeline: dbuf LDS, STAGE(t+1) issued after barrier, swizzled layout.
// T1 XCD-chunked block swizzle (grid count % 8 == 0).
// MODE 2: f32 out + residual (N=1024), Bt only.
// MODE 4: x<8: RoPE->Cb (N=1024); x>=8: plain bf16 -> Cb2 (N=512, B=Bt2)
// MODE 5: x<8: RoPE->Cb (N=1024); x>=8: vT store  -> Cb2 (B=Bt2)
template<int MODE>
__global__ __launch_bounds__(256) void k_gemm(const u16* __restrict__ A,
                                              const u16* __restrict__ Bt,
                                              const u16* __restrict__ Bt2,
                                              u16* __restrict__ Cb,
                                              u16* __restrict__ Cb2,
                                              float* __restrict__ Cf,
                                              const float* __restrict__ resid,
                                              const float2* __restrict__ cs,
                                              int K){
  __shared__ __align__(16) u16 Al[2][128*64];
  __shared__ __align__(16) u16 Bl[2][128*64];
  const int tid = threadIdx.x, lane = tid & 63, w = tid >> 6;
  const int wm = (w >> 1) * 64, wn = (w & 1) * 64;

  // T1: XCD-chunked swizzle — same-row (by) blocks co-locate on one XCD
  const int gx = gridDim.x;
  const int nwg = gx * gridDim.y;
  int fid = blockIdx.y * gx + blockIdx.x;
  fid = (fid & 7) * (nwg >> 3) + (fid >> 3);
  const int bx = fid % gx, by = fid / gx;

  const bool second = (MODE != 2) && (bx >= 8);
  const u16* B = second ? Bt2 : Bt;
  const int n0 = (second ? bx - 8 : bx) * 128;
  const int m0 = by * 128;
  const int lr = lane & 15, lg = lane >> 4;
  const int nt = K >> 6;

  f32x4 acc[4][4] = {};

#ifdef USE_GLL
  const int rin  = lane >> 3;
  const int colq = (lane & 7) ^ rin;
  auto stage = [&](int t_){
    u16* Ad = &Al[t_ & 1][0];
    u16* Bd = &Bl[t_ & 1][0];
    const int kb = t_ << 6;
    #pragma unroll
    for (int j=0;j<4;++j){
      const int c = w*4 + j;
      GL2L(A + (size_t)(m0 + c*8 + rin)*K + kb + colq*8, Ad + c*512);
      GL2L(B + (size_t)(n0 + c*8 + rin)*K + kb + colq*8, Bd + c*512);
    }
  };
#else
  auto stage = [&](int t_){
    u16* Ad = &Al[t_ & 1][0];
    u16* Bd = &Bl[t_ & 1][0];
    const int kb = t_ << 6;
    const int srow = tid >> 1, scol = (tid & 1) * 32;
    #pragma unroll
    for (int j=0;j<4;++j){
      *(short8*)(Ad + srow*64 + scol + j*8) = *(const short8*)(A + (size_t)(m0+srow)*K + kb + scol + j*8);
      *(short8*)(Bd + srow*64 + scol + j*8) = *(const short8*)(B + (size_t)(n0+srow)*K + kb + scol + j*8);
    }
  };
#endif

  stage(0);
  for (int t = 0; t < nt; ++t){
    __syncthreads();
    if (t + 1 < nt) stage(t + 1);
    const u16* Ab = &Al[t & 1][0];
    const u16* Bb = &Bl[t & 1][0];
    #pragma unroll
    for (int kk=0; kk<2; ++kk){
      const int cb = kk*64 + lg*16;
      short8 af[4], bfr[4];
      #pragma unroll
      for (int m=0;m<4;++m){
        const int r = wm + m*16 + lr;
        af[m] = *(const short8*)((const char*)Ab + LSWZ(r*128 + cb, r));
      }
      #pragma unroll
      for (int n=0;n<4;++n){
        const int r = wn + n*16 + lr;
        bfr[n] = *(const short8*)((const char*)Bb + LSWZ(r*128 + cb, r));
      }
      #pragma unroll
      for (int m=0;m<4;++m)
        #pragma unroll
        for (int n=0;n<4;++n)
          acc[m][n] = mfma16(af[m], bfr[n], acc[m][n]);
    }
  }

  #pragma unroll
  for (int m=0;m<4;++m){
    const int rb = m0 + wm + m*16 + lg*4;
    if (MODE == 2){
      #pragma unroll
      for (int n=0;n<4;++n){
        const int c = n0 + wn + n*16 + lr;
        #pragma unroll
        for (int i=0;i<4;++i){
          const size_t off = (size_t)(rb+i)*1024 + c;
          Cf[off] = acc[m][n][i] + resid[off];
        }
      }
    } else if (!second){
      #pragma unroll
      for (int n=0;n<2;++n){
        const int c = n0 + wn + n*16 + lr;
        const int j = n*16 + lr;
        #pragma unroll
        for (int i=0;i<4;++i){
          const float2 t = cs[(size_t)((rb+i) & 2047)*32 + j];
          const float t1 = acc[m][n][i], t2 = acc[m][n+2][i];
          Cb[(size_t)(rb+i)*1024 + c]      = f2bf(t1*t.x - t2*t.y);
          Cb[(size_t)(rb+i)*1024 + c + 32] = f2bf(t1*t.y + t2*t.x);
        }
      }
    } else if (MODE == 4){
      #pragma unroll
      for (int n=0;n<4;++n){
        const int c = n0 + wn + n*16 + lr;
        #pragma unroll
        for (int i=0;i<4;++i) Cb2[(size_t)(rb+i)*512 + c] = f2bf(acc[m][n][i]);
      }
    } else {
      #pragma unroll
      for (int n=0;n<4;++n){
        const int c = n0 + wn + n*16 + lr;
        const int b = rb >> 11, s = rb & 2047;
        u16x4 pk;
        pk.x = f2bf(acc[m][n][0]); pk.y = f2bf(acc[m][n][1]);
        pk.z = f2bf(acc[m][n][2]); pk.w = f2bf(acc[m][n][3]);
        *(u16x4*)(Cb2 + (((size_t)(b*1024 + c)) << 11) + s) = pk;
      }
    }
  }
}

// ---------------- flash attention: 32x32 MFMA, in-register softmax/P ---------
// q pre-scaled by 0.125*log2(e). q,k: [b][s][h*64+hd]; vT: [(b*1024+d)][s]
// 4 waves x 32 q-rows (QBLK=128), KVBLK=64, K/V dbuf (32KB), no P LDS.
// Tile loop unrolled x2: LDS read offsets precomputed once, buffer parity is a
// literal +0/+8192 folded into ds_read offset; staging via running pointers.
__global__ __launch_bounds__(256, 3) void k_attn(const u16* __restrict__ q,
                                                 const u16* __restrict__ kmat,
                                                 const u16* __restrict__ vT,
                                                 u16* __restrict__ o){
  __shared__ __align__(16) u16 Kl[2][64*64];   // buf1 = byte offset +8192
  __shared__ __align__(16) u16 Vl[2][64*64];
  const int tid = threadIdx.x, lane = tid & 63, w = tid >> 6;   // 4 waves
  const int l31 = lane & 31, hi = lane >> 5;

  // XCD-aware bijective swizzle: 1024 blocks, each head's 16 blocks on 1 XCD
  const int fid = blockIdx.y * 16 + blockIdx.x;
  const int sid = (fid & 7) * 128 + (fid >> 3);
  const int qx = sid & 15, bh = sid >> 4;
  const int b = bh >> 4, h = bh & 15;
  const int q0 = qx * 128;

  // Q fragments (B-operand): lane = q-col q0+w*32+l31; chain c: hd = c*16+hi*8+j
  short8 qf[4];
  {
    const size_t base = ((size_t)(b*2048 + q0 + w*32 + l31) << 10) + (h<<6) + hi*8;
    qf[0] = *(const short8*)(q + base);
    qf[1] = *(const short8*)(q + base + 16);
    qf[2] = *(const short8*)(q + base + 32);
    qf[3] = *(const short8*)(q + base + 48);
  }
  f32x16 oacc0 = {}, oacc1 = {};        // O[q(reg,hi)][d = {0,1}*32 + l31]
  float m = -1e30f, l = 0.f;            // per-lane state for q = l31 (synced w/ partner)

  // precomputed swizzled LDS read byte-offsets (identical for K and V tiles)
  int roff[8];
  #pragma unroll
  for (int c=0;c<4;++c){
    roff[c*2+0] = swz(l31*128      + c*32 + hi*16, l31);
    roff[c*2+1] = swz((32+l31)*128 + c*32 + hi*16, 32+l31);
  }

  // staging: wave w owns chunks 2w, 2w+1 of K and V (8 rows x 128B each);
  // running pointers advanced by constants (K: +64 rows, V: +64 cols)
  const int rin  = lane >> 3;
  const int colq = (lane & 7) ^ rin;    // pre-swizzled 16B slot
  const u16* kp0 = kmat + ((size_t)(b*2048 + w*16 + rin) << 10) + (h<<6) + colq*8;
  const u16* kp1 = kp0 + ((size_t)8 << 10);
  const u16* vp0 = vT + (((size_t)(b*1024 + h*64 + w*16 + rin)) << 11) + colq*8;
  const u16* vp1 = vp0 + ((size_t)8 << 11);
  u16* const Kd0 = Kl[0] + w*1024;  u16* const Kd1 = Kl[1] + w*1024;
  u16* const Vd0 = Vl[0] + w*1024;  u16* const Vd1 = Vl[1] + w*1024;

#ifdef USE_GLL
  #define STAGE(KD, VD) { GL2L(kp0, KD); GL2L(kp1, KD + 512);                   \
      GL2L(vp0, VD); GL2L(vp1, VD + 512);                                       \
      kp0 += 65536; kp1 += 65536; vp0 += 64; vp1 += 64; }
#else
  #define STAGE(KD, VD) { *(short8*)(KD + lane*8) = *(const short8*)(kp0);      \
      *(short8*)(KD + 512 + lane*8) = *(const short8*)(kp1);                    \
      *(short8*)(VD + lane*8) = *(const short8*)(vp0);                          \
      *(short8*)(VD + 512 + lane*8) = *(const short8*)(vp1);                    \
      kp0 += 65536; kp1 += 65536; vp0 += 64; vp1 += 64; }
#endif

  // one KV tile: BOFF is a literal (0 / 8192) -> folds into ds_read offset imm
  #define TILE(BOFF) {                                                          \
    f32x16 s0 = {}, s1 = {};                                                    \
    __builtin_amdgcn_s_setprio(1);                                              \
    _Pragma("unroll")                                                           \
    for (int c=0;c<4;++c){                                                      \
      short8 kf0 = *(const short8*)((const char*)Kl + roff[c*2+0] + BOFF);      \
      short8 kf1 = *(const short8*)((const char*)Kl + roff[c*2+1] + BOFF);      \
      s0 = mfma32(kf0, qf[c], s0);                                              \
      s1 = mfma32(kf1, qf[c], s1);                                              \
    }                                                                           \
    __builtin_amdgcn_s_setprio(0);                                              \
    float tmax = fmaxf(s0[0], s0[1]);                                           \
    _Pragma("unroll")                                                           \
    for (int r=1;r<8;++r) tmax = fmaxf(fmaxf(tmax, s0[2*r]), s0[2*r+1]);        \
    _Pragma("unroll")                                                           \
    for (int r=0;r<8;++r) tmax = fmaxf(fmaxf(tmax, s1[2*r]), s1[2*r+1]);        \
    tmax = fmaxf(tmax, __shfl_xor(tmax, 32, 64));                               \
    if (__any(tmax > m + 8.0f)){                                                \
      const float mn = fmaxf(m, tmax);                                          \
      const float corr = fexp2(m - mn);                                         \
      m = mn; l *= corr;                                                        \
      _Pragma("unroll")                                                         \
      for (int reg=0; reg<16; ++reg){                                           \
        const int cq = (reg&3) + 8*(reg>>2) + 4*hi;                             \
        const float cr = __shfl(corr, cq, 64);                                  \
        oacc0[reg] *= cr; oacc1[reg] *= cr;                                     \
      }                                                                         \
    }                                                                           \
    float rs0 = 0.f, rs1 = 0.f;                                                 \
    u32 pk0[8], pk1[8];                                                         \
    _Pragma("unroll")                                                           \
    for (int a=0;a<4;++a){                                                      \
      _Pragma("unroll")                                                         \
      for (int e=0;e<2;++e){                                                    \
        float pa = fexp2(s0[a*4+e*2] - m), pb = fexp2(s0[a*4+e*2+1] - m);       \
        rs0 += pa + pb;  pk0[a*2+e] = pkbf(pa, pb);                             \
        pa = fexp2(s1[a*4+e*2] - m); pb = fexp2(s1[a*4+e*2+1] - m);             \
        rs1 += pa + pb;  pk1[a*2+e] = pkbf(pa, pb);                             \
      }                                                                         \
    }                                                                           \
    float rs = rs0 + rs1;                                                       \
    rs += __shfl_xor(rs, 32, 64);                                               \
    l += rs;                                                                    \
    __builtin_amdgcn_s_setprio(1);                                              \
    _Pragma("unroll")                                                           \
    for (int c=0;c<4;++c){                                                      \
      u32* pks = (c < 2) ? pk0 : pk1;                                           \
      const int cc = c & 1;                                                     \
      u32 a0 = pks[(2*cc)*2+0], b0 = pks[(2*cc+1)*2+0];                         \
      u32 a1 = pks[(2*cc)*2+1], b1 = pks[(2*cc+1)*2+1];                         \
      asm volatile("v_permlane32_swap_b32 %0, %1" : "+v"(a0), "+v"(b0));        \
      asm volatile("v_permlane32_swap_b32 %0, %1" : "+v"(a1), "+v"(b1));        \
      u32x4 pfv; pfv.x = a0; pfv.y = a1; pfv.z = b0; pfv.w = b1;                \
      const short8 pf = __builtin_bit_cast(short8, pfv);                        \
      short8 vf0 = *(const short8*)((const char*)Vl + roff[c*2+0] + BOFF);      \
      short8 vf1 = *(const short8*)((const char*)Vl + roff[c*2+1] + BOFF);      \
      oacc0 = mfma32(pf, vf0, oacc0);                                           \
      oacc1 = mfma32(pf, vf1, oacc1);                                           \
    }                                                                           \
    __builtin_amdgcn_s_setprio(0);                                              \
  }

  STAGE(Kd0, Vd0);                      // tile 0 -> buf0
  #pragma unroll 1
  for (int tt = 0; tt < 16; ++tt){
    __syncthreads();                    // buf1 free + drains GLL of tile 2tt
    STAGE(Kd1, Vd1);                    // tile 2tt+1 -> buf1 (in flight)
    TILE(0);                            // compute tile 2tt from buf0
    __syncthreads();                    // buf0 free + drains GLL of tile 2tt+1
    if (tt < 15) STAGE(Kd0, Vd0);       // tile 2tt+2 -> buf0 (in flight)
    TILE(8192);                         // compute tile 2tt+1 from buf1
  }

  // epilogue: divide by l (per O-row), store O[q][d]
  const float linv = 1.0f / l;
  #pragma unroll
  for (int reg=0; reg<16; ++reg){
    const int cq = (reg&3) + 8*(reg>>2) + 4*hi;
    const float lv = __shfl(linv, cq, 64);
    const size_t rowbase = ((size_t)(b*2048 + q0 + w*32 + cq) << 10) + (h<<6);
    o[rowbase + l31]      = f2bf(oacc0[reg] * lv);
    o[rowbase + 32 + l31] = f2bf(oacc1[reg] * lv);
  }
  #undef STAGE
  #undef TILE
}

// ---------------------------------------------------------------------------
extern "C" void kernel_launch(void* const* d_in, const int* in_sizes, int n_in,
                              void* d_out, int out_size, void* d_ws, size_t ws_size,
                              hipStream_t stream){
  const float* x      = (const float*)d_in[0];
  const float* norm_w = (const float*)d_in[1];
  const float* wq     = (const float*)d_in[2];
  const float* kvd    = (const float*)d_in[3];
  const float* wk     = (const float*)d_in[4];
  const float* wv     = (const float*)d_in[5];
  const float* wo     = (const float*)d_in[6];
  float* out = (float*)d_out;

  char* ws = (char*)d_ws;
  const size_t SZ = (size_t)8192*1024*2;       // 16 MB bf16 tensor
  u16* xn   = (u16*)(ws);
  u16* q    = (u16*)(ws + SZ);
  u16* kmat = (u16*)(ws + 2*SZ);
  u16* vT   = (u16*)(ws + 3*SZ);
  u16* attn = (u16*)(ws + 4*SZ);
  u16* kv   = (u16*)(ws + 5*SZ);               // 8 MB
  u16* wqT  = (u16*)(ws + 5*SZ + (size_t)8192*512*2);
  u16* kvdT = wqT  + 1024*1024;
  u16* wkT  = kvdT + 512*1024;
  u16* wvT  = wkT  + 1024*512;
  u16* woT  = wvT  + 1024*512;
  float2* cs = (float2*)(woT + 1024*1024);

  const float QSCALE = 0.125f * 1.4426950408889634f;   // softmax scale * log2(e)

  // prep: weights (z=0..4) + cs (z=5) + rmsnorm (z=6)
  k_prep<<<dim3(32,32,7), 256, 0, stream>>>(wq, kvd, wk, wv, wo, x, norm_w,
                                            wqT, kvdT, wkT, wvT, woT, xn, cs, QSCALE);

  // q = rope(xn@wq*QSCALE) | kv = xn@kvd        (fused, shared A)
  k_gemm<4><<<dim3(12,64), 256, 0, stream>>>(xn, wqT, kvdT, q, kv, nullptr, nullptr, cs, 1024);
  // kmat = rope(kv@wk) | vT = (kv@wv)^T         (fused, shared A)
  k_gemm<5><<<dim3(16,64), 256, 0, stream>>>(kv, wkT, wvT, kmat, vT, nullptr, nullptr, cs, 512);

  k_attn<<<dim3(16,64), 256, 0, stream>>>(q, kmat, vT, attn);

  // out = attn @ wo + x
  k_gemm<2><<<dim3(8,64), 256, 0, stream>>>(attn, woT, nullptr, nullptr, nullptr, out, x, nullptr, 1024);
}

// Round 10
// 193.252 us; speedup vs baseline: 2.0770x; 1.0403x over previous
//
#include <hip/hip_runtime.h>

typedef unsigned short u16;
typedef unsigned int   u32;
typedef __attribute__((ext_vector_type(8)))  __bf16 bf16x8;
typedef __attribute__((ext_vector_type(2)))  __bf16 bf16x2;
typedef __attribute__((ext_vector_type(8)))  short  short8;
typedef __attribute__((ext_vector_type(4)))  float  f32x4;
typedef __attribute__((ext_vector_type(16))) float  f32x16;
typedef __attribute__((ext_vector_type(4)))  u16    u16x4;
typedef __attribute__((ext_vector_type(4)))  u32    u32x4;

#define DEV static __device__ __forceinline__

DEV u16 f2bf(float f){ return __builtin_bit_cast(u16, (__bf16)f); }
DEV u32 pkbf(float a, float b){ bf16x2 t; t[0] = (__bf16)a; t[1] = (__bf16)b;
                                return __builtin_bit_cast(u32, t); }

#if __has_builtin(__builtin_amdgcn_exp2f)
DEV float fexp2(float x){ return __builtin_amdgcn_exp2f(x); }
#else
DEV float fexp2(float x){ return exp2f(x); }
#endif

DEV f32x4 mfma16(short8 a, short8 b, f32x4 c){
  return __builtin_amdgcn_mfma_f32_16x16x32_bf16(
      __builtin_bit_cast(bf16x8, a), __builtin_bit_cast(bf16x8, b), c, 0, 0, 0);
}
DEV f32x16 mfma32(short8 a, short8 b, f32x16 c){
  return __builtin_amdgcn_mfma_f32_32x32x16_bf16(
      __builtin_bit_cast(bf16x8, a), __builtin_bit_cast(bf16x8, b), c, 0, 0, 0);
}
// XOR swizzle for 128-byte-row LDS tiles
DEV int swz(int byteoff, int row){ return byteoff ^ ((row & 7) << 4); }

#if __has_builtin(__builtin_amdgcn_global_load_lds)
#define USE_GLL 1
typedef __attribute__((address_space(1))) const u32 gas_u32;
typedef __attribute__((address_space(3)))       u32 las_u32;
#define GL2L(g, l) __builtin_amdgcn_global_load_lds((gas_u32*)(g), (las_u32*)(l), 16, 0, 0)
#define LSWZ(boff, r) swz(boff, r)
#else
#define LSWZ(boff, r) (boff)
#endif

// ---------------- prep: 5 weight transposes + cs table + RMSNorm -------------
// z=0..4: W(K,N) f32 -> Wt(N,K) bf16; z=5: cs table; z=6: RMSNorm (8 rows/blk)
__global__ __launch_bounds__(256) void k_prep(const float* __restrict__ wq,
                                              const float* __restrict__ kvd,
                                              const float* __restrict__ wk,
                                              const float* __restrict__ wv,
                                              const float* __restrict__ wo,
                                              const float* __restrict__ x,
                                              const float* __restrict__ norm_w,
                                              u16* __restrict__ wqT, u16* __restrict__ kvdT,
                                              u16* __restrict__ wkT, u16* __restrict__ wvT,
                                              u16* __restrict__ woT, u16* __restrict__ xn,
                                              float2* __restrict__ cs, float qscale){
  const int z = blockIdx.z;
  if (z == 6){
    const int bid = blockIdx.y*32 + blockIdx.x;
    const int t = threadIdx.x;
    __shared__ float ps[4];
    const float4 g = ((const float4*)norm_w)[t];
    #pragma unroll 1
    for (int it = 0; it < 8; ++it){
      const int row = bid*8 + it;
      const float4 v = ((const float4*)(x + (size_t)row*1024))[t];
      float ss = v.x*v.x + v.y*v.y + v.z*v.z + v.w*v.w;
      #pragma unroll
      for (int off=32; off; off>>=1) ss += __shfl_xor(ss, off, 64);
      if ((t & 63) == 0) ps[t>>6] = ss;
      __syncthreads();
      const float tot = ps[0]+ps[1]+ps[2]+ps[3];
      const float rinv = rsqrtf(tot * (1.0f/1024.0f) + 1e-6f);
      u16x4 o;
      o.x = f2bf(v.x*rinv*g.x); o.y = f2bf(v.y*rinv*g.y);
      o.z = f2bf(v.z*rinv*g.z); o.w = f2bf(v.w*rinv*g.w);
      *(u16x4*)(xn + (size_t)row*1024 + t*4) = o;
      __syncthreads();
    }
    return;
  }
  if (z == 5){
    if (blockIdx.y >= 8) return;
    const int idx = (blockIdx.y*32 + blockIdx.x)*256 + threadIdx.x;   // 65536 total
    const int s = idx >> 5, j = idx & 31;
    const float ang = (float)s * expf(-(float)j * (9.210340371976184f/32.0f));
    cs[idx] = make_float2(cosf(ang), sinf(ang));
    return;
  }
  const float* W; u16* Wt; int K, N; float sc = 1.0f;
  switch (z){
    case 0: W = wq;  Wt = wqT;  K = 1024; N = 1024; sc = qscale; break;
    case 1: W = kvd; Wt = kvdT; K = 1024; N = 512;  break;
    case 2: W = wk;  Wt = wkT;  K = 512;  N = 1024; break;
    case 3: W = wv;  Wt = wvT;  K = 512;  N = 1024; break;
    default: W = wo; Wt = woT;  K = 1024; N = 1024; break;
  }
  const int k0 = blockIdx.x*32, n0 = blockIdx.y*32;
  if (k0 >= K || n0 >= N) return;
  __shared__ float t[32][33];
  const int tx = threadIdx.x & 31, ty = threadIdx.x >> 5;
  #pragma unroll
  for (int j=0;j<4;++j) t[ty + j*8][tx] = W[(size_t)(k0+ty+j*8)*N + n0 + tx];
  __syncthreads();
  #pragma unroll
  for (int j=0;j<4;++j) Wt[(size_t)(n0+ty+j*8)*K + k0 + tx] = f2bf(t[tx][ty+j*8]*sc);
}

// ---------------- GEMM: A(M,K) bf16 rm x Bt(N,K) bf16 rm --------------------
// 2-phase pipeline: dbuf LDS, STAGE(t+1) issued after barrier, swizzled layout.
// T1 XCD-chunked block swizzle (grid count % 8 == 0).
// MODE 2: f32 out + residual (N=1024), Bt only.
// MODE 4: x<8: RoPE->Cb (N=1024); x>=8: plain bf16 -> Cb2 (N=512, B=Bt2)
// MODE 5: x<8: RoPE->Cb (N=1024); x>=8: vT store  -> Cb2 (B=Bt2)
template<int MODE>
__global__ __launch_bounds__(256) void k_gemm(const u16* __restrict__ A,
                                              const u16* __restrict__ Bt,
                                              const u16* __restrict__ Bt2,
                                              u16* __restrict__ Cb,
                                              u16* __restrict__ Cb2,
                                              float* __restrict__ Cf,
                                              const float* __restrict__ resid,
                                              const float2* __restrict__ cs,
                                              int K){
  __shared__ __align__(16) u16 Al[2][128*64];
  __shared__ __align__(16) u16 Bl[2][128*64];
  const int tid = threadIdx.x, lane = tid & 63, w = tid >> 6;
  const int wm = (w >> 1) * 64, wn = (w & 1) * 64;

  // T1: XCD-chunked swizzle — same-row (by) blocks co-locate on one XCD
  const int gx = gridDim.x;
  const int nwg = gx * gridDim.y;
  int fid = blockIdx.y * gx + blockIdx.x;
  fid = (fid & 7) * (nwg >> 3) + (fid >> 3);
  const int bx = fid % gx, by = fid / gx;

  const bool second = (MODE != 2) && (bx >= 8);
  const u16* B = second ? Bt2 : Bt;
  const int n0 = (second ? bx - 8 : bx) * 128;
  const int m0 = by * 128;
  const int lr = lane & 15, lg = lane >> 4;
  const int nt = K >> 6;

  f32x4 acc[4][4] = {};

#ifdef USE_GLL
  const int rin  = lane >> 3;
  const int colq = (lane & 7) ^ rin;
  auto stage = [&](int t_){
    u16* Ad = &Al[t_ & 1][0];
    u16* Bd = &Bl[t_ & 1][0];
    const int kb = t_ << 6;
    #pragma unroll
    for (int j=0;j<4;++j){
      const int c = w*4 + j;
      GL2L(A + (size_t)(m0 + c*8 + rin)*K + kb + colq*8, Ad + c*512);
      GL2L(B + (size_t)(n0 + c*8 + rin)*K + kb + colq*8, Bd + c*512);
    }
  };
#else
  auto stage = [&](int t_){
    u16* Ad = &Al[t_ & 1][0];
    u16* Bd = &Bl[t_ & 1][0];
    const int kb = t_ << 6;
    const int srow = tid >> 1, scol = (tid & 1) * 32;
    #pragma unroll
    for (int j=0;j<4;++j){
      *(short8*)(Ad + srow*64 + scol + j*8) = *(const short8*)(A + (size_t)(m0+srow)*K + kb + scol + j*8);
      *(short8*)(Bd + srow*64 + scol + j*8) = *(const short8*)(B + (size_t)(n0+srow)*K + kb + scol + j*8);
    }
  };
#endif

  stage(0);
  for (int t = 0; t < nt; ++t){
    __syncthreads();
    if (t + 1 < nt) stage(t + 1);
    const u16* Ab = &Al[t & 1][0];
    const u16* Bb = &Bl[t & 1][0];
    #pragma unroll
    for (int kk=0; kk<2; ++kk){
      const int cb = kk*64 + lg*16;
      short8 af[4], bfr[4];
      #pragma unroll
      for (int m=0;m<4;++m){
        const int r = wm + m*16 + lr;
        af[m] = *(const short8*)((const char*)Ab + LSWZ(r*128 + cb, r));
      }
      #pragma unroll
      for (int n=0;n<4;++n){
        const int r = wn + n*16 + lr;
        bfr[n] = *(const short8*)((const char*)Bb + LSWZ(r*128 + cb, r));
      }
      #pragma unroll
      for (int m=0;m<4;++m)
        #pragma unroll
        for (int n=0;n<4;++n)
          acc[m][n] = mfma16(af[m], bfr[n], acc[m][n]);
    }
  }

  #pragma unroll
  for (int m=0;m<4;++m){
    const int rb = m0 + wm + m*16 + lg*4;
    if (MODE == 2){
      #pragma unroll
      for (int n=0;n<4;++n){
        const int c = n0 + wn + n*16 + lr;
        #pragma unroll
        for (int i=0;i<4;++i){
          const size_t off = (size_t)(rb+i)*1024 + c;
          Cf[off] = acc[m][n][i] + resid[off];
        }
      }
    } else if (!second){
      #pragma unroll
      for (int n=0;n<2;++n){
        const int c = n0 + wn + n*16 + lr;
        const int j = n*16 + lr;
        #pragma unroll
        for (int i=0;i<4;++i){
          const float2 t = cs[(size_t)((rb+i) & 2047)*32 + j];
          const float t1 = acc[m][n][i], t2 = acc[m][n+2][i];
          Cb[(size_t)(rb+i)*1024 + c]      = f2bf(t1*t.x - t2*t.y);
          Cb[(size_t)(rb+i)*1024 + c + 32] = f2bf(t1*t.y + t2*t.x);
        }
      }
    } else if (MODE == 4){
      #pragma unroll
      for (int n=0;n<4;++n){
        const int c = n0 + wn + n*16 + lr;
        #pragma unroll
        for (int i=0;i<4;++i) Cb2[(size_t)(rb+i)*512 + c] = f2bf(acc[m][n][i]);
      }
    } else {
      #pragma unroll
      for (int n=0;n<4;++n){
        const int c = n0 + wn + n*16 + lr;
        const int b = rb >> 11, s = rb & 2047;
        u16x4 pk;
        pk.x = f2bf(acc[m][n][0]); pk.y = f2bf(acc[m][n][1]);
        pk.z = f2bf(acc[m][n][2]); pk.w = f2bf(acc[m][n][3]);
        *(u16x4*)(Cb2 + (((size_t)(b*1024 + c)) << 11) + s) = pk;
      }
    }
  }
}

// ---------------- flash attention: 32x32 MFMA, T15 2-deep pipeline -----------
// q pre-scaled by 0.125*log2(e). q,k: [b][s][h*64+hd]; vT: [(b*1024+d)][s]
// 4 waves x 32 q-rows (QBLK=128), KVBLK=64, K/V TRIPLE-buffered (48KB).
// Per iter t: QK(t+1) MFMAs issue BEFORE softmax(t) (MFMA || VALU overlap),
// then PV(t); barrier; STAGE(t+3) into buf(t%3) (reads of it are pre-barrier).
__global__ __launch_bounds__(256, 2) void k_attn(const u16* __restrict__ q,
                                                 const u16* __restrict__ kmat,
                                                 const u16* __restrict__ vT,
                                                 u16* __restrict__ o){
  __shared__ __align__(16) u16 Kl[3][64*64];   // buf i at byte offset i*8192
  __shared__ __align__(16) u16 Vl[3][64*64];
  const int tid = threadIdx.x, lane = tid & 63, w = tid >> 6;   // 4 waves
  const int l31 = lane & 31, hi = lane >> 5;

  // XCD-aware bijective swizzle: 1024 blocks, each head's 16 blocks on 1 XCD
  const int fid = blockIdx.y * 16 + blockIdx.x;
  const int sid = (fid & 7) * 128 + (fid >> 3);
  const int qx = sid & 15, bh = sid >> 4;
  const int b = bh >> 4, h = bh & 15;
  const int q0 = qx * 128;

  // Q fragments (B-operand): lane = q-col q0+w*32+l31; chain c: hd = c*16+hi*8+j
  short8 qf[4];
  {
    const size_t base = ((size_t)(b*2048 + q0 + w*32 + l31) << 10) + (h<<6) + hi*8;
    qf[0] = *(const short8*)(q + base);
    qf[1] = *(const short8*)(q + base + 16);
    qf[2] = *(const short8*)(q + base + 32);
    qf[3] = *(const short8*)(q + base + 48);
  }
  f32x16 oacc0 = {}, oacc1 = {};        // O[q(reg,hi)][d = {0,1}*32 + l31]
  float m = -1e30f, l = 0.f;            // per-lane state for q = l31 (partner-synced)

  // precomputed swizzled LDS read byte-offsets (within one 8KB tile)
  int roff[8];
  #pragma unroll
  for (int c=0;c<4;++c){
    roff[c*2+0] = swz(l31*128      + c*32 + hi*16, l31);
    roff[c*2+1] = swz((32+l31)*128 + c*32 + hi*16, 32+l31);
  }

  // staging: wave w owns chunks 2w, 2w+1 (8 rows x 128B each); running ptrs
  const int rin  = lane >> 3;
  const int colq = (lane & 7) ^ rin;    // pre-swizzled 16B slot
  const u16* kp0 = kmat + ((size_t)(b*2048 + w*16 + rin) << 10) + (h<<6) + colq*8;
  const u16* kp1 = kp0 + ((size_t)8 << 10);
  const u16* vp0 = vT + (((size_t)(b*1024 + h*64 + w*16 + rin)) << 11) + colq*8;
  const u16* vp1 = vp0 + ((size_t)8 << 11);

#ifdef USE_GLL
  #define STAGE(CUR) { u16* KD = (u16*)((char*)Kl + (CUR)*8192) + w*1024;       \
      u16* VD = (u16*)((char*)Vl + (CUR)*8192) + w*1024;                        \
      GL2L(kp0, KD); GL2L(kp1, KD + 512);                                       \
      GL2L(vp0, VD); GL2L(vp1, VD + 512);                                       \
      kp0 += 65536; kp1 += 65536; vp0 += 64; vp1 += 64; }
#else
  #define STAGE(CUR) { u16* KD = (u16*)((char*)Kl + (CUR)*8192) + w*1024;       \
      u16* VD = (u16*)((char*)Vl + (CUR)*8192) + w*1024;                        \
      *(short8*)(KD + lane*8) = *(const short8*)(kp0);                          \
      *(short8*)(KD + 512 + lane*8) = *(const short8*)(kp1);                    \
      *(short8*)(VD + lane*8) = *(const short8*)(vp0);                          \
      *(short8*)(VD + 512 + lane*8) = *(const short8*)(vp1);                    \
      kp0 += 65536; kp1 += 65536; vp0 += 64; vp1 += 64; }
#endif

  // QK^T of one tile from buf NXT into N0/N1
  #define QKT(NXT, N0, N1) {                                                    \
    __builtin_amdgcn_s_setprio(1);                                              \
    _Pragma("unroll")                                                           \
    for (int c=0;c<4;++c){                                                      \
      short8 kf0 = *(const short8*)((const char*)Kl + roff[c*2+0] + (NXT)*8192);\
      short8 kf1 = *(const short8*)((const char*)Kl + roff[c*2+1] + (NXT)*8192);\
      N0 = mfma32(kf0, qf[c], N0);                                              \
      N1 = mfma32(kf1, qf[c], N1);                                              \
    }                                                                           \
    __builtin_amdgcn_s_setprio(0); }

  // softmax on s0/s1 (tile t) + PV from buf CUR
  #define SMAX_PV(CUR) {                                                        \
    float tmax = fmaxf(s0[0], s0[1]);                                           \
    _Pragma("unroll")                                                           \
    for (int r=1;r<8;++r) tmax = fmaxf(fmaxf(tmax, s0[2*r]), s0[2*r+1]);        \
    _Pragma("unroll")                                                           \
    for (int r=0;r<8;++r) tmax = fmaxf(fmaxf(tmax, s1[2*r]), s1[2*r+1]);        \
    { u32 ta = __builtin_bit_cast(u32, tmax), tb = ta;                          \
      asm volatile("v_permlane32_swap_b32 %0, %1" : "+v"(ta), "+v"(tb));        \
      tmax = fmaxf(__builtin_bit_cast(float, ta), __builtin_bit_cast(float, tb)); } \
    if (__any(tmax > m + 8.0f)){                                                \
      const float mn = fmaxf(m, tmax);                                          \
      const float corr = fexp2(m - mn);                                         \
      m = mn; l *= corr;                                                        \
      _Pragma("unroll")                                                         \
      for (int reg=0; reg<16; ++reg){                                           \
        const int cq = (reg&3) + 8*(reg>>2) + 4*hi;                             \
        const float cr = __shfl(corr, cq, 64);                                  \
        oacc0[reg] *= cr; oacc1[reg] *= cr;                                     \
      }                                                                         \
    }                                                                           \
    float rs0 = 0.f, rs1 = 0.f;                                                 \
    u32 pk0[8], pk1[8];                                                         \
    _Pragma("unroll")                                                           \
    for (int a=0;a<4;++a){                                                      \
      _Pragma("unroll")                                                         \
      for (int e=0;e<2;++e){                                                    \
        float pa = fexp2(s0[a*4+e*2] - m), pb = fexp2(s0[a*4+e*2+1] - m);       \
        rs0 += pa + pb;  pk0[a*2+e] = pkbf(pa, pb);                             \
        pa = fexp2(s1[a*4+e*2] - m); pb = fexp2(s1[a*4+e*2+1] - m);             \
        rs1 += pa + pb;  pk1[a*2+e] = pkbf(pa, pb);                             \
      }                                                                         \
    }                                                                           \
    { float rsx = rs0 + rs1;                                                    \
      u32 ra = __builtin_bit_cast(u32, rsx), rb = ra;                           \
      asm volatile("v_permlane32_swap_b32 %0, %1" : "+v"(ra), "+v"(rb));        \
      l += __builtin_bit_cast(float, ra) + __builtin_bit_cast(float, rb); }     \
    __builtin_amdgcn_s_setprio(1);                                              \
    _Pragma("unroll")                                                           \
    for (int c=0;c<4;++c){                                                      \
      u32* pks = (c < 2) ? pk0 : pk1;                                           \
      const int cc = c & 1;                                                     \
      u32 a0 = pks[(2*cc)*2+0], b0 = pks[(2*cc+1)*2+0];                         \
      u32 a1 = pks[(2*cc)*2+1], b1 = pks[(2*cc+1)*2+1];                         \
      asm volatile("v_permlane32_swap_b32 %0, %1" : "+v"(a0), "+v"(b0));        \
      asm volatile("v_permlane32_swap_b32 %0, %1" : "+v"(a1), "+v"(b1));        \
      u32x4 pfv; pfv.x = a0; pfv.y = a1; pfv.z = b0; pfv.w = b1;                \
      const short8 pf = __builtin_bit_cast(short8, pfv);                        \
      short8 vf0 = *(const short8*)((const char*)Vl + roff[c*2+0] + (CUR)*8192);\
      short8 vf1 = *(const short8*)((const char*)Vl + roff[c*2+1] + (CUR)*8192);\
      oacc0 = mfma32(pf, vf0, oacc0);                                           \
      oacc1 = mfma32(pf, vf1, oacc1);                                           \
    }                                                                           \
    __builtin_amdgcn_s_setprio(0); }

  // iter t: QK(t+1) || softmax(t); PV(t); barrier; STAGE(t+3)->buf(t%3)
  #define BODY(CUR, NXT, DOSTAGE) {                                             \
    f32x16 n0 = {}, n1 = {};                                                    \
    QKT(NXT, n0, n1)                                                            \
    SMAX_PV(CUR)                                                                \
    __syncthreads();                                                            \
    if (DOSTAGE) STAGE(CUR);                                                    \
    s0 = n0; s1 = n1; }

  // prologue: stage tiles 0,1,2; compute s(0)
  STAGE(0); STAGE(1); STAGE(2);
  __syncthreads();
  f32x16 s0 = {}, s1 = {};
  QKT(0, s0, s1)

  #pragma unroll 1
  for (int u = 0; u < 10; ++u){           // t = 3u, 3u+1, 3u+2  (t in 0..29)
    BODY(0, 1, true)                      // stage tile t+3 in 3..30
    BODY(1, 2, true)
    BODY(2, 0, (u < 9))                   // u=9 would stage tile 32 — skip
  }
  // t = 30: QK(31) from buf1, softmax(30), PV(30) from buf0
  {
    f32x16 n0 = {}, n1 = {};
    QKT(1, n0, n1)
    SMAX_PV(0)
    s0 = n0; s1 = n1;
  }
  // t = 31: softmax(31), PV(31) from buf1
  SMAX_PV(1)

  // epilogue: divide by l (per O-row), store O[q][d]
  const float linv = 1.0f / l;
  #pragma unroll
  for (int reg=0; reg<16; ++reg){
    const int cq = (reg&3) + 8*(reg>>2) + 4*hi;
    const float lv = __shfl(linv, cq, 64);
    const size_t rowbase = ((size_t)(b*2048 + q0 + w*32 + cq) << 10) + (h<<6);
    o[rowbase + l31]      = f2bf(oacc0[reg] * lv);
    o[rowbase + 32 + l31] = f2bf(oacc1[reg] * lv);
  }
  #undef STAGE
  #undef QKT
  #undef SMAX_PV
  #undef BODY
}

// ---------------------------------------------------------------------------
extern "C" void kernel_launch(void* const* d_in, const int* in_sizes, int n_in,
                              void* d_out, int out_size, void* d_ws, size_t ws_size,
                              hipStream_t stream){
  const float* x      = (const float*)d_in[0];
  const float* norm_w = (const float*)d_in[1];
  const float* wq     = (const float*)d_in[2];
  const float* kvd    = (const float*)d_in[3];
  const float* wk     = (const float*)d_in[4];
  const float* wv     = (const float*)d_in[5];
  const float* wo     = (const float*)d_in[6];
  float* out = (float*)d_out;

  char* ws = (char*)d_ws;
  const size_t SZ = (size_t)8192*1024*2;       // 16 MB bf16 tensor
  u16* xn   = (u16*)(ws);
  u16* q    = (u16*)(ws + SZ);
  u16* kmat = (u16*)(ws + 2*SZ);
  u16* vT   = (u16*)(ws + 3*SZ);
  u16* attn = (u16*)(ws + 4*SZ);
  u16* kv   = (u16*)(ws + 5*SZ);               // 8 MB
  u16* wqT  = (u16*)(ws + 5*SZ + (size_t)8192*512*2);
  u16* kvdT = wqT  + 1024*1024;
  u16* wkT  = kvdT + 512*1024;
  u16* wvT  = wkT  + 1024*512;
  u16* woT  = wvT  + 1024*512;
  float2* cs = (float2*)(woT + 1024*1024);

  const float QSCALE = 0.125f * 1.4426950408889634f;   // softmax scale * log2(e)

  // prep: weights (z=0..4) + cs (z=5) + rmsnorm (z=6)
  k_prep<<<dim3(32,32,7), 256, 0, stream>>>(wq, kvd, wk, wv, wo, x, norm_w,
                                            wqT, kvdT, wkT, wvT, woT, xn, cs, QSCALE);

  // q = rope(xn@wq*QSCALE) | kv = xn@kvd        (fused, shared A)
  k_gemm<4><<<dim3(12,64), 256, 0, stream>>>(xn, wqT, kvdT, q, kv, nullptr, nullptr, cs, 1024);
  // kmat = rope(kv@wk) | vT = (kv@wv)^T         (fused, shared A)
  k_gemm<5><<<dim3(16,64), 256, 0, stream>>>(kv, wkT, wvT, kmat, vT, nullptr, nullptr, cs, 512);

  k_attn<<<dim3(16,64), 256, 0, stream>>>(q, kmat, vT, attn);

  // out = attn @ wo + x
  k_gemm<2><<<dim3(8,64), 256, 0, stream>>>(attn, woT, nullptr, nullptr, nullptr, out, x, nullptr, 1024);
}

// Round 12
// 188.957 us; speedup vs baseline: 2.1242x; 1.0227x over previous
//
#include <hip/hip_runtime.h>

typedef unsigned short u16;
typedef unsigned int   u32;
typedef __attribute__((ext_vector_type(8)))  __bf16 bf16x8;
typedef __attribute__((ext_vector_type(2)))  __bf16 bf16x2;
typedef __attribute__((ext_vector_type(8)))  short  short8;
typedef __attribute__((ext_vector_type(4)))  float  f32x4;
typedef __attribute__((ext_vector_type(16))) float  f32x16;
typedef __attribute__((ext_vector_type(4)))  u16    u16x4;
typedef __attribute__((ext_vector_type(4)))  u32    u32x4;

#define DEV static __device__ __forceinline__

DEV u16 f2bf(float f){ return __builtin_bit_cast(u16, (__bf16)f); }
DEV u32 pkbf(float a, float b){ bf16x2 t; t[0] = (__bf16)a; t[1] = (__bf16)b;
                                return __builtin_bit_cast(u32, t); }

#if __has_builtin(__builtin_amdgcn_exp2f)
DEV float fexp2(float x){ return __builtin_amdgcn_exp2f(x); }
#else
DEV float fexp2(float x){ return exp2f(x); }
#endif

DEV f32x4 mfma16(short8 a, short8 b, f32x4 c){
  return __builtin_amdgcn_mfma_f32_16x16x32_bf16(
      __builtin_bit_cast(bf16x8, a), __builtin_bit_cast(bf16x8, b), c, 0, 0, 0);
}
DEV f32x16 mfma32(short8 a, short8 b, f32x16 c){
  return __builtin_amdgcn_mfma_f32_32x32x16_bf16(
      __builtin_bit_cast(bf16x8, a), __builtin_bit_cast(bf16x8, b), c, 0, 0, 0);
}
// XOR swizzle for 128-byte-row LDS tiles
DEV int swz(int byteoff, int row){ return byteoff ^ ((row & 7) << 4); }

#if __has_builtin(__builtin_amdgcn_global_load_lds)
#define USE_GLL 1
typedef __attribute__((address_space(1))) const u32 gas_u32;
typedef __attribute__((address_space(3)))       u32 las_u32;
#define GL2L(g, l) __builtin_amdgcn_global_load_lds((gas_u32*)(g), (las_u32*)(l), 16, 0, 0)
#define LSWZ(boff, r) swz(boff, r)
#else
#define LSWZ(boff, r) (boff)
#endif

// ---------------- prep: 5 weight transposes + cs table + RMSNorm -------------
// z=0..4: W(K,N) f32 -> Wt(N,K) bf16; z=5: cs table; z=6: RMSNorm (8 rows/blk)
__global__ __launch_bounds__(256) void k_prep(const float* __restrict__ wq,
                                              const float* __restrict__ kvd,
                                              const float* __restrict__ wk,
                                              const float* __restrict__ wv,
                                              const float* __restrict__ wo,
                                              const float* __restrict__ x,
                                              const float* __restrict__ norm_w,
                                              u16* __restrict__ wqT, u16* __restrict__ kvdT,
                                              u16* __restrict__ wkT, u16* __restrict__ wvT,
                                              u16* __restrict__ woT, u16* __restrict__ xn,
                                              float2* __restrict__ cs, float qscale){
  const int z = blockIdx.z;
  if (z == 6){
    const int bid = blockIdx.y*32 + blockIdx.x;
    const int t = threadIdx.x;
    __shared__ float ps[4];
    const float4 g = ((const float4*)norm_w)[t];
    #pragma unroll 1
    for (int it = 0; it < 8; ++it){
      const int row = bid*8 + it;
      const float4 v = ((const float4*)(x + (size_t)row*1024))[t];
      float ss = v.x*v.x + v.y*v.y + v.z*v.z + v.w*v.w;
      #pragma unroll
      for (int off=32; off; off>>=1) ss += __shfl_xor(ss, off, 64);
      if ((t & 63) == 0) ps[t>>6] = ss;
      __syncthreads();
      const float tot = ps[0]+ps[1]+ps[2]+ps[3];
      const float rinv = rsqrtf(tot * (1.0f/1024.0f) + 1e-6f);
      u16x4 o;
      o.x = f2bf(v.x*rinv*g.x); o.y = f2bf(v.y*rinv*g.y);
      o.z = f2bf(v.z*rinv*g.z); o.w = f2bf(v.w*rinv*g.w);
      *(u16x4*)(xn + (size_t)row*1024 + t*4) = o;
      __syncthreads();
    }
    return;
  }
  if (z == 5){
    if (blockIdx.y >= 8) return;
    const int idx = (blockIdx.y*32 + blockIdx.x)*256 + threadIdx.x;   // 65536 total
    const int s = idx >> 5, j = idx & 31;
    const float ang = (float)s * expf(-(float)j * (9.210340371976184f/32.0f));
    cs[idx] = make_float2(cosf(ang), sinf(ang));
    return;
  }
  const float* W; u16* Wt; int K, N; float sc = 1.0f;
  switch (z){
    case 0: W = wq;  Wt = wqT;  K = 1024; N = 1024; sc = qscale; break;
    case 1: W = kvd; Wt = kvdT; K = 1024; N = 512;  break;
    case 2: W = wk;  Wt = wkT;  K = 512;  N = 1024; break;
    case 3: W = wv;  Wt = wvT;  K = 512;  N = 1024; break;
    default: W = wo; Wt = woT;  K = 1024; N = 1024; break;
  }
  const int k0 = blockIdx.x*32, n0 = blockIdx.y*32;
  if (k0 >= K || n0 >= N) return;
  __shared__ float t[32][33];
  const int tx = threadIdx.x & 31, ty = threadIdx.x >> 5;
  #pragma unroll
  for (int j=0;j<4;++j) t[ty + j*8][tx] = W[(size_t)(k0+ty+j*8)*N + n0 + tx];
  __syncthreads();
  #pragma unroll
  for (int j=0;j<4;++j) Wt[(size_t)(n0+ty+j*8)*K + k0 + tx] = f2bf(t[tx][ty+j*8]*sc);
}

// ---------------- GEMM: A(M,K) bf16 rm x Bt(N,K) bf16 rm --------------------
// 2-phase pipeline: dbuf LDS, STAGE(t+1) issued after barrier, swizzled layout.
// T1 XCD-chunked block swizzle (grid count % 8 == 0).
// MODE 2: f32 out + residual (N=1024), Bt only.
// MODE 4: x<8: RoPE->Cb (N=1024); x>=8: plain bf16 -> Cb2 (N=512, B=Bt2)
// MODE 5: x<8: RoPE->Cb (N=1024); x>=8: vT store  -> Cb2 (B=Bt2)
template<int MODE>
__global__ __launch_bounds__(256) void k_gemm(const u16* __restrict__ A,
                                              const u16* __restrict__ Bt,
                                              const u16* __restrict__ Bt2,
                                              u16* __restrict__ Cb,
                                              u16* __restrict__ Cb2,
                                              float* __restrict__ Cf,
                                              const float* __restrict__ resid,
                                              const float2* __restrict__ cs,
                                              int K){
  __shared__ __align__(16) u16 Al[2][128*64];
  __shared__ __align__(16) u16 Bl[2][128*64];
  const int tid = threadIdx.x, lane = tid & 63, w = tid >> 6;
  const int wm = (w >> 1) * 64, wn = (w & 1) * 64;

  // T1: XCD-chunked swizzle — same-row (by) blocks co-locate on one XCD
  const int gx = gridDim.x;
  const int nwg = gx * gridDim.y;
  int fid = blockIdx.y * gx + blockIdx.x;
  fid = (fid & 7) * (nwg >> 3) + (fid >> 3);
  const int bx = fid % gx, by = fid / gx;

  const bool second = (MODE != 2) && (bx >= 8);
  const u16* B = second ? Bt2 : Bt;
  const int n0 = (second ? bx - 8 : bx) * 128;
  const int m0 = by * 128;
  const int lr = lane & 15, lg = lane >> 4;
  const int nt = K >> 6;

  f32x4 acc[4][4] = {};

#ifdef USE_GLL
  const int rin  = lane >> 3;
  const int colq = (lane & 7) ^ rin;
  auto stage = [&](int t_){
    u16* Ad = &Al[t_ & 1][0];
    u16* Bd = &Bl[t_ & 1][0];
    const int kb = t_ << 6;
    #pragma unroll
    for (int j=0;j<4;++j){
      const int c = w*4 + j;
      GL2L(A + (size_t)(m0 + c*8 + rin)*K + kb + colq*8, Ad + c*512);
      GL2L(B + (size_t)(n0 + c*8 + rin)*K + kb + colq*8, Bd + c*512);
    }
  };
#else
  auto stage = [&](int t_){
    u16* Ad = &Al[t_ & 1][0];
    u16* Bd = &Bl[t_ & 1][0];
    const int kb = t_ << 6;
    const int srow = tid >> 1, scol = (tid & 1) * 32;
    #pragma unroll
    for (int j=0;j<4;++j){
      *(short8*)(Ad + srow*64 + scol + j*8) = *(const short8*)(A + (size_t)(m0+srow)*K + kb + scol + j*8);
      *(short8*)(Bd + srow*64 + scol + j*8) = *(const short8*)(B + (size_t)(n0+srow)*K + kb + scol + j*8);
    }
  };
#endif

  stage(0);
  for (int t = 0; t < nt; ++t){
    __syncthreads();
    if (t + 1 < nt) stage(t + 1);
    const u16* Ab = &Al[t & 1][0];
    const u16* Bb = &Bl[t & 1][0];
    #pragma unroll
    for (int kk=0; kk<2; ++kk){
      const int cb = kk*64 + lg*16;
      short8 af[4], bfr[4];
      #pragma unroll
      for (int m=0;m<4;++m){
        const int r = wm + m*16 + lr;
        af[m] = *(const short8*)((const char*)Ab + LSWZ(r*128 + cb, r));
      }
      #pragma unroll
      for (int n=0;n<4;++n){
        const int r = wn + n*16 + lr;
        bfr[n] = *(const short8*)((const char*)Bb + LSWZ(r*128 + cb, r));
      }
      #pragma unroll
      for (int m=0;m<4;++m)
        #pragma unroll
        for (int n=0;n<4;++n)
          acc[m][n] = mfma16(af[m], bfr[n], acc[m][n]);
    }
  }

  #pragma unroll
  for (int m=0;m<4;++m){
    const int rb = m0 + wm + m*16 + lg*4;
    if (MODE == 2){
      #pragma unroll
      for (int n=0;n<4;++n){
        const int c = n0 + wn + n*16 + lr;
        #pragma unroll
        for (int i=0;i<4;++i){
          const size_t off = (size_t)(rb+i)*1024 + c;
          Cf[off] = acc[m][n][i] + resid[off];
        }
      }
    } else if (!second){
      #pragma unroll
      for (int n=0;n<2;++n){
        const int c = n0 + wn + n*16 + lr;
        const int j = n*16 + lr;
        #pragma unroll
        for (int i=0;i<4;++i){
          const float2 t = cs[(size_t)((rb+i) & 2047)*32 + j];
          const float t1 = acc[m][n][i], t2 = acc[m][n+2][i];
          Cb[(size_t)(rb+i)*1024 + c]      = f2bf(t1*t.x - t2*t.y);
          Cb[(size_t)(rb+i)*1024 + c + 32] = f2bf(t1*t.y + t2*t.x);
        }
      }
    } else if (MODE == 4){
      #pragma unroll
      for (int n=0;n<4;++n){
        const int c = n0 + wn + n*16 + lr;
        #pragma unroll
        for (int i=0;i<4;++i) Cb2[(size_t)(rb+i)*512 + c] = f2bf(acc[m][n][i]);
      }
    } else {
      #pragma unroll
      for (int n=0;n<4;++n){
        const int c = n0 + wn + n*16 + lr;
        const int b = rb >> 11, s = rb & 2047;
        u16x4 pk;
        pk.x = f2bf(acc[m][n][0]); pk.y = f2bf(acc[m][n][1]);
        pk.z = f2bf(acc[m][n][2]); pk.w = f2bf(acc[m][n][3]);
        *(u16x4*)(Cb2 + (((size_t)(b*1024 + c)) << 11) + s) = pk;
      }
    }
  }
}

// ---------------- flash attention: 32x32 MFMA, in-register softmax/P ---------
// q pre-scaled by 0.125*log2(e). q,k: [b][s][h*64+hd]; vT: [(b*1024+d)][s]
// 8 waves x 32 q-rows (QBLK=256), KVBLK=64, K/V dbuf (32KB), no P LDS.
// Race-free 2-buffer schedule (R9): barrier -> STAGE(next) -> TILE(cur).
// Grid 512 x 8 waves = 4096 waves = exactly 4 waves/SIMD chip-wide (TLP).
__global__ __launch_bounds__(512, 4) void k_attn(const u16* __restrict__ q,
                                                 const u16* __restrict__ kmat,
                                                 const u16* __restrict__ vT,
                                                 u16* __restrict__ o){
  __shared__ __align__(16) u16 Kl[2][64*64];   // buf1 = byte offset +8192
  __shared__ __align__(16) u16 Vl[2][64*64];
  const int tid = threadIdx.x, lane = tid & 63, w = tid >> 6;   // 8 waves
  const int l31 = lane & 31, hi = lane >> 5;

  // XCD-aware bijective swizzle: 512 blocks; 8 (b,h) pairs per XCD
  const int fid = blockIdx.y * 8 + blockIdx.x;
  const int sid = (fid & 7) * 64 + (fid >> 3);
  const int qx = sid & 7, bh = sid >> 3;
  const int b = bh >> 4, h = bh & 15;
  const int q0 = qx * 256;

  // Q fragments (B-operand): lane = q-col q0+w*32+l31; chain c: hd = c*16+hi*8+j
  short8 qf[4];
  {
    const size_t base = ((size_t)(b*2048 + q0 + w*32 + l31) << 10) + (h<<6) + hi*8;
    qf[0] = *(const short8*)(q + base);
    qf[1] = *(const short8*)(q + base + 16);
    qf[2] = *(const short8*)(q + base + 32);
    qf[3] = *(const short8*)(q + base + 48);
  }
  f32x16 oacc0 = {}, oacc1 = {};        // O[q(reg,hi)][d = {0,1}*32 + l31]
  float m = -1e30f, l = 0.f;            // per-lane state for q = l31 (partner-synced)

  // precomputed swizzled LDS read byte-offsets (identical for K and V tiles)
  int roff[8];
  #pragma unroll
  for (int c=0;c<4;++c){
    roff[c*2+0] = swz(l31*128      + c*32 + hi*16, l31);
    roff[c*2+1] = swz((32+l31)*128 + c*32 + hi*16, 32+l31);
  }

  // staging: wave w owns chunk w (8 rows x 128B) of K and of V; running ptrs
  const int rin  = lane >> 3;
  const int colq = (lane & 7) ^ rin;    // pre-swizzled 16B slot
  const u16* kp0 = kmat + ((size_t)(b*2048 + w*8 + rin) << 10) + (h<<6) + colq*8;
  const u16* vp0 = vT + (((size_t)(b*1024 + h*64 + w*8 + rin)) << 11) + colq*8;
  u16* const Kd0 = Kl[0] + w*512;  u16* const Kd1 = Kl[1] + w*512;
  u16* const Vd0 = Vl[0] + w*512;  u16* const Vd1 = Vl[1] + w*512;

#ifdef USE_GLL
  #define STAGE(KD, VD) { GL2L(kp0, KD); GL2L(vp0, VD);                         \
      kp0 += 65536; vp0 += 64; }
#else
  #define STAGE(KD, VD) { *(short8*)(KD + lane*8) = *(const short8*)(kp0);      \
      *(short8*)(VD + lane*8) = *(const short8*)(vp0);                          \
      kp0 += 65536; vp0 += 64; }
#endif

  // one KV tile: BOFF is a literal (0 / 8192) -> folds into ds_read offset imm
  #define TILE(BOFF) {                                                          \
    f32x16 s0 = {}, s1 = {};                                                    \
    __builtin_amdgcn_s_setprio(1);                                              \
    _Pragma("unroll")                                                           \
    for (int c=0;c<4;++c){                                                      \
      short8 kf0 = *(const short8*)((const char*)Kl + roff[c*2+0] + BOFF);      \
      short8 kf1 = *(const short8*)((const char*)Kl + roff[c*2+1] + BOFF);      \
      s0 = mfma32(kf0, qf[c], s0);                                              \
      s1 = mfma32(kf1, qf[c], s1);                                              \
    }                                                                           \
    __builtin_amdgcn_s_setprio(0);                                              \
    float tmax = fmaxf(s0[0], s0[1]);                                           \
    _Pragma("unroll")                                                           \
    for (int r=1;r<8;++r) tmax = fmaxf(fmaxf(tmax, s0[2*r]), s0[2*r+1]);        \
    _Pragma("unroll")                                                           \
    for (int r=0;r<8;++r) tmax = fmaxf(fmaxf(tmax, s1[2*r]), s1[2*r+1]);        \
    tmax = fmaxf(tmax, __shfl_xor(tmax, 32, 64));                               \
    if (__any(tmax > m + 8.0f)){                                                \
      const float mn = fmaxf(m, tmax);                                          \
      const float corr = fexp2(m - mn);                                         \
      m = mn; l *= corr;                                                        \
      _Pragma("unroll")                                                         \
      for (int reg=0; reg<16; ++reg){                                           \
        const int cq = (reg&3) + 8*(reg>>2) + 4*hi;                             \
        const float cr = __shfl(corr, cq, 64);                                  \
        oacc0[reg] *= cr; oacc1[reg] *= cr;                                     \
      }                                                                         \
    }                                                                           \
    float rs0 = 0.f, rs1 = 0.f;                                                 \
    u32 pk0[8], pk1[8];                                                         \
    _Pragma("unroll")                                                           \
    for (int a=0;a<4;++a){                                                      \
      _Pragma("unroll")                                                         \
      for (int e=0;e<2;++e){                                                    \
        float pa = fexp2(s0[a*4+e*2] - m), pb = fexp2(s0[a*4+e*2+1] - m);       \
        rs0 += pa + pb;  pk0[a*2+e] = pkbf(pa, pb);                             \
        pa = fexp2(s1[a*4+e*2] - m); pb = fexp2(s1[a*4+e*2+1] - m);             \
        rs1 += pa + pb;  pk1[a*2+e] = pkbf(pa, pb);                             \
      }                                                                         \
    }                                                                           \
    float rs = rs0 + rs1;                                                       \
    rs += __shfl_xor(rs, 32, 64);                                               \
    l += rs;                                                                    \
    __builtin_amdgcn_s_setprio(1);                                              \
    _Pragma("unroll")                                                           \
    for (int c=0;c<4;++c){                                                      \
      u32* pks = (c < 2) ? pk0 : pk1;                                           \
      const int cc = c & 1;                                                     \
      u32 a0 = pks[(2*cc)*2+0], b0 = pks[(2*cc+1)*2+0];                         \
      u32 a1 = pks[(2*cc)*2+1], b1 = pks[(2*cc+1)*2+1];                         \
      asm volatile("v_permlane32_swap_b32 %0, %1" : "+v"(a0), "+v"(b0));        \
      asm volatile("v_permlane32_swap_b32 %0, %1" : "+v"(a1), "+v"(b1));        \
      u32x4 pfv; pfv.x = a0; pfv.y = a1; pfv.z = b0; pfv.w = b1;                \
      const short8 pf = __builtin_bit_cast(short8, pfv);                        \
      short8 vf0 = *(const short8*)((const char*)Vl + roff[c*2+0] + BOFF);      \
      short8 vf1 = *(const short8*)((const char*)Vl + roff[c*2+1] + BOFF);      \
      oacc0 = mfma32(pf, vf0, oacc0);                                           \
      oacc1 = mfma32(pf, vf1, oacc1);                                           \
    }                                                                           \
    __builtin_amdgcn_s_setprio(0);                                              \
  }

  STAGE(Kd0, Vd0);                      // tile 0 -> buf0
  #pragma unroll 1
  for (int tt = 0; tt < 16; ++tt){
    __syncthreads();                    // buf1 free + drains GLL of tile 2tt
    STAGE(Kd1, Vd1);                    // tile 2tt+1 -> buf1 (in flight)
    TILE(0);                            // compute tile 2tt from buf0
    __syncthreads();                    // buf0 free + drains GLL of tile 2tt+1
    if (tt < 15) STAGE(Kd0, Vd0);       // tile 2tt+2 -> buf0 (in flight)
    TILE(8192);                         // compute tile 2tt+1 from buf1
  }

  // epilogue: divide by l (per O-row), store O[q][d]
  const float linv = 1.0f / l;
  #pragma unroll
  for (int reg=0; reg<16; ++reg){
    const int cq = (reg&3) + 8*(reg>>2) + 4*hi;
    const float lv = __shfl(linv, cq, 64);
    const size_t rowbase = ((size_t)(b*2048 + q0 + w*32 + cq) << 10) + (h<<6);
    o[rowbase + l31]      = f2bf(oacc0[reg] * lv);
    o[rowbase + 32 + l31] = f2bf(oacc1[reg] * lv);
  }
  #undef STAGE
  #undef TILE
}

// ---------------------------------------------------------------------------
extern "C" void kernel_launch(void* const* d_in, const int* in_sizes, int n_in,
                              void* d_out, int out_size, void* d_ws, size_t ws_size,
                              hipStream_t stream){
  const float* x      = (const float*)d_in[0];
  const float* norm_w = (const float*)d_in[1];
  const float* wq     = (const float*)d_in[2];
  const float* kvd    = (const float*)d_in[3];
  const float* wk     = (const float*)d_in[4];
  const float* wv     = (const float*)d_in[5];
  const float* wo     = (const float*)d_in[6];
  float* out = (float*)d_out;

  char* ws = (char*)d_ws;
  const size_t SZ = (size_t)8192*1024*2;       // 16 MB bf16 tensor
  u16* xn   = (u16*)(ws);
  u16* q    = (u16*)(ws + SZ);
  u16* kmat = (u16*)(ws + 2*SZ);
  u16* vT   = (u16*)(ws + 3*SZ);
  u16* attn = (u16*)(ws + 4*SZ);
  u16* kv   = (u16*)(ws + 5*SZ);               // 8 MB
  u16* wqT  = (u16*)(ws + 5*SZ + (size_t)8192*512*2);
  u16* kvdT = wqT  + 1024*1024;
  u16* wkT  = kvdT + 512*1024;
  u16* wvT  = wkT  + 1024*512;
  u16* woT  = wvT  + 1024*512;
  float2* cs = (float2*)(woT + 1024*1024);

  const float QSCALE = 0.125f * 1.4426950408889634f;   // softmax scale * log2(e)

  // prep: weights (z=0..4) + cs (z=5) + rmsnorm (z=6)
  k_prep<<<dim3(32,32,7), 256, 0, stream>>>(wq, kvd, wk, wv, wo, x, norm_w,
                                            wqT, kvdT, wkT, wvT, woT, xn, cs, QSCALE);

  // q = rope(xn@wq*QSCALE) | kv = xn@kvd        (fused, shared A)
  k_gemm<4><<<dim3(12,64), 256, 0, stream>>>(xn, wqT, kvdT, q, kv, nullptr, nullptr, cs, 1024);
  // kmat = rope(kv@wk) | vT = (kv@wv)^T         (fused, shared A)
  k_gemm<5><<<dim3(16,64), 256, 0, stream>>>(kv, wkT, wvT, kmat, vT, nullptr, nullptr, cs, 512);

  k_attn<<<dim3(8,64), 512, 0, stream>>>(q, kmat, vT, attn);

  // out = attn @ wo + x
  k_gemm<2><<<dim3(8,64), 256, 0, stream>>>(attn, woT, nullptr, nullptr, nullptr, out, x, nullptr, 1024);
}